// Round 3
// baseline (3571.679 us; speedup 1.0000x reference)
//
#include <hip/hip_runtime.h>
#include <math.h>

#define DI __device__ __forceinline__
#define HW128 (128*128)
#define HW256 (256*256)

__device__ const float BN_RS = 0.9999950000374997f; // 1/sqrt(1+1e-5)

DI float leakyf(float x){ return x >= 0.f ? x : 0.2f*x; }

// ---------------------------------------------------------------------------
// Prepack: transpose conv weights to [ic][tap][oc] (contiguous oc for scalar
// dwordx16 loads), fold BN scale into the 3x3 convs, transpose fc2.
// ---------------------------------------------------------------------------
__global__ __launch_bounds__(256) void prepack(
    const float* __restrict__ w7a, const float* __restrict__ w1,
    const float* __restrict__ w3a, const float* __restrict__ b3a, const float* __restrict__ g3a, const float* __restrict__ be3a,
    const float* __restrict__ w3b, const float* __restrict__ b3b, const float* __restrict__ g3b, const float* __restrict__ be3b,
    const float* __restrict__ w3c, const float* __restrict__ b3c, const float* __restrict__ g3c, const float* __restrict__ be3c,
    const float* __restrict__ w7b, const float* __restrict__ fc2w,
    float* __restrict__ p7a, float* __restrict__ p1,
    float* __restrict__ p3a, float* __restrict__ q3a,
    float* __restrict__ p3b, float* __restrict__ q3b,
    float* __restrict__ p3c, float* __restrict__ q3c,
    float* __restrict__ p7b, float* __restrict__ pf2)
{
    int i = blockIdx.x * 256 + threadIdx.x;
    if (i < 50176) {
        { int oc = i & 15,  t = (i >> 4) % 49, ic = (i >> 4) / 49;
          p7a[i] = w7a[(oc*64 + ic)*49 + t]; }           // w7a: (16,64,7,7)
        { int oc = i & 63,  t = (i >> 6) % 49, ic = (i >> 6) / 49;
          p7b[i] = w7b[(oc*16 + ic)*49 + t]; }           // w7b: (64,16,7,7)
    }
    if (i < 256) { int oc = i & 15, ic = i >> 4; p1[i] = w1[oc*16 + ic]; }
    if (i < 2304) {
        int oc = i & 15, t = (i >> 4) % 9, ic = (i >> 4) / 9;
        int src = (oc*16 + ic)*9 + t;
        p3a[i] = w3a[src] * (g3a[oc]*BN_RS);
        p3b[i] = w3b[src] * (g3b[oc]*BN_RS);
        p3c[i] = w3c[src] * (g3c[oc]*BN_RS);
    }
    if (i < 16) {
        q3a[i] = b3a[i]*(g3a[i]*BN_RS) + be3a[i];
        q3b[i] = b3b[i]*(g3b[i]*BN_RS) + be3b[i];
        q3c[i] = b3c[i]*(g3c[i]*BN_RS) + be3c[i];
    }
    if (i < 4096) { int j = i >> 6, c = i & 63; pf2[i] = fc2w[c*64 + j]; } // fc2^T
}

// ---------------------------------------------------------------------------
// Stage A+B: conv7x7(64->16) -> leaky -> conv1x1(16->16) -> leaky -> BN
// x: (8,64,128,128) -> y2: (8,16,128,128).  16x16 spatial tile per block.
// ---------------------------------------------------------------------------
__global__ __launch_bounds__(256) void conv7a_1x1_bn(
    const float* __restrict__ x, const float* __restrict__ p7a,
    const float* __restrict__ b7a, const float* __restrict__ p1,
    const float* __restrict__ b1, const float* __restrict__ bng,
    const float* __restrict__ bnb, float* __restrict__ y2)
{
    __shared__ float tile[8][22][22];
    const int tx = threadIdx.x, ty = threadIdx.y;
    const int n = blockIdx.z, ox = blockIdx.x*16, oy = blockIdx.y*16;
    const int tid = ty*16 + tx;
    float acc[16];
#pragma unroll
    for (int o = 0; o < 16; ++o) acc[o] = 0.f;

    for (int icc = 0; icc < 64; icc += 8) {
        __syncthreads();
        for (int i = tid; i < 8*22*22; i += 256) {
            int ic = i / 484; int rem = i - ic*484;
            int r = rem / 22; int cc = rem - r*22;
            int iy = oy + r - 3, ix = ox + cc - 3;
            float v = 0.f;
            if (iy >= 0 && iy < 128 && ix >= 0 && ix < 128)
                v = x[((n*64 + icc + ic)*128 + iy)*128 + ix];
            tile[ic][r][cc] = v;
        }
        __syncthreads();
        for (int ic = 0; ic < 8; ++ic) {
            const float* wrow = p7a + (icc + ic)*49*16;
            for (int ky = 0; ky < 7; ++ky) {
#pragma unroll
                for (int kx = 0; kx < 7; ++kx) {
                    float v = tile[ic][ty + ky][tx + kx];
                    const float* w = wrow + (ky*7 + kx)*16;
#pragma unroll
                    for (int o = 0; o < 16; ++o) acc[o] += v * w[o];
                }
            }
        }
    }
    float l[16];
#pragma unroll
    for (int o = 0; o < 16; ++o) l[o] = leakyf(acc[o] + b7a[o]);
    const int p = (oy + ty)*128 + (ox + tx);
#pragma unroll
    for (int o = 0; o < 16; ++o) {
        float u = b1[o];
#pragma unroll
        for (int ic = 0; ic < 16; ++ic) u += l[ic] * p1[ic*16 + o];
        u = leakyf(u);
        u = u * (bng[o]*BN_RS) + bnb[o];
        y2[(n*16 + o)*HW128 + p] = u;
    }
}

// ---------------------------------------------------------------------------
// Bilinear resize 128->256, align_corners=True. One thread per output pixel
// per channel; blockIdx.z = flattened (n*C + c).
// ---------------------------------------------------------------------------
__global__ __launch_bounds__(256) void resize_128_256(
    const float* __restrict__ in, float* __restrict__ out)
{
    int nc = blockIdx.z;
    int ox = blockIdx.x*16 + threadIdx.x;
    int oy = blockIdx.y*16 + threadIdx.y;
    float sy = oy * (127.f/255.f), sx = ox * (127.f/255.f);
    int y0 = min((int)sy, 126), x0 = min((int)sx, 126);
    float fy = sy - y0, fx = sx - x0;
    const float* b = in + nc*HW128;
    float v00 = b[y0*128 + x0],       v01 = b[y0*128 + x0 + 1];
    float v10 = b[y0*128 + 128 + x0], v11 = b[y0*128 + 128 + x0 + 1];
    float top = v00*(1.f-fx) + v01*fx;
    float bot = v10*(1.f-fx) + v11*fx;
    out[nc*HW256 + oy*256 + ox] = top*(1.f-fy) + bot*fy;
}

// ---------------------------------------------------------------------------
// 3x3 conv 16->16 with pre-folded BN. MODE 0: leaky epilogue. MODE 1: +res.
// ---------------------------------------------------------------------------
template<int ADD_RES>
__global__ __launch_bounds__(256) void conv3x3_bn(
    const float* __restrict__ in, const float* __restrict__ pw,
    const float* __restrict__ pb, const float* __restrict__ res,
    float* __restrict__ out)
{
    __shared__ float tile[16][18][18];
    const int tx = threadIdx.x, ty = threadIdx.y;
    const int n = blockIdx.z, ox = blockIdx.x*16, oy = blockIdx.y*16;
    const int tid = ty*16 + tx;
    for (int i = tid; i < 16*18*18; i += 256) {
        int ic = i / 324; int rem = i - ic*324;
        int r = rem / 18; int cc = rem - r*18;
        int iy = oy + r - 1, ix = ox + cc - 1;
        float v = 0.f;
        if (iy >= 0 && iy < 256 && ix >= 0 && ix < 256)
            v = in[((n*16 + ic)*256 + iy)*256 + ix];
        tile[ic][r][cc] = v;
    }
    __syncthreads();
    float acc[16];
#pragma unroll
    for (int o = 0; o < 16; ++o) acc[o] = pb[o];
    for (int ic = 0; ic < 16; ++ic) {
#pragma unroll
        for (int ky = 0; ky < 3; ++ky) {
#pragma unroll
            for (int kx = 0; kx < 3; ++kx) {
                float v = tile[ic][ty + ky][tx + kx];
                const float* w = pw + (ic*9 + ky*3 + kx)*16;
#pragma unroll
                for (int o = 0; o < 16; ++o) acc[o] += v * w[o];
            }
        }
    }
    const int p = (oy + ty)*256 + (ox + tx);
#pragma unroll
    for (int o = 0; o < 16; ++o) {
        float u = acc[o];
        if (ADD_RES) u += res[(n*16 + o)*HW256 + p];
        else         u = leakyf(u);
        out[(n*16 + o)*HW256 + p] = u;
    }
}

// ---------------------------------------------------------------------------
// Stage G: conv7x7(16->64) + bilinear identity(x) add; also emits the
// attention key logit k[n,p] = dot(a_k_w, out0[n,:,p]) + a_k_b.
// ---------------------------------------------------------------------------
__global__ __launch_bounds__(256) void conv7b_ident_k(
    const float* __restrict__ z, const float* __restrict__ pw,
    const float* __restrict__ bias, const float* __restrict__ x,
    const float* __restrict__ akw, const float* __restrict__ akb,
    float* __restrict__ out0, float* __restrict__ kbuf)
{
    __shared__ float tile[16][22][22];
    const int tx = threadIdx.x, ty = threadIdx.y;
    const int n = blockIdx.z, ox = blockIdx.x*16, oy = blockIdx.y*16;
    const int tid = ty*16 + tx;
    for (int i = tid; i < 16*22*22; i += 256) {
        int ic = i / 484; int rem = i - ic*484;
        int r = rem / 22; int cc = rem - r*22;
        int iy = oy + r - 3, ix = ox + cc - 3;
        float v = 0.f;
        if (iy >= 0 && iy < 256 && ix >= 0 && ix < 256)
            v = z[((n*16 + ic)*256 + iy)*256 + ix];
        tile[ic][r][cc] = v;
    }
    __syncthreads();
    float acc[64];
#pragma unroll
    for (int o = 0; o < 64; ++o) acc[o] = bias[o];
    for (int ic = 0; ic < 16; ++ic) {
        for (int ky = 0; ky < 7; ++ky) {
            for (int kx = 0; kx < 7; ++kx) {
                float v = tile[ic][ty + ky][tx + kx];
                const float* w = pw + (ic*49 + ky*7 + kx)*64;
#pragma unroll
                for (int o = 0; o < 64; ++o) acc[o] += v * w[o];
            }
        }
    }
    // epilogue: + bilinear(x), write out0, compute k
    const int ohy = oy + ty, ohx = ox + tx;
    float sy = ohy * (127.f/255.f), sx = ohx * (127.f/255.f);
    int y0 = min((int)sy, 126), x0 = min((int)sx, 126);
    float fy = sy - y0, fx = sx - x0;
    const float* xb = x + n*64*HW128;
    const int p = ohy*256 + ohx;
    float kacc = akb[0];
#pragma unroll
    for (int o = 0; o < 64; ++o) {
        const float* xc = xb + o*HW128;
        float v00 = xc[y0*128 + x0],       v01 = xc[y0*128 + x0 + 1];
        float v10 = xc[y0*128 + 128 + x0], v11 = xc[y0*128 + 128 + x0 + 1];
        float idv = (v00*(1.f-fx) + v01*fx)*(1.f-fy) + (v10*(1.f-fx) + v11*fx)*fy;
        float u = acc[o] + idv;
        out0[(n*64 + o)*HW256 + p] = u;
        kacc += akw[o] * u;
    }
    kbuf[n*65536 + p] = kacc;
}

// ---------------------------------------------------------------------------
// Softmax stats per image: max and 1/sum(exp(k-max)) over 65536 positions.
// ---------------------------------------------------------------------------
__global__ __launch_bounds__(1024) void softmax_stats(
    const float* __restrict__ kb, float* __restrict__ st)
{
    __shared__ float red[16];
    __shared__ float bc;
    const int n = blockIdx.x, tid = threadIdx.x;
    const float* kp = kb + n*65536;
    float mx = -3.0e38f;
    for (int i = tid; i < 65536; i += 1024) mx = fmaxf(mx, kp[i]);
#pragma unroll
    for (int off = 1; off < 64; off <<= 1) mx = fmaxf(mx, __shfl_xor(mx, off));
    int w = tid >> 6, l = tid & 63;
    if (l == 0) red[w] = mx;
    __syncthreads();
    if (tid == 0) {
        float m = red[0];
        for (int i = 1; i < 16; ++i) m = fmaxf(m, red[i]);
        bc = m;
    }
    __syncthreads();
    float MX = bc;
    float s = 0.f;
    for (int i = tid; i < 65536; i += 1024) s += __expf(kp[i] - MX);
#pragma unroll
    for (int off = 1; off < 64; off <<= 1) s += __shfl_xor(s, off);
    __syncthreads();
    if (l == 0) red[w] = s;
    __syncthreads();
    if (tid == 0) {
        float S = 0.f;
        for (int i = 0; i < 16; ++i) S += red[i];
        st[n] = MX; st[8 + n] = 1.f / S;
    }
}

// ---------------------------------------------------------------------------
// Raw softmax-weighted channel sums: S[n,c] = sum_p exp(k-mx) * out0[n,c,p].
// grid = (8 channel-groups, 8 n); block = 256.
// ---------------------------------------------------------------------------
__global__ __launch_bounds__(256) void att_wsum(
    const float* __restrict__ out0, const float* __restrict__ kb,
    const float* __restrict__ st, float* __restrict__ S)
{
    const int cg = blockIdx.x, n = blockIdx.y, c0 = cg*8;
    const float mx = st[n];
    const float* kp = kb + n*65536;
    const float* base = out0 + (size_t)(n*64 + c0)*HW256;
    float acc[8];
#pragma unroll
    for (int c = 0; c < 8; ++c) acc[c] = 0.f;
    for (int p = threadIdx.x; p < 65536; p += 256) {
        float e = __expf(kp[p] - mx);
#pragma unroll
        for (int c = 0; c < 8; ++c) acc[c] += e * base[c*HW256 + p];
    }
#pragma unroll
    for (int c = 0; c < 8; ++c)
#pragma unroll
        for (int off = 1; off < 64; off <<= 1) acc[c] += __shfl_xor(acc[c], off);
    __shared__ float red[4][8];
    int w = threadIdx.x >> 6, l = threadIdx.x & 63;
    if (l == 0) {
#pragma unroll
        for (int c = 0; c < 8; ++c) red[w][c] = acc[c];
    }
    __syncthreads();
    if (threadIdx.x < 8)
        S[n*64 + c0 + threadIdx.x] =
            red[0][threadIdx.x] + red[1][threadIdx.x] + red[2][threadIdx.x] + red[3][threadIdx.x];
}

// ---------------------------------------------------------------------------
// context[n,vc] = a_v_b + invZ * dot(a_v_w[vc,:], S[n,:]);
// addc[n,c] = a_r_b[c] + dot(a_r_w[c,:], context[n,:])
// ---------------------------------------------------------------------------
__global__ __launch_bounds__(512) void ctx_addc(
    const float* __restrict__ S, const float* __restrict__ st,
    const float* __restrict__ avw, const float* __restrict__ avb,
    const float* __restrict__ arw, const float* __restrict__ arb,
    float* __restrict__ addc)
{
    __shared__ float ctx[8][8];
    const int tid = threadIdx.x;
    if (tid < 64) {
        int n = tid >> 3, vc = tid & 7;
        float s = 0.f;
        for (int c = 0; c < 64; ++c) s += avw[vc*64 + c] * S[n*64 + c];
        ctx[n][vc] = s * st[8 + n] + avb[vc];
    }
    __syncthreads();
    int n = tid >> 6, c = tid & 63;
    float a = arb[c];
#pragma unroll
    for (int vc = 0; vc < 8; ++vc) a += arw[c*8 + vc] * ctx[n][vc];
    addc[n*64 + c] = a;
}

// ---------------------------------------------------------------------------
// Transformer (in place on d_out): t = out0 + addc; t += MLP(LN(t)).
// One thread per token; all register arrays statically indexed.
// ---------------------------------------------------------------------------
__global__ __launch_bounds__(256) void transformer(
    float* __restrict__ out0, const float* __restrict__ addc,
    const float* __restrict__ lng, const float* __restrict__ lnb,
    const float* __restrict__ fc1w, const float* __restrict__ fc1b,
    const float* __restrict__ pf2, const float* __restrict__ fc2b)
{
    const int id = blockIdx.x*256 + threadIdx.x;
    const int n = id >> 16, p = id & 65535;
    float* base = out0 + (size_t)n*64*HW256 + p;
    const float* ac = addc + n*64;
    float t[64];
#pragma unroll
    for (int c = 0; c < 64; ++c) t[c] = base[c*HW256] + ac[c];
    float mu = 0.f;
#pragma unroll
    for (int c = 0; c < 64; ++c) mu += t[c];
    mu *= (1.f/64.f);
    float var = 0.f;
#pragma unroll
    for (int c = 0; c < 64; ++c) { float d = t[c] - mu; var += d*d; }
    var *= (1.f/64.f);
    float rs = rsqrtf(var + 1e-5f);
    float acc[64];
#pragma unroll
    for (int c = 0; c < 64; ++c) {
        acc[c] = t[c] + fc2b[c];
        t[c] = (t[c] - mu)*rs*lng[c] + lnb[c];
    }
    for (int j = 0; j < 64; ++j) {
        float m = fc1b[j];
#pragma unroll
        for (int i = 0; i < 64; ++i) m += t[i] * fc1w[j*64 + i];
        float g = 0.5f*m*(1.f + erff(m*0.70710678118654752f));
        const float* w2 = pf2 + j*64;
#pragma unroll
        for (int c = 0; c < 64; ++c) acc[c] += g * w2[c];
    }
#pragma unroll
    for (int c = 0; c < 64; ++c) base[c*HW256] = acc[c];
}

// ---------------------------------------------------------------------------
extern "C" void kernel_launch(void* const* d_in, const int* in_sizes, int n_in,
                              void* d_out, int out_size, void* d_ws, size_t ws_size,
                              hipStream_t stream)
{
    (void)in_sizes; (void)n_in; (void)out_size; (void)ws_size;
    const float* x    = (const float*)d_in[0];
    const float* w7a  = (const float*)d_in[1];
    const float* b7a  = (const float*)d_in[2];
    const float* w1   = (const float*)d_in[3];
    const float* b1   = (const float*)d_in[4];
    const float* g1   = (const float*)d_in[5];
    const float* be1  = (const float*)d_in[6];
    const float* w3a  = (const float*)d_in[7];
    const float* b3a  = (const float*)d_in[8];
    const float* g3a  = (const float*)d_in[9];
    const float* be3a = (const float*)d_in[10];
    const float* w3b  = (const float*)d_in[11];
    const float* b3b  = (const float*)d_in[12];
    const float* g3b  = (const float*)d_in[13];
    const float* be3b = (const float*)d_in[14];
    const float* w3c  = (const float*)d_in[15];
    const float* b3c  = (const float*)d_in[16];
    const float* g3c  = (const float*)d_in[17];
    const float* be3c = (const float*)d_in[18];
    const float* w7b  = (const float*)d_in[19];
    const float* b7b  = (const float*)d_in[20];
    const float* akw  = (const float*)d_in[21];
    const float* akb  = (const float*)d_in[22];
    const float* avw  = (const float*)d_in[25];
    const float* avb  = (const float*)d_in[26];
    const float* arw  = (const float*)d_in[27];
    const float* arb  = (const float*)d_in[28];
    const float* lng  = (const float*)d_in[29];
    const float* lnb  = (const float*)d_in[30];
    const float* fc1w = (const float*)d_in[31];
    const float* fc1b = (const float*)d_in[32];
    const float* fc2w = (const float*)d_in[33];
    const float* fc2b = (const float*)d_in[34];

    float* ws   = (float*)d_ws;
    float* o_y2 = ws;                       // 2,097,152
    float* o_y  = o_y2 + 2097152;           // 8,388,608
    float* o_z1 = o_y  + 8388608;           // 8,388,608
    float* o_z2 = o_z1 + 8388608;           // 8,388,608
    float* o_k  = o_z2 + 8388608;           // 524,288
    float* o_st = o_k  + 524288;            // 64
    float* o_S  = o_st + 64;                // 512
    float* o_ad = o_S  + 512;               // 512
    float* p7a  = o_ad + 512;               // 50,176
    float* p1   = p7a  + 50176;             // 256
    float* p3a  = p1   + 256;   float* q3a = p3a + 2304;
    float* p3b  = q3a  + 16;    float* q3b = p3b + 2304;
    float* p3c  = q3b  + 16;    float* q3c = p3c + 2304;
    float* p7b  = q3c  + 16;                // 50,176
    float* pf2  = p7b  + 50176;             // 4,096

    float* out0 = (float*)d_out;

    prepack<<<196, 256, 0, stream>>>(w7a, w1, w3a,b3a,g3a,be3a, w3b,b3b,g3b,be3b,
                                     w3c,b3c,g3c,be3c, w7b, fc2w,
                                     p7a, p1, p3a,q3a, p3b,q3b, p3c,q3c, p7b, pf2);
    conv7a_1x1_bn<<<dim3(8,8,8), dim3(16,16), 0, stream>>>(x, p7a, b7a, p1, b1, g1, be1, o_y2);
    resize_128_256<<<dim3(16,16,128), dim3(16,16), 0, stream>>>(o_y2, o_y);
    conv3x3_bn<0><<<dim3(16,16,8), dim3(16,16), 0, stream>>>(o_y,  p3a, q3a, nullptr, o_z1);
    conv3x3_bn<1><<<dim3(16,16,8), dim3(16,16), 0, stream>>>(o_z1, p3b, q3b, o_y,     o_z2);
    conv3x3_bn<1><<<dim3(16,16,8), dim3(16,16), 0, stream>>>(o_z2, p3c, q3c, o_y,     o_z1);
    conv7b_ident_k<<<dim3(16,16,8), dim3(16,16), 0, stream>>>(o_z1, p7b, b7b, x, akw, akb, out0, o_k);
    softmax_stats<<<8, 1024, 0, stream>>>(o_k, o_st);
    att_wsum<<<dim3(8,8), 256, 0, stream>>>(out0, o_k, o_st, o_S);
    ctx_addc<<<1, 512, 0, stream>>>(o_S, o_st, avw, avb, arw, arb, o_ad);
    transformer<<<2048, 256, 0, stream>>>(out0, o_ad, lng, lnb, fc1w, fc1b, pf2, fc2b);
}

// Round 4
// 2088.095 us; speedup vs baseline: 1.7105x; 1.7105x over previous
//
#include <hip/hip_runtime.h>
#include <math.h>

#define DI __device__ __forceinline__
#define HW128 (128*128)
#define HW256 (256*256)

__device__ const float BN_RS = 0.9999950000374997f; // 1/sqrt(1+1e-5)

DI float leakyf(float x){ return x >= 0.f ? x : 0.2f*x; }

DI unsigned short f2bf(float f){
    unsigned u = __float_as_uint(f);
    return (unsigned short)((u + 0x7fffu + ((u >> 16) & 1u)) >> 16);
}

typedef __attribute__((ext_vector_type(8))) short short8v;
typedef __attribute__((ext_vector_type(4))) float float4v;

// ---------------------------------------------------------------------------
// Prepack: [ic][tap][oc] layouts for VALU convs; bf16 [kstep][oc][k=32] for
// the MFMA 7x7 conv (kstep = ky*4 + kxpair, k = (kx&1)*16 + ic, kx=7 zero-pad);
// fold BN into 3x3 weights; transpose fc2.
// ---------------------------------------------------------------------------
__global__ __launch_bounds__(256) void prepack(
    const float* __restrict__ w7a, const float* __restrict__ w1,
    const float* __restrict__ w3a, const float* __restrict__ b3a, const float* __restrict__ g3a, const float* __restrict__ be3a,
    const float* __restrict__ w3b, const float* __restrict__ b3b, const float* __restrict__ g3b, const float* __restrict__ be3b,
    const float* __restrict__ w3c, const float* __restrict__ b3c, const float* __restrict__ g3c, const float* __restrict__ be3c,
    const float* __restrict__ w7b, const float* __restrict__ fc2w,
    float* __restrict__ p7a, float* __restrict__ p1,
    float* __restrict__ p3a, float* __restrict__ q3a,
    float* __restrict__ p3b, float* __restrict__ q3b,
    float* __restrict__ p3c, float* __restrict__ q3c,
    unsigned short* __restrict__ pwB, float* __restrict__ pf2)
{
    int i = blockIdx.x * 256 + threadIdx.x;
    if (i < 50176) {
        int oc = i & 15,  t = (i >> 4) % 49, ic = (i >> 4) / 49;
        p7a[i] = w7a[(oc*64 + ic)*49 + t];               // w7a: (16,64,7,7)
    }
    if (i < 57344) {                                      // MFMA weights, bf16
        int ks = i >> 11;            // 0..27
        int oc = (i >> 5) & 63;
        int k  = i & 31;
        int ky = ks >> 2;
        int kx = ((ks & 3) << 1) + (k >> 4);
        int ic = k & 15;
        pwB[i] = (kx < 7) ? f2bf(w7b[((oc*16 + ic)*7 + ky)*7 + kx]) : (unsigned short)0;
    }
    if (i < 256) { int oc = i & 15, ic = i >> 4; p1[i] = w1[oc*16 + ic]; }
    if (i < 2304) {
        int oc = i & 15, t = (i >> 4) % 9, ic = (i >> 4) / 9;
        int src = (oc*16 + ic)*9 + t;
        p3a[i] = w3a[src] * (g3a[oc]*BN_RS);
        p3b[i] = w3b[src] * (g3b[oc]*BN_RS);
        p3c[i] = w3c[src] * (g3c[oc]*BN_RS);
    }
    if (i < 16) {
        q3a[i] = b3a[i]*(g3a[i]*BN_RS) + be3a[i];
        q3b[i] = b3b[i]*(g3b[i]*BN_RS) + be3b[i];
        q3c[i] = b3c[i]*(g3c[i]*BN_RS) + be3c[i];
    }
    if (i < 4096) { int j = i >> 6, c = i & 63; pf2[i] = fc2w[c*64 + j]; } // fc2^T
}

// ---------------------------------------------------------------------------
// Stage A+B: conv7x7(64->16) -> leaky -> conv1x1(16->16) -> leaky -> BN
// ---------------------------------------------------------------------------
__global__ __launch_bounds__(256) void conv7a_1x1_bn(
    const float* __restrict__ x, const float* __restrict__ p7a,
    const float* __restrict__ b7a, const float* __restrict__ p1,
    const float* __restrict__ b1, const float* __restrict__ bng,
    const float* __restrict__ bnb, float* __restrict__ y2)
{
    __shared__ float tile[8][22][22];
    const int tx = threadIdx.x, ty = threadIdx.y;
    const int n = blockIdx.z, ox = blockIdx.x*16, oy = blockIdx.y*16;
    const int tid = ty*16 + tx;
    float acc[16];
#pragma unroll
    for (int o = 0; o < 16; ++o) acc[o] = 0.f;

    for (int icc = 0; icc < 64; icc += 8) {
        __syncthreads();
        for (int i = tid; i < 8*22*22; i += 256) {
            int ic = i / 484; int rem = i - ic*484;
            int r = rem / 22; int cc = rem - r*22;
            int iy = oy + r - 3, ix = ox + cc - 3;
            float v = 0.f;
            if (iy >= 0 && iy < 128 && ix >= 0 && ix < 128)
                v = x[((n*64 + icc + ic)*128 + iy)*128 + ix];
            tile[ic][r][cc] = v;
        }
        __syncthreads();
        for (int ic = 0; ic < 8; ++ic) {
            const float* wrow = p7a + (icc + ic)*49*16;
            for (int ky = 0; ky < 7; ++ky) {
#pragma unroll
                for (int kx = 0; kx < 7; ++kx) {
                    float v = tile[ic][ty + ky][tx + kx];
                    const float* w = wrow + (ky*7 + kx)*16;
#pragma unroll
                    for (int o = 0; o < 16; ++o) acc[o] += v * w[o];
                }
            }
        }
    }
    float l[16];
#pragma unroll
    for (int o = 0; o < 16; ++o) l[o] = leakyf(acc[o] + b7a[o]);
    const int p = (oy + ty)*128 + (ox + tx);
#pragma unroll
    for (int o = 0; o < 16; ++o) {
        float u = b1[o];
#pragma unroll
        for (int ic = 0; ic < 16; ++ic) u += l[ic] * p1[ic*16 + o];
        u = leakyf(u);
        u = u * (bng[o]*BN_RS) + bnb[o];
        y2[(n*16 + o)*HW128 + p] = u;
    }
}

// ---------------------------------------------------------------------------
// Bilinear resize 128->256, align_corners=True.
// ---------------------------------------------------------------------------
__global__ __launch_bounds__(256) void resize_128_256(
    const float* __restrict__ in, float* __restrict__ out)
{
    int nc = blockIdx.z;
    int ox = blockIdx.x*16 + threadIdx.x;
    int oy = blockIdx.y*16 + threadIdx.y;
    float sy = oy * (127.f/255.f), sx = ox * (127.f/255.f);
    int y0 = min((int)sy, 126), x0 = min((int)sx, 126);
    float fy = sy - y0, fx = sx - x0;
    const float* b = in + nc*HW128;
    float v00 = b[y0*128 + x0],       v01 = b[y0*128 + x0 + 1];
    float v10 = b[y0*128 + 128 + x0], v11 = b[y0*128 + 128 + x0 + 1];
    float top = v00*(1.f-fx) + v01*fx;
    float bot = v10*(1.f-fx) + v11*fx;
    out[nc*HW256 + oy*256 + ox] = top*(1.f-fy) + bot*fy;
}

// ---------------------------------------------------------------------------
// 3x3 conv 16->16 with pre-folded BN.
// MODE 0: leaky -> f32 out.  MODE 1: +res -> f32 out.
// MODE 2: +res -> bf16 channel-inner out ci[n][p][ic16] (for MFMA conv).
// ---------------------------------------------------------------------------
template<int MODE>
__global__ __launch_bounds__(256) void conv3x3_bn(
    const float* __restrict__ in, const float* __restrict__ pw,
    const float* __restrict__ pb, const float* __restrict__ res,
    float* __restrict__ out, unsigned short* __restrict__ ci)
{
    __shared__ float tile[16][18][18];
    const int tx = threadIdx.x, ty = threadIdx.y;
    const int n = blockIdx.z, ox = blockIdx.x*16, oy = blockIdx.y*16;
    const int tid = ty*16 + tx;
    for (int i = tid; i < 16*18*18; i += 256) {
        int ic = i / 324; int rem = i - ic*324;
        int r = rem / 18; int cc = rem - r*18;
        int iy = oy + r - 1, ix = ox + cc - 1;
        float v = 0.f;
        if (iy >= 0 && iy < 256 && ix >= 0 && ix < 256)
            v = in[((n*16 + ic)*256 + iy)*256 + ix];
        tile[ic][r][cc] = v;
    }
    __syncthreads();
    float acc[16];
#pragma unroll
    for (int o = 0; o < 16; ++o) acc[o] = pb[o];
    for (int ic = 0; ic < 16; ++ic) {
#pragma unroll
        for (int ky = 0; ky < 3; ++ky) {
#pragma unroll
            for (int kx = 0; kx < 3; ++kx) {
                float v = tile[ic][ty + ky][tx + kx];
                const float* w = pw + (ic*9 + ky*3 + kx)*16;
#pragma unroll
                for (int o = 0; o < 16; ++o) acc[o] += v * w[o];
            }
        }
    }
    const int p = (oy + ty)*256 + (ox + tx);
    if (MODE == 0) {
#pragma unroll
        for (int o = 0; o < 16; ++o) out[(n*16 + o)*HW256 + p] = leakyf(acc[o]);
    } else if (MODE == 1) {
#pragma unroll
        for (int o = 0; o < 16; ++o)
            out[(n*16 + o)*HW256 + p] = acc[o] + res[(n*16 + o)*HW256 + p];
    } else {
        unsigned int q[8];
#pragma unroll
        for (int h = 0; h < 8; ++h) {
            float a0 = acc[2*h]     + res[(n*16 + 2*h)*HW256 + p];
            float a1 = acc[2*h + 1] + res[(n*16 + 2*h + 1)*HW256 + p];
            q[h] = (unsigned)f2bf(a0) | ((unsigned)f2bf(a1) << 16);
        }
        uint4* dst = (uint4*)ci + (size_t)(n*65536 + p)*2;
        dst[0] = make_uint4(q[0], q[1], q[2], q[3]);
        dst[1] = make_uint4(q[4], q[5], q[6], q[7]);
    }
}

// ---------------------------------------------------------------------------
// conv7x7 16->64 via MFMA implicit GEMM.
// z_ci: bf16 [n][256][256][16].  LDS tile [22 rows][24 cols][16 ic] bf16.
// K = 7 ky * 4 kx-pairs * (2 kx * 16 ic = 32) = 28 MFMA K-steps.
// A-frag: lane reads 8 contiguous bf16 (ds_read_b128); spans 2 adjacent taps.
// Block: 16x16 pixels x 64 oc; 4 waves, each 4 Mtiles(y-rows) x 4 Ntiles.
// Writes conv-only result (no bias) to out0 [n][oc][y][x].
// ---------------------------------------------------------------------------
__global__ __launch_bounds__(256) void conv7b_mfma(
    const unsigned short* __restrict__ z_ci,
    const unsigned short* __restrict__ pwB,
    float* __restrict__ out0)
{
    __shared__ __align__(16) unsigned short tile[22*24*16]; // 16,896 B
    const int tid = threadIdx.x;
    const int n = blockIdx.z, ox = blockIdx.x*16, oy = blockIdx.y*16;

    // stage: 22 rows x 48 x 16B units, linear LDS, bounds-checked
    const uint4* zc = (const uint4*)z_ci;
    uint4* tl4 = (uint4*)tile;
    for (int u = tid; u < 1056; u += 256) {
        int r = u / 48, s = u - r*48;
        int y = oy + r - 3, xcol = ox + (s >> 1) - 3;
        uint4 v = make_uint4(0u, 0u, 0u, 0u);
        if (y >= 0 && y < 256 && xcol >= 0 && xcol < 256)
            v = zc[(size_t)((n*256 + y)*256 + xcol)*2 + (s & 1)];
        tl4[u] = v;
    }
    __syncthreads();

    const int w = tid >> 6, l = tid & 63;
    const int lg = l >> 4, ln = l & 15;
    float4v acc[4][4];
#pragma unroll
    for (int mi = 0; mi < 4; ++mi)
#pragma unroll
        for (int nt = 0; nt < 4; ++nt)
            acc[mi][nt] = (float4v){0.f, 0.f, 0.f, 0.f};

    const short8v* Bb = (const short8v*)pwB;   // 16B units: [ks*256 + nt*64 + ln*4 + lg]
    for (int ks = 0; ks < 28; ++ks) {
        const int ky = ks >> 2, kxp = (ks & 3) << 1;
        short8v a[4], b[4];
#pragma unroll
        for (int mi = 0; mi < 4; ++mi) {
            int row = (4*w + mi) + ky;                      // py + ky
            int off = (row*24 + ln + kxp)*16 + lg*8;        // shorts (16B aligned)
            a[mi] = *(const short8v*)(tile + off);
        }
#pragma unroll
        for (int nt = 0; nt < 4; ++nt)
            b[nt] = Bb[ks*256 + nt*64 + ln*4 + lg];
#pragma unroll
        for (int mi = 0; mi < 4; ++mi)
#pragma unroll
            for (int nt = 0; nt < 4; ++nt)
                acc[mi][nt] = __builtin_amdgcn_mfma_f32_16x16x32_bf16(
                    a[mi], b[nt], acc[mi][nt], 0, 0, 0);
    }

    // store: C lane holds col(oc)=ln, rows(px)=lg*4+0..3 -> dwordx4 per tile
#pragma unroll
    for (int mi = 0; mi < 4; ++mi) {
        const int yy = oy + 4*w + mi;
#pragma unroll
        for (int nt = 0; nt < 4; ++nt) {
            const int oc = nt*16 + ln;
            float* dst = out0 + (size_t)(n*64 + oc)*HW256 + yy*256 + ox + lg*4;
            *(float4v*)dst = acc[mi][nt];
        }
    }
}

// ---------------------------------------------------------------------------
// Epilogue: out0 += bias + bilinear(x); emit attention key logit k.
// ---------------------------------------------------------------------------
__global__ __launch_bounds__(256) void bilin_k(
    float* __restrict__ out0, const float* __restrict__ x,
    const float* __restrict__ bias,
    const float* __restrict__ akw, const float* __restrict__ akb,
    float* __restrict__ kbuf)
{
    const int tx = threadIdx.x, ty = threadIdx.y;
    const int n = blockIdx.z;
    const int ohx = blockIdx.x*16 + tx, ohy = blockIdx.y*16 + ty;
    float sy = ohy * (127.f/255.f), sx = ohx * (127.f/255.f);
    int y0 = min((int)sy, 126), x0 = min((int)sx, 126);
    float fy = sy - y0, fx = sx - x0;
    const float* xb = x + n*64*HW128;
    const int p = ohy*256 + ohx;
    float kacc = akb[0];
#pragma unroll
    for (int o = 0; o < 64; ++o) {
        const float* xc = xb + o*HW128;
        float v00 = xc[y0*128 + x0],       v01 = xc[y0*128 + x0 + 1];
        float v10 = xc[y0*128 + 128 + x0], v11 = xc[y0*128 + 128 + x0 + 1];
        float idv = (v00*(1.f-fx) + v01*fx)*(1.f-fy) + (v10*(1.f-fx) + v11*fx)*fy;
        size_t idx = (size_t)(n*64 + o)*HW256 + p;
        float u = out0[idx] + bias[o] + idv;
        out0[idx] = u;
        kacc += akw[o] * u;
    }
    kbuf[n*65536 + p] = kacc;
}

// ---------------------------------------------------------------------------
// Softmax stats per image.
// ---------------------------------------------------------------------------
__global__ __launch_bounds__(1024) void softmax_stats(
    const float* __restrict__ kb, float* __restrict__ st)
{
    __shared__ float red[16];
    __shared__ float bc;
    const int n = blockIdx.x, tid = threadIdx.x;
    const float* kp = kb + n*65536;
    float mx = -3.0e38f;
    for (int i = tid; i < 65536; i += 1024) mx = fmaxf(mx, kp[i]);
#pragma unroll
    for (int off = 1; off < 64; off <<= 1) mx = fmaxf(mx, __shfl_xor(mx, off));
    int w = tid >> 6, l = tid & 63;
    if (l == 0) red[w] = mx;
    __syncthreads();
    if (tid == 0) {
        float m = red[0];
        for (int i = 1; i < 16; ++i) m = fmaxf(m, red[i]);
        bc = m;
    }
    __syncthreads();
    float MX = bc;
    float s = 0.f;
    for (int i = tid; i < 65536; i += 1024) s += __expf(kp[i] - MX);
#pragma unroll
    for (int off = 1; off < 64; off <<= 1) s += __shfl_xor(s, off);
    __syncthreads();
    if (l == 0) red[w] = s;
    __syncthreads();
    if (tid == 0) {
        float S = 0.f;
        for (int i = 0; i < 16; ++i) S += red[i];
        st[n] = MX; st[8 + n] = 1.f / S;
    }
}

// ---------------------------------------------------------------------------
// S[n,c] = sum_p exp(k-mx) * out0[n,c,p].
// ---------------------------------------------------------------------------
__global__ __launch_bounds__(256) void att_wsum(
    const float* __restrict__ out0, const float* __restrict__ kb,
    const float* __restrict__ st, float* __restrict__ S)
{
    const int cg = blockIdx.x, n = blockIdx.y, c0 = cg*8;
    const float mx = st[n];
    const float* kp = kb + n*65536;
    const float* base = out0 + (size_t)(n*64 + c0)*HW256;
    float acc[8];
#pragma unroll
    for (int c = 0; c < 8; ++c) acc[c] = 0.f;
    for (int p = threadIdx.x; p < 65536; p += 256) {
        float e = __expf(kp[p] - mx);
#pragma unroll
        for (int c = 0; c < 8; ++c) acc[c] += e * base[c*HW256 + p];
    }
#pragma unroll
    for (int c = 0; c < 8; ++c)
#pragma unroll
        for (int off = 1; off < 64; off <<= 1) acc[c] += __shfl_xor(acc[c], off);
    __shared__ float red[4][8];
    int w = threadIdx.x >> 6, l = threadIdx.x & 63;
    if (l == 0) {
#pragma unroll
        for (int c = 0; c < 8; ++c) red[w][c] = acc[c];
    }
    __syncthreads();
    if (threadIdx.x < 8)
        S[n*64 + c0 + threadIdx.x] =
            red[0][threadIdx.x] + red[1][threadIdx.x] + red[2][threadIdx.x] + red[3][threadIdx.x];
}

// ---------------------------------------------------------------------------
// context + per-(n,c) attention addend.
// ---------------------------------------------------------------------------
__global__ __launch_bounds__(512) void ctx_addc(
    const float* __restrict__ S, const float* __restrict__ st,
    const float* __restrict__ avw, const float* __restrict__ avb,
    const float* __restrict__ arw, const float* __restrict__ arb,
    float* __restrict__ addc)
{
    __shared__ float ctx[8][8];
    const int tid = threadIdx.x;
    if (tid < 64) {
        int n = tid >> 3, vc = tid & 7;
        float s = 0.f;
        for (int c = 0; c < 64; ++c) s += avw[vc*64 + c] * S[n*64 + c];
        ctx[n][vc] = s * st[8 + n] + avb[vc];
    }
    __syncthreads();
    int n = tid >> 6, c = tid & 63;
    float a = arb[c];
#pragma unroll
    for (int vc = 0; vc < 8; ++vc) a += arw[c*8 + vc] * ctx[n][vc];
    addc[n*64 + c] = a;
}

// ---------------------------------------------------------------------------
// Transformer (in place on d_out).
// ---------------------------------------------------------------------------
__global__ __launch_bounds__(256) void transformer(
    float* __restrict__ out0, const float* __restrict__ addc,
    const float* __restrict__ lng, const float* __restrict__ lnb,
    const float* __restrict__ fc1w, const float* __restrict__ fc1b,
    const float* __restrict__ pf2, const float* __restrict__ fc2b)
{
    const int id = blockIdx.x*256 + threadIdx.x;
    const int n = id >> 16, p = id & 65535;
    float* base = out0 + (size_t)n*64*HW256 + p;
    const float* ac = addc + n*64;
    float t[64];
#pragma unroll
    for (int c = 0; c < 64; ++c) t[c] = base[c*HW256] + ac[c];
    float mu = 0.f;
#pragma unroll
    for (int c = 0; c < 64; ++c) mu += t[c];
    mu *= (1.f/64.f);
    float var = 0.f;
#pragma unroll
    for (int c = 0; c < 64; ++c) { float d = t[c] - mu; var += d*d; }
    var *= (1.f/64.f);
    float rs = rsqrtf(var + 1e-5f);
    float acc[64];
#pragma unroll
    for (int c = 0; c < 64; ++c) {
        acc[c] = t[c] + fc2b[c];
        t[c] = (t[c] - mu)*rs*lng[c] + lnb[c];
    }
    for (int j = 0; j < 64; ++j) {
        float m = fc1b[j];
#pragma unroll
        for (int i = 0; i < 64; ++i) m += t[i] * fc1w[j*64 + i];
        float g = 0.5f*m*(1.f + erff(m*0.70710678118654752f));
        const float* w2 = pf2 + j*64;
#pragma unroll
        for (int c = 0; c < 64; ++c) acc[c] += g * w2[c];
    }
#pragma unroll
    for (int c = 0; c < 64; ++c) base[c*HW256] = acc[c];
}

// ---------------------------------------------------------------------------
extern "C" void kernel_launch(void* const* d_in, const int* in_sizes, int n_in,
                              void* d_out, int out_size, void* d_ws, size_t ws_size,
                              hipStream_t stream)
{
    (void)in_sizes; (void)n_in; (void)out_size; (void)ws_size;
    const float* x    = (const float*)d_in[0];
    const float* w7a  = (const float*)d_in[1];
    const float* b7a  = (const float*)d_in[2];
    const float* w1   = (const float*)d_in[3];
    const float* b1   = (const float*)d_in[4];
    const float* g1   = (const float*)d_in[5];
    const float* be1  = (const float*)d_in[6];
    const float* w3a  = (const float*)d_in[7];
    const float* b3a  = (const float*)d_in[8];
    const float* g3a  = (const float*)d_in[9];
    const float* be3a = (const float*)d_in[10];
    const float* w3b  = (const float*)d_in[11];
    const float* b3b  = (const float*)d_in[12];
    const float* g3b  = (const float*)d_in[13];
    const float* be3b = (const float*)d_in[14];
    const float* w3c  = (const float*)d_in[15];
    const float* b3c  = (const float*)d_in[16];
    const float* g3c  = (const float*)d_in[17];
    const float* be3c = (const float*)d_in[18];
    const float* w7b  = (const float*)d_in[19];
    const float* b7b  = (const float*)d_in[20];
    const float* akw  = (const float*)d_in[21];
    const float* akb  = (const float*)d_in[22];
    const float* avw  = (const float*)d_in[25];
    const float* avb  = (const float*)d_in[26];
    const float* arw  = (const float*)d_in[27];
    const float* arb  = (const float*)d_in[28];
    const float* lng  = (const float*)d_in[29];
    const float* lnb  = (const float*)d_in[30];
    const float* fc1w = (const float*)d_in[31];
    const float* fc1b = (const float*)d_in[32];
    const float* fc2w = (const float*)d_in[33];
    const float* fc2b = (const float*)d_in[34];

    float* ws   = (float*)d_ws;
    float* o_y2 = ws;                       // 2,097,152
    float* o_y  = o_y2 + 2097152;           // 8,388,608
    float* o_z1 = o_y  + 8388608;           // 8,388,608 (f32 z1; later bf16 z_ci)
    float* o_z2 = o_z1 + 8388608;           // 8,388,608
    float* o_k  = o_z2 + 8388608;           // 524,288
    float* o_st = o_k  + 524288;            // 64
    float* o_S  = o_st + 64;                // 512
    float* o_ad = o_S  + 512;               // 512
    float* p7a  = o_ad + 512;               // 50,176
    float* p1   = p7a  + 50176;             // 256
    float* p3a  = p1   + 256;   float* q3a = p3a + 2304;
    float* p3b  = q3a  + 16;    float* q3b = p3b + 2304;
    float* p3c  = q3b  + 16;    float* q3c = p3c + 2304;
    unsigned short* pwB = (unsigned short*)(q3c + 16);   // 57,344 bf16 (in old p7b slot: 50,176 f32)
    float* pf2  = (q3c + 16) + 50176;       // 4,096

    unsigned short* z_ci = (unsigned short*)o_z1;  // bf16 [8][256][256][16] = 16.8 MB

    float* out0 = (float*)d_out;

    prepack<<<224, 256, 0, stream>>>(w7a, w1, w3a,b3a,g3a,be3a, w3b,b3b,g3b,be3b,
                                     w3c,b3c,g3c,be3c, w7b, fc2w,
                                     p7a, p1, p3a,q3a, p3b,q3b, p3c,q3c, pwB, pf2);
    conv7a_1x1_bn<<<dim3(8,8,8), dim3(16,16), 0, stream>>>(x, p7a, b7a, p1, b1, g1, be1, o_y2);
    resize_128_256<<<dim3(16,16,128), dim3(16,16), 0, stream>>>(o_y2, o_y);
    conv3x3_bn<0><<<dim3(16,16,8), dim3(16,16), 0, stream>>>(o_y,  p3a, q3a, nullptr, o_z1, nullptr);
    conv3x3_bn<1><<<dim3(16,16,8), dim3(16,16), 0, stream>>>(o_z1, p3b, q3b, o_y,     o_z2, nullptr);
    conv3x3_bn<2><<<dim3(16,16,8), dim3(16,16), 0, stream>>>(o_z2, p3c, q3c, o_y,     nullptr, z_ci);
    conv7b_mfma<<<dim3(16,16,8), 256, 0, stream>>>(z_ci, pwB, out0);
    bilin_k<<<dim3(16,16,8), dim3(16,16), 0, stream>>>(out0, x, b7b, akw, akb, o_k);
    softmax_stats<<<8, 1024, 0, stream>>>(o_k, o_st);
    att_wsum<<<dim3(8,8), 256, 0, stream>>>(out0, o_k, o_st, o_S);
    ctx_addc<<<1, 512, 0, stream>>>(o_S, o_st, avw, avb, arw, arb, o_ad);
    transformer<<<2048, 256, 0, stream>>>(out0, o_ad, lng, lnb, fc1w, fc1b, pf2, fc2b);
}

// Round 5
// 1059.625 us; speedup vs baseline: 3.3707x; 1.9706x over previous
//
#include <hip/hip_runtime.h>
#include <math.h>

#define DI __device__ __forceinline__
#define HW128 (128*128)
#define HW256 (256*256)

__device__ const float BN_RS = 0.9999950000374997f; // 1/sqrt(1+1e-5)

DI float leakyf(float x){ return x >= 0.f ? x : 0.2f*x; }

DI unsigned short f2bf(float f){
    unsigned u = __float_as_uint(f);
    return (unsigned short)((u + 0x7fffu + ((u >> 16) & 1u)) >> 16);
}

typedef __attribute__((ext_vector_type(8))) short short8v;
typedef __attribute__((ext_vector_type(4))) float float4v;

// ---------------------------------------------------------------------------
// Prepack: [ic][tap][oc] layouts for VALU convs; bf16 [kstep][oc][k=32] for
// the MFMA 7x7 conv; bf16 fc1/fc2 for the MFMA transformer; fold BN into 3x3.
// ---------------------------------------------------------------------------
__global__ __launch_bounds__(256) void prepack(
    const float* __restrict__ w7a, const float* __restrict__ w1,
    const float* __restrict__ w3a, const float* __restrict__ b3a, const float* __restrict__ g3a, const float* __restrict__ be3a,
    const float* __restrict__ w3b, const float* __restrict__ b3b, const float* __restrict__ g3b, const float* __restrict__ be3b,
    const float* __restrict__ w3c, const float* __restrict__ b3c, const float* __restrict__ g3c, const float* __restrict__ be3c,
    const float* __restrict__ w7b, const float* __restrict__ fc1w, const float* __restrict__ fc2w,
    float* __restrict__ p7a, float* __restrict__ p1,
    float* __restrict__ p3a, float* __restrict__ q3a,
    float* __restrict__ p3b, float* __restrict__ q3b,
    float* __restrict__ p3c, float* __restrict__ q3c,
    unsigned short* __restrict__ pwB,
    unsigned short* __restrict__ pwT1, unsigned short* __restrict__ pwT2)
{
    int i = blockIdx.x * 256 + threadIdx.x;
    if (i < 50176) {
        int oc = i & 15,  t = (i >> 4) % 49, ic = (i >> 4) / 49;
        p7a[i] = w7a[(oc*64 + ic)*49 + t];               // w7a: (16,64,7,7)
    }
    if (i < 57344) {                                      // MFMA conv weights, bf16
        int ks = i >> 11;            // 0..27
        int oc = (i >> 5) & 63;
        int k  = i & 31;
        int ky = ks >> 2;
        int kx = ((ks & 3) << 1) + (k >> 4);
        int ic = k & 15;
        pwB[i] = (kx < 7) ? f2bf(w7b[((oc*16 + ic)*7 + ky)*7 + kx]) : (unsigned short)0;
    }
    if (i < 256) { int oc = i & 15, ic = i >> 4; p1[i] = w1[oc*16 + ic]; }
    if (i < 2304) {
        int oc = i & 15, t = (i >> 4) % 9, ic = (i >> 4) / 9;
        int src = (oc*16 + ic)*9 + t;
        p3a[i] = w3a[src] * (g3a[oc]*BN_RS);
        p3b[i] = w3b[src] * (g3b[oc]*BN_RS);
        p3c[i] = w3c[src] * (g3c[oc]*BN_RS);
    }
    if (i < 16) {
        q3a[i] = b3a[i]*(g3a[i]*BN_RS) + be3a[i];
        q3b[i] = b3b[i]*(g3b[i]*BN_RS) + be3b[i];
        q3c[i] = b3c[i]*(g3c[i]*BN_RS) + be3c[i];
    }
    // transformer weights: W1b[col=j][k=i] = fc1w[j][i]; W2b[col=c][k=j] = fc2w[c][j]
    if (i < 4096) { pwT1[i] = f2bf(fc1w[i]); pwT2[i] = f2bf(fc2w[i]); }
}

// ---------------------------------------------------------------------------
// Stage A+B: conv7x7(64->16) -> leaky -> conv1x1(16->16) -> leaky -> BN
// ---------------------------------------------------------------------------
__global__ __launch_bounds__(256) void conv7a_1x1_bn(
    const float* __restrict__ x, const float* __restrict__ p7a,
    const float* __restrict__ b7a, const float* __restrict__ p1,
    const float* __restrict__ b1, const float* __restrict__ bng,
    const float* __restrict__ bnb, float* __restrict__ y2)
{
    __shared__ float tile[8][22][22];
    const int tx = threadIdx.x, ty = threadIdx.y;
    const int n = blockIdx.z, ox = blockIdx.x*16, oy = blockIdx.y*16;
    const int tid = ty*16 + tx;
    float acc[16];
#pragma unroll
    for (int o = 0; o < 16; ++o) acc[o] = 0.f;

    for (int icc = 0; icc < 64; icc += 8) {
        __syncthreads();
        for (int i = tid; i < 8*22*22; i += 256) {
            int ic = i / 484; int rem = i - ic*484;
            int r = rem / 22; int cc = rem - r*22;
            int iy = oy + r - 3, ix = ox + cc - 3;
            float v = 0.f;
            if (iy >= 0 && iy < 128 && ix >= 0 && ix < 128)
                v = x[((n*64 + icc + ic)*128 + iy)*128 + ix];
            tile[ic][r][cc] = v;
        }
        __syncthreads();
        for (int ic = 0; ic < 8; ++ic) {
            const float* wrow = p7a + (icc + ic)*49*16;
            for (int ky = 0; ky < 7; ++ky) {
#pragma unroll
                for (int kx = 0; kx < 7; ++kx) {
                    float v = tile[ic][ty + ky][tx + kx];
                    const float* w = wrow + (ky*7 + kx)*16;
#pragma unroll
                    for (int o = 0; o < 16; ++o) acc[o] += v * w[o];
                }
            }
        }
    }
    float l[16];
#pragma unroll
    for (int o = 0; o < 16; ++o) l[o] = leakyf(acc[o] + b7a[o]);
    const int p = (oy + ty)*128 + (ox + tx);
#pragma unroll
    for (int o = 0; o < 16; ++o) {
        float u = b1[o];
#pragma unroll
        for (int ic = 0; ic < 16; ++ic) u += l[ic] * p1[ic*16 + o];
        u = leakyf(u);
        u = u * (bng[o]*BN_RS) + bnb[o];
        y2[(n*16 + o)*HW128 + p] = u;
    }
}

// ---------------------------------------------------------------------------
// Bilinear resize 128->256, align_corners=True.
// ---------------------------------------------------------------------------
__global__ __launch_bounds__(256) void resize_128_256(
    const float* __restrict__ in, float* __restrict__ out)
{
    int nc = blockIdx.z;
    int ox = blockIdx.x*16 + threadIdx.x;
    int oy = blockIdx.y*16 + threadIdx.y;
    float sy = oy * (127.f/255.f), sx = ox * (127.f/255.f);
    int y0 = min((int)sy, 126), x0 = min((int)sx, 126);
    float fy = sy - y0, fx = sx - x0;
    const float* b = in + nc*HW128;
    float v00 = b[y0*128 + x0],       v01 = b[y0*128 + x0 + 1];
    float v10 = b[y0*128 + 128 + x0], v11 = b[y0*128 + 128 + x0 + 1];
    float top = v00*(1.f-fx) + v01*fx;
    float bot = v10*(1.f-fx) + v11*fx;
    out[nc*HW256 + oy*256 + ox] = top*(1.f-fy) + bot*fy;
}

// ---------------------------------------------------------------------------
// 3x3 conv 16->16 with pre-folded BN.
// MODE 0: leaky -> f32 out.  MODE 1: +res -> f32 out.
// MODE 2: +res -> bf16 channel-inner out ci[n][p][ic16] (for MFMA conv).
// ---------------------------------------------------------------------------
template<int MODE>
__global__ __launch_bounds__(256) void conv3x3_bn(
    const float* __restrict__ in, const float* __restrict__ pw,
    const float* __restrict__ pb, const float* __restrict__ res,
    float* __restrict__ out, unsigned short* __restrict__ ci)
{
    __shared__ float tile[16][18][18];
    const int tx = threadIdx.x, ty = threadIdx.y;
    const int n = blockIdx.z, ox = blockIdx.x*16, oy = blockIdx.y*16;
    const int tid = ty*16 + tx;
    for (int i = tid; i < 16*18*18; i += 256) {
        int ic = i / 324; int rem = i - ic*324;
        int r = rem / 18; int cc = rem - r*18;
        int iy = oy + r - 1, ix = ox + cc - 1;
        float v = 0.f;
        if (iy >= 0 && iy < 256 && ix >= 0 && ix < 256)
            v = in[((n*16 + ic)*256 + iy)*256 + ix];
        tile[ic][r][cc] = v;
    }
    __syncthreads();
    float acc[16];
#pragma unroll
    for (int o = 0; o < 16; ++o) acc[o] = pb[o];
    for (int ic = 0; ic < 16; ++ic) {
#pragma unroll
        for (int ky = 0; ky < 3; ++ky) {
#pragma unroll
            for (int kx = 0; kx < 3; ++kx) {
                float v = tile[ic][ty + ky][tx + kx];
                const float* w = pw + (ic*9 + ky*3 + kx)*16;
#pragma unroll
                for (int o = 0; o < 16; ++o) acc[o] += v * w[o];
            }
        }
    }
    const int p = (oy + ty)*256 + (ox + tx);
    if (MODE == 0) {
#pragma unroll
        for (int o = 0; o < 16; ++o) out[(n*16 + o)*HW256 + p] = leakyf(acc[o]);
    } else if (MODE == 1) {
#pragma unroll
        for (int o = 0; o < 16; ++o)
            out[(n*16 + o)*HW256 + p] = acc[o] + res[(n*16 + o)*HW256 + p];
    } else {
        unsigned int q[8];
#pragma unroll
        for (int h = 0; h < 8; ++h) {
            float a0 = acc[2*h]     + res[(n*16 + 2*h)*HW256 + p];
            float a1 = acc[2*h + 1] + res[(n*16 + 2*h + 1)*HW256 + p];
            q[h] = (unsigned)f2bf(a0) | ((unsigned)f2bf(a1) << 16);
        }
        uint4* dst = (uint4*)ci + (size_t)(n*65536 + p)*2;
        dst[0] = make_uint4(q[0], q[1], q[2], q[3]);
        dst[1] = make_uint4(q[4], q[5], q[6], q[7]);
    }
}

// ---------------------------------------------------------------------------
// conv7x7 16->64 via MFMA implicit GEMM (verified R4).
// ---------------------------------------------------------------------------
__global__ __launch_bounds__(256) void conv7b_mfma(
    const unsigned short* __restrict__ z_ci,
    const unsigned short* __restrict__ pwB,
    float* __restrict__ out0)
{
    __shared__ __align__(16) unsigned short tile[22*24*16]; // 16,896 B
    const int tid = threadIdx.x;
    const int n = blockIdx.z, ox = blockIdx.x*16, oy = blockIdx.y*16;

    const uint4* zc = (const uint4*)z_ci;
    uint4* tl4 = (uint4*)tile;
    for (int u = tid; u < 1056; u += 256) {
        int r = u / 48, s = u - r*48;
        int y = oy + r - 3, xcol = ox + (s >> 1) - 3;
        uint4 v = make_uint4(0u, 0u, 0u, 0u);
        if (y >= 0 && y < 256 && xcol >= 0 && xcol < 256)
            v = zc[(size_t)((n*256 + y)*256 + xcol)*2 + (s & 1)];
        tl4[u] = v;
    }
    __syncthreads();

    const int w = tid >> 6, l = tid & 63;
    const int lg = l >> 4, ln = l & 15;
    float4v acc[4][4];
#pragma unroll
    for (int mi = 0; mi < 4; ++mi)
#pragma unroll
        for (int nt = 0; nt < 4; ++nt)
            acc[mi][nt] = (float4v){0.f, 0.f, 0.f, 0.f};

    const short8v* Bb = (const short8v*)pwB;
    for (int ks = 0; ks < 28; ++ks) {
        const int ky = ks >> 2, kxp = (ks & 3) << 1;
        short8v a[4], b[4];
#pragma unroll
        for (int mi = 0; mi < 4; ++mi) {
            int row = (4*w + mi) + ky;
            int off = (row*24 + ln + kxp)*16 + lg*8;
            a[mi] = *(const short8v*)(tile + off);
        }
#pragma unroll
        for (int nt = 0; nt < 4; ++nt)
            b[nt] = Bb[ks*256 + nt*64 + ln*4 + lg];
#pragma unroll
        for (int mi = 0; mi < 4; ++mi)
#pragma unroll
            for (int nt = 0; nt < 4; ++nt)
                acc[mi][nt] = __builtin_amdgcn_mfma_f32_16x16x32_bf16(
                    a[mi], b[nt], acc[mi][nt], 0, 0, 0);
    }

#pragma unroll
    for (int mi = 0; mi < 4; ++mi) {
        const int yy = oy + 4*w + mi;
#pragma unroll
        for (int nt = 0; nt < 4; ++nt) {
            const int oc = nt*16 + ln;
            float* dst = out0 + (size_t)(n*64 + oc)*HW256 + yy*256 + ox + lg*4;
            *(float4v*)dst = acc[mi][nt];
        }
    }
}

// ---------------------------------------------------------------------------
// Epilogue: out0 += bias + bilinear(x); emit attention key logit k.
// ---------------------------------------------------------------------------
__global__ __launch_bounds__(256) void bilin_k(
    float* __restrict__ out0, const float* __restrict__ x,
    const float* __restrict__ bias,
    const float* __restrict__ akw, const float* __restrict__ akb,
    float* __restrict__ kbuf)
{
    const int tx = threadIdx.x, ty = threadIdx.y;
    const int n = blockIdx.z;
    const int ohx = blockIdx.x*16 + tx, ohy = blockIdx.y*16 + ty;
    float sy = ohy * (127.f/255.f), sx = ohx * (127.f/255.f);
    int y0 = min((int)sy, 126), x0 = min((int)sx, 126);
    float fy = sy - y0, fx = sx - x0;
    const float* xb = x + n*64*HW128;
    const int p = ohy*256 + ohx;
    float kacc = akb[0];
#pragma unroll
    for (int o = 0; o < 64; ++o) {
        const float* xc = xb + o*HW128;
        float v00 = xc[y0*128 + x0],       v01 = xc[y0*128 + x0 + 1];
        float v10 = xc[y0*128 + 128 + x0], v11 = xc[y0*128 + 128 + x0 + 1];
        float idv = (v00*(1.f-fx) + v01*fx)*(1.f-fy) + (v10*(1.f-fx) + v11*fx)*fy;
        size_t idx = (size_t)(n*64 + o)*HW256 + p;
        float u = out0[idx] + bias[o] + idv;
        out0[idx] = u;
        kacc += akw[o] * u;
    }
    kbuf[n*65536 + p] = kacc;
}

// ---------------------------------------------------------------------------
// Softmax stats per image.
// ---------------------------------------------------------------------------
__global__ __launch_bounds__(1024) void softmax_stats(
    const float* __restrict__ kb, float* __restrict__ st)
{
    __shared__ float red[16];
    __shared__ float bc;
    const int n = blockIdx.x, tid = threadIdx.x;
    const float* kp = kb + n*65536;
    float mx = -3.0e38f;
    for (int i = tid; i < 65536; i += 1024) mx = fmaxf(mx, kp[i]);
#pragma unroll
    for (int off = 1; off < 64; off <<= 1) mx = fmaxf(mx, __shfl_xor(mx, off));
    int w = tid >> 6, l = tid & 63;
    if (l == 0) red[w] = mx;
    __syncthreads();
    if (tid == 0) {
        float m = red[0];
        for (int i = 1; i < 16; ++i) m = fmaxf(m, red[i]);
        bc = m;
    }
    __syncthreads();
    float MX = bc;
    float s = 0.f;
    for (int i = tid; i < 65536; i += 1024) s += __expf(kp[i] - MX);
#pragma unroll
    for (int off = 1; off < 64; off <<= 1) s += __shfl_xor(s, off);
    __syncthreads();
    if (l == 0) red[w] = s;
    __syncthreads();
    if (tid == 0) {
        float S = 0.f;
        for (int i = 0; i < 16; ++i) S += red[i];
        st[n] = MX; st[8 + n] = 1.f / S;
    }
}

// ---------------------------------------------------------------------------
// S[n,c] = sum_p exp(k-mx) * out0[n,c,p].
// ---------------------------------------------------------------------------
__global__ __launch_bounds__(256) void att_wsum(
    const float* __restrict__ out0, const float* __restrict__ kb,
    const float* __restrict__ st, float* __restrict__ S)
{
    const int cg = blockIdx.x, n = blockIdx.y, c0 = cg*8;
    const float mx = st[n];
    const float* kp = kb + n*65536;
    const float* base = out0 + (size_t)(n*64 + c0)*HW256;
    float acc[8];
#pragma unroll
    for (int c = 0; c < 8; ++c) acc[c] = 0.f;
    for (int p = threadIdx.x; p < 65536; p += 256) {
        float e = __expf(kp[p] - mx);
#pragma unroll
        for (int c = 0; c < 8; ++c) acc[c] += e * base[c*HW256 + p];
    }
#pragma unroll
    for (int c = 0; c < 8; ++c)
#pragma unroll
        for (int off = 1; off < 64; off <<= 1) acc[c] += __shfl_xor(acc[c], off);
    __shared__ float red[4][8];
    int w = threadIdx.x >> 6, l = threadIdx.x & 63;
    if (l == 0) {
#pragma unroll
        for (int c = 0; c < 8; ++c) red[w][c] = acc[c];
    }
    __syncthreads();
    if (threadIdx.x < 8)
        S[n*64 + c0 + threadIdx.x] =
            red[0][threadIdx.x] + red[1][threadIdx.x] + red[2][threadIdx.x] + red[3][threadIdx.x];
}

// ---------------------------------------------------------------------------
// context + per-(n,c) attention addend.
// ---------------------------------------------------------------------------
__global__ __launch_bounds__(512) void ctx_addc(
    const float* __restrict__ S, const float* __restrict__ st,
    const float* __restrict__ avw, const float* __restrict__ avb,
    const float* __restrict__ arw, const float* __restrict__ arb,
    float* __restrict__ addc)
{
    __shared__ float ctx[8][8];
    const int tid = threadIdx.x;
    if (tid < 64) {
        int n = tid >> 3, vc = tid & 7;
        float s = 0.f;
        for (int c = 0; c < 64; ++c) s += avw[vc*64 + c] * S[n*64 + c];
        ctx[n][vc] = s * st[8 + n] + avb[vc];
    }
    __syncthreads();
    int n = tid >> 6, c = tid & 63;
    float a = arb[c];
#pragma unroll
    for (int vc = 0; vc < 8; ++vc) a += arw[c*8 + vc] * ctx[n][vc];
    addc[n*64 + c] = a;
}

// ---------------------------------------------------------------------------
// Transformer via MFMA. Block = 256 thr (4 waves), 128 tokens of one image.
// Phase 1: coalesced load t = out0 + addc -> LDS Xf[128][68] f32.
// Phase 2: 128 threads do per-token LN (f32) -> Xb[128][72] bf16.
// Phase 3: GEMM1 (128x64x64) MFMA + bias + exact GELU -> Hb bf16 (aliases Xf).
// Phase 4: GEMM2 (128x64x64) MFMA; float4 RMW epilogue on out0.
// ---------------------------------------------------------------------------
__global__ __launch_bounds__(256) void transformer_mfma(
    float* __restrict__ out0, const float* __restrict__ addc,
    const float* __restrict__ lng, const float* __restrict__ lnb,
    const unsigned short* __restrict__ W1b, const float* __restrict__ fc1b,
    const unsigned short* __restrict__ W2b, const float* __restrict__ fc2b)
{
    __shared__ __align__(16) unsigned char lds[53248];
    float*          Xf = (float*)lds;                         // [128][68] f32
    unsigned short* Hb = (unsigned short*)lds;                // [128][72] bf16 (after Xf dead)
    unsigned short* Xb = (unsigned short*)(lds + 34816);      // [128][72] bf16

    const int tid = threadIdx.x;
    const int n = blockIdx.x >> 9;
    const int p0 = (blockIdx.x & 511) << 7;
    const float* ac = addc + n*64;

    // Phase 1: load 128 tokens x 64 ch, float4 per lane, + addc
#pragma unroll
    for (int k = 0; k < 8; ++k) {
        int v = k*256 + tid;
        int c = v >> 5, i4 = (v & 31) << 2;
        float4v q = *(const float4v*)(out0 + (size_t)(n*64 + c)*HW256 + p0 + i4);
        float a = ac[c];
#pragma unroll
        for (int r = 0; r < 4; ++r) Xf[(i4 + r)*68 + c] = q[r] + a;
    }
    __syncthreads();

    // Phase 2: LN per token (threads 0..127)
    if (tid < 128) {
        float t[64];
#pragma unroll
        for (int c4 = 0; c4 < 16; ++c4) {
            float4v q = *(const float4v*)&Xf[tid*68 + c4*4];
#pragma unroll
            for (int r = 0; r < 4; ++r) t[c4*4 + r] = q[r];
        }
        float mu = 0.f;
#pragma unroll
        for (int c = 0; c < 64; ++c) mu += t[c];
        mu *= (1.f/64.f);
        float var = 0.f;
#pragma unroll
        for (int c = 0; c < 64; ++c) { float d = t[c] - mu; var += d*d; }
        var *= (1.f/64.f);
        float rs = rsqrtf(var + 1e-5f);
#pragma unroll
        for (int c8 = 0; c8 < 8; ++c8) {
            short8v pk;
#pragma unroll
            for (int e = 0; e < 8; ++e) {
                int c = c8*8 + e;
                pk[e] = (short)f2bf((t[c] - mu)*rs*lng[c] + lnb[c]);
            }
            *(short8v*)&Xb[tid*72 + c8*8] = pk;
        }
    }
    __syncthreads();

    const int w = tid >> 6, l = tid & 63, lg = l >> 4, ln = l & 15;

    // Phase 3: GEMM1 + GELU
    float4v acc1[2][4];
#pragma unroll
    for (int mt = 0; mt < 2; ++mt)
#pragma unroll
        for (int nt = 0; nt < 4; ++nt) acc1[mt][nt] = (float4v){0.f,0.f,0.f,0.f};
#pragma unroll
    for (int kk = 0; kk < 2; ++kk) {
        short8v a[2], b[4];
#pragma unroll
        for (int mt = 0; mt < 2; ++mt)
            a[mt] = *(const short8v*)&Xb[(w*32 + mt*16 + ln)*72 + kk*32 + lg*8];
#pragma unroll
        for (int nt = 0; nt < 4; ++nt)
            b[nt] = *(const short8v*)&W1b[(nt*16 + ln)*64 + kk*32 + lg*8];
#pragma unroll
        for (int mt = 0; mt < 2; ++mt)
#pragma unroll
            for (int nt = 0; nt < 4; ++nt)
                acc1[mt][nt] = __builtin_amdgcn_mfma_f32_16x16x32_bf16(
                    a[mt], b[nt], acc1[mt][nt], 0, 0, 0);
    }
#pragma unroll
    for (int mt = 0; mt < 2; ++mt)
#pragma unroll
        for (int nt = 0; nt < 4; ++nt) {
            int j = nt*16 + ln;
            float bj = fc1b[j];
#pragma unroll
            for (int r = 0; r < 4; ++r) {
                int token = w*32 + mt*16 + lg*4 + r;
                float m = acc1[mt][nt][r] + bj;
                float g = 0.5f*m*(1.f + erff(m*0.70710678118654752f));
                Hb[token*72 + j] = f2bf(g);
            }
        }
    __syncthreads();

    // Phase 4: GEMM2 + epilogue RMW
    float4v acc2[2][4];
#pragma unroll
    for (int mt = 0; mt < 2; ++mt)
#pragma unroll
        for (int nt = 0; nt < 4; ++nt) acc2[mt][nt] = (float4v){0.f,0.f,0.f,0.f};
#pragma unroll
    for (int kk = 0; kk < 2; ++kk) {
        short8v a[2], b[4];
#pragma unroll
        for (int mt = 0; mt < 2; ++mt)
            a[mt] = *(const short8v*)&Hb[(w*32 + mt*16 + ln)*72 + kk*32 + lg*8];
#pragma unroll
        for (int nt = 0; nt < 4; ++nt)
            b[nt] = *(const short8v*)&W2b[(nt*16 + ln)*64 + kk*32 + lg*8];
#pragma unroll
        for (int mt = 0; mt < 2; ++mt)
#pragma unroll
            for (int nt = 0; nt < 4; ++nt)
                acc2[mt][nt] = __builtin_amdgcn_mfma_f32_16x16x32_bf16(
                    a[mt], b[nt], acc2[mt][nt], 0, 0, 0);
    }
#pragma unroll
    for (int mt = 0; mt < 2; ++mt)
#pragma unroll
        for (int nt = 0; nt < 4; ++nt) {
            int c = nt*16 + ln;
            int tb = w*32 + mt*16 + lg*4;
            float add = fc2b[c] + ac[c];
            float* dst = out0 + (size_t)(n*64 + c)*HW256 + p0 + tb;
            float4v o = *(float4v*)dst;
#pragma unroll
            for (int r = 0; r < 4; ++r) o[r] += acc2[mt][nt][r] + add;
            *(float4v*)dst = o;
        }
}

// ---------------------------------------------------------------------------
extern "C" void kernel_launch(void* const* d_in, const int* in_sizes, int n_in,
                              void* d_out, int out_size, void* d_ws, size_t ws_size,
                              hipStream_t stream)
{
    (void)in_sizes; (void)n_in; (void)out_size; (void)ws_size;
    const float* x    = (const float*)d_in[0];
    const float* w7a  = (const float*)d_in[1];
    const float* b7a  = (const float*)d_in[2];
    const float* w1   = (const float*)d_in[3];
    const float* b1   = (const float*)d_in[4];
    const float* g1   = (const float*)d_in[5];
    const float* be1  = (const float*)d_in[6];
    const float* w3a  = (const float*)d_in[7];
    const float* b3a  = (const float*)d_in[8];
    const float* g3a  = (const float*)d_in[9];
    const float* be3a = (const float*)d_in[10];
    const float* w3b  = (const float*)d_in[11];
    const float* b3b  = (const float*)d_in[12];
    const float* g3b  = (const float*)d_in[13];
    const float* be3b = (const float*)d_in[14];
    const float* w3c  = (const float*)d_in[15];
    const float* b3c  = (const float*)d_in[16];
    const float* g3c  = (const float*)d_in[17];
    const float* be3c = (const float*)d_in[18];
    const float* w7b  = (const float*)d_in[19];
    const float* b7b  = (const float*)d_in[20];
    const float* akw  = (const float*)d_in[21];
    const float* akb  = (const float*)d_in[22];
    const float* avw  = (const float*)d_in[25];
    const float* avb  = (const float*)d_in[26];
    const float* arw  = (const float*)d_in[27];
    const float* arb  = (const float*)d_in[28];
    const float* lng  = (const float*)d_in[29];
    const float* lnb  = (const float*)d_in[30];
    const float* fc1w = (const float*)d_in[31];
    const float* fc1b = (const float*)d_in[32];
    const float* fc2w = (const float*)d_in[33];
    const float* fc2b = (const float*)d_in[34];

    float* ws   = (float*)d_ws;
    float* o_y2 = ws;                       // 2,097,152
    float* o_y  = o_y2 + 2097152;           // 8,388,608
    float* o_z1 = o_y  + 8388608;           // 8,388,608 (f32 z1; later bf16 z_ci)
    float* o_z2 = o_z1 + 8388608;           // 8,388,608
    float* o_k  = o_z2 + 8388608;           // 524,288
    float* o_st = o_k  + 524288;            // 64
    float* o_S  = o_st + 64;                // 512
    float* o_ad = o_S  + 512;               // 512
    float* p7a  = o_ad + 512;               // 50,176
    float* p1   = p7a  + 50176;             // 256
    float* p3a  = p1   + 256;   float* q3a = p3a + 2304;
    float* p3b  = q3a  + 16;    float* q3b = p3b + 2304;
    float* p3c  = q3b  + 16;    float* q3c = p3c + 2304;
    unsigned short* pwB  = (unsigned short*)(q3c + 16);  // 57,344 bf16
    unsigned short* pwT1 = pwB + 57344;                  // 4,096 bf16
    unsigned short* pwT2 = pwT1 + 4096;                  // 4,096 bf16

    unsigned short* z_ci = (unsigned short*)o_z1;  // bf16 [8][256][256][16] = 16.8 MB

    float* out0 = (float*)d_out;

    prepack<<<224, 256, 0, stream>>>(w7a, w1, w3a,b3a,g3a,be3a, w3b,b3b,g3b,be3b,
                                     w3c,b3c,g3c,be3c, w7b, fc1w, fc2w,
                                     p7a, p1, p3a,q3a, p3b,q3b, p3c,q3c, pwB, pwT1, pwT2);
    conv7a_1x1_bn<<<dim3(8,8,8), dim3(16,16), 0, stream>>>(x, p7a, b7a, p1, b1, g1, be1, o_y2);
    resize_128_256<<<dim3(16,16,128), dim3(16,16), 0, stream>>>(o_y2, o_y);
    conv3x3_bn<0><<<dim3(16,16,8), dim3(16,16), 0, stream>>>(o_y,  p3a, q3a, nullptr, o_z1, nullptr);
    conv3x3_bn<1><<<dim3(16,16,8), dim3(16,16), 0, stream>>>(o_z1, p3b, q3b, o_y,     o_z2, nullptr);
    conv3x3_bn<2><<<dim3(16,16,8), dim3(16,16), 0, stream>>>(o_z2, p3c, q3c, o_y,     nullptr, z_ci);
    conv7b_mfma<<<dim3(16,16,8), 256, 0, stream>>>(z_ci, pwB, out0);
    bilin_k<<<dim3(16,16,8), dim3(16,16), 0, stream>>>(out0, x, b7b, akw, akb, o_k);
    softmax_stats<<<8, 1024, 0, stream>>>(o_k, o_st);
    att_wsum<<<dim3(8,8), 256, 0, stream>>>(out0, o_k, o_st, o_S);
    ctx_addc<<<1, 512, 0, stream>>>(o_S, o_st, avw, avb, arw, arb, o_ad);
    transformer_mfma<<<4096, 256, 0, stream>>>(out0, o_ad, lng, lnb, pwT1, fc1b, pwT2, fc2b);
}

// Round 6
// 622.593 us; speedup vs baseline: 5.7368x; 1.7020x over previous
//
#include <hip/hip_runtime.h>
#include <math.h>

#define DI __device__ __forceinline__
#define HW128 (128*128)
#define HW256 (256*256)

__device__ const float BN_RS = 0.9999950000374997f; // 1/sqrt(1+1e-5)

DI float leakyf(float x){ return x >= 0.f ? x : 0.2f*x; }

DI unsigned short f2bf(float f){
    unsigned u = __float_as_uint(f);
    return (unsigned short)((u + 0x7fffu + ((u >> 16) & 1u)) >> 16);
}

typedef __attribute__((ext_vector_type(8))) short short8v;
typedef __attribute__((ext_vector_type(4))) float float4v;

// ---------------------------------------------------------------------------
// Prepack: bf16 [g][ks28][oc16][k32] for MFMA conv7a; bf16 [ks28][oc64][k32]
// for MFMA conv7b; [ic][oc] f32 for the 1x1; BN-folded 3x3; bf16 fc1/fc2.
// ---------------------------------------------------------------------------
__global__ __launch_bounds__(256) void prepack(
    const float* __restrict__ w7a, const float* __restrict__ w1,
    const float* __restrict__ w3a, const float* __restrict__ b3a, const float* __restrict__ g3a, const float* __restrict__ be3a,
    const float* __restrict__ w3b, const float* __restrict__ b3b, const float* __restrict__ g3b, const float* __restrict__ be3b,
    const float* __restrict__ w3c, const float* __restrict__ b3c, const float* __restrict__ g3c, const float* __restrict__ be3c,
    const float* __restrict__ w7b, const float* __restrict__ fc1w, const float* __restrict__ fc2w,
    unsigned short* __restrict__ p7aB, float* __restrict__ p1,
    float* __restrict__ p3a, float* __restrict__ q3a,
    float* __restrict__ p3b, float* __restrict__ q3b,
    float* __restrict__ p3c, float* __restrict__ q3c,
    unsigned short* __restrict__ pwB,
    unsigned short* __restrict__ pwT1, unsigned short* __restrict__ pwT2)
{
    int i = blockIdx.x * 256 + threadIdx.x;
    if (i < 57344) {                                      // conv7a MFMA weights
        int g = i / 14336, rem = i - g*14336;
        int ks = rem >> 9, oc = (rem >> 5) & 15, k = rem & 31;
        int ky = ks >> 2, kx = ((ks & 3) << 1) + (k >> 4), ic = g*16 + (k & 15);
        p7aB[i] = (kx < 7) ? f2bf(w7a[(oc*64 + ic)*49 + ky*7 + kx]) : (unsigned short)0;
    }
    if (i < 57344) {                                      // conv7b MFMA weights
        int ks = i >> 11;            // 0..27
        int oc = (i >> 5) & 63;
        int k  = i & 31;
        int ky = ks >> 2;
        int kx = ((ks & 3) << 1) + (k >> 4);
        int ic = k & 15;
        pwB[i] = (kx < 7) ? f2bf(w7b[((oc*16 + ic)*7 + ky)*7 + kx]) : (unsigned short)0;
    }
    if (i < 256) { int oc = i & 15, ic = i >> 4; p1[i] = w1[oc*16 + ic]; }
    if (i < 2304) {
        int oc = i & 15, t = (i >> 4) % 9, ic = (i >> 4) / 9;
        int src = (oc*16 + ic)*9 + t;
        p3a[i] = w3a[src] * (g3a[oc]*BN_RS);
        p3b[i] = w3b[src] * (g3b[oc]*BN_RS);
        p3c[i] = w3c[src] * (g3c[oc]*BN_RS);
    }
    if (i < 16) {
        q3a[i] = b3a[i]*(g3a[i]*BN_RS) + be3a[i];
        q3b[i] = b3b[i]*(g3b[i]*BN_RS) + be3b[i];
        q3c[i] = b3c[i]*(g3c[i]*BN_RS) + be3c[i];
    }
    if (i < 4096) { pwT1[i] = f2bf(fc1w[i]); pwT2[i] = f2bf(fc2w[i]); }
}

// ---------------------------------------------------------------------------
// x (8,64,128,128) f32 -> xci bf16 [n][g=ic/16][y*128+x][16]
// ---------------------------------------------------------------------------
__global__ __launch_bounds__(256) void x_to_ci(
    const float* __restrict__ x, unsigned short* __restrict__ xci)
{
    int idx = blockIdx.x*256 + threadIdx.x;   // 524,288
    int p = idx & 16383, gn = idx >> 14;
    int g = gn & 3, n = gn >> 2;
    const float* xb = x + (size_t)(n*64 + g*16)*HW128 + p;
    unsigned q[8];
#pragma unroll
    for (int h = 0; h < 8; ++h) {
        float a0 = xb[(size_t)(2*h)*HW128];
        float a1 = xb[(size_t)(2*h + 1)*HW128];
        q[h] = (unsigned)f2bf(a0) | ((unsigned)f2bf(a1) << 16);
    }
    uint4* dst = (uint4*)xci + (size_t)idx*2;
    dst[0] = make_uint4(q[0], q[1], q[2], q[3]);
    dst[1] = make_uint4(q[4], q[5], q[6], q[7]);
}

// ---------------------------------------------------------------------------
// conv7x7 64->16 via MFMA implicit GEMM (conv7b template, ic-grouped) then
// f32 1x1(16->16) + leaky + BN epilogue through LDS.
// ---------------------------------------------------------------------------
__global__ __launch_bounds__(256) void conv7a_mfma(
    const unsigned short* __restrict__ xci,
    const unsigned short* __restrict__ pw,
    const float* __restrict__ b7a, const float* __restrict__ p1,
    const float* __restrict__ b1, const float* __restrict__ bng,
    const float* __restrict__ bnb, float* __restrict__ y2)
{
    __shared__ __align__(16) unsigned char lds[17408];
    unsigned short* tile = (unsigned short*)lds;   // [22][24][16] bf16 (16,896 B)
    float* P16 = (float*)lds;                      // [256][17] f32 (aliases tile)

    const int tid = threadIdx.x;
    const int n = blockIdx.z, ox = blockIdx.x*16, oy = blockIdx.y*16;
    const int w = tid >> 6, l = tid & 63, lg = l >> 4, ln = l & 15;

    float4v acc[4];
#pragma unroll
    for (int mi = 0; mi < 4; ++mi) acc[mi] = (float4v){0.f,0.f,0.f,0.f};

    const uint4* xc4 = (const uint4*)xci;
    uint4* tl4 = (uint4*)tile;
    const short8v* Bb = (const short8v*)pw;

    for (int g = 0; g < 4; ++g) {
        __syncthreads();
        for (int u = tid; u < 1056; u += 256) {
            int r = u / 48, s = u - r*48;
            int y = oy + r - 3, xcol = ox + (s >> 1) - 3;
            uint4 v = make_uint4(0u,0u,0u,0u);
            if (y >= 0 && y < 128 && xcol >= 0 && xcol < 128)
                v = xc4[((size_t)(n*4 + g)*16384 + y*128 + xcol)*2 + (s & 1)];
            tl4[u] = v;
        }
        __syncthreads();
        for (int ks = 0; ks < 28; ++ks) {
            const int ky = ks >> 2, kxp = (ks & 3) << 1;
            short8v b = Bb[(g*28 + ks)*64 + ln*4 + lg];
            short8v a[4];
#pragma unroll
            for (int mi = 0; mi < 4; ++mi) {
                int row = (4*w + mi) + ky;
                a[mi] = *(const short8v*)(tile + (row*24 + ln + kxp)*16 + lg*8);
            }
#pragma unroll
            for (int mi = 0; mi < 4; ++mi)
                acc[mi] = __builtin_amdgcn_mfma_f32_16x16x32_bf16(a[mi], b, acc[mi], 0, 0, 0);
        }
    }
    __syncthreads();
    // leaky(conv7a + bias) -> LDS f32 [px 256][17]
    const float bo = b7a[ln];
#pragma unroll
    for (int mi = 0; mi < 4; ++mi)
#pragma unroll
        for (int r = 0; r < 4; ++r)
            P16[((4*w + mi)*16 + lg*4 + r)*17 + ln] = leakyf(acc[mi][r] + bo);
    __syncthreads();
    // per-thread f32 1x1 + leaky + BN
    const int py = tid >> 4, pxx = tid & 15;
    float lv[16];
#pragma unroll
    for (int ic = 0; ic < 16; ++ic) lv[ic] = P16[tid*17 + ic];
    const int p = (oy + py)*128 + ox + pxx;
#pragma unroll
    for (int o = 0; o < 16; ++o) {
        float u = b1[o];
#pragma unroll
        for (int ic = 0; ic < 16; ++ic) u += lv[ic] * p1[ic*16 + o];
        u = leakyf(u);
        u = u * (bng[o]*BN_RS) + bnb[o];
        y2[(n*16 + o)*HW128 + p] = u;
    }
}

// ---------------------------------------------------------------------------
// Bilinear resize 128->256, align_corners=True.
// ---------------------------------------------------------------------------
__global__ __launch_bounds__(256) void resize_128_256(
    const float* __restrict__ in, float* __restrict__ out)
{
    int nc = blockIdx.z;
    int ox = blockIdx.x*16 + threadIdx.x;
    int oy = blockIdx.y*16 + threadIdx.y;
    float sy = oy * (127.f/255.f), sx = ox * (127.f/255.f);
    int y0 = min((int)sy, 126), x0 = min((int)sx, 126);
    float fy = sy - y0, fx = sx - x0;
    const float* b = in + nc*HW128;
    float v00 = b[y0*128 + x0],       v01 = b[y0*128 + x0 + 1];
    float v10 = b[y0*128 + 128 + x0], v11 = b[y0*128 + 128 + x0 + 1];
    float top = v00*(1.f-fx) + v01*fx;
    float bot = v10*(1.f-fx) + v11*fx;
    out[nc*HW256 + oy*256 + ox] = top*(1.f-fy) + bot*fy;
}

// ---------------------------------------------------------------------------
// 3x3 conv 16->16 with pre-folded BN.
// MODE 0: leaky -> f32.  MODE 1: +res -> f32.  MODE 2: +res -> bf16 ci.
// ---------------------------------------------------------------------------
template<int MODE>
__global__ __launch_bounds__(256) void conv3x3_bn(
    const float* __restrict__ in, const float* __restrict__ pw,
    const float* __restrict__ pb, const float* __restrict__ res,
    float* __restrict__ out, unsigned short* __restrict__ ci)
{
    __shared__ float tile[16][18][18];
    const int tx = threadIdx.x, ty = threadIdx.y;
    const int n = blockIdx.z, ox = blockIdx.x*16, oy = blockIdx.y*16;
    const int tid = ty*16 + tx;
    for (int i = tid; i < 16*18*18; i += 256) {
        int ic = i / 324; int rem = i - ic*324;
        int r = rem / 18; int cc = rem - r*18;
        int iy = oy + r - 1, ix = ox + cc - 1;
        float v = 0.f;
        if (iy >= 0 && iy < 256 && ix >= 0 && ix < 256)
            v = in[((n*16 + ic)*256 + iy)*256 + ix];
        tile[ic][r][cc] = v;
    }
    __syncthreads();
    float acc[16];
#pragma unroll
    for (int o = 0; o < 16; ++o) acc[o] = pb[o];
    for (int ic = 0; ic < 16; ++ic) {
#pragma unroll
        for (int ky = 0; ky < 3; ++ky) {
#pragma unroll
            for (int kx = 0; kx < 3; ++kx) {
                float v = tile[ic][ty + ky][tx + kx];
                const float* w = pw + (ic*9 + ky*3 + kx)*16;
#pragma unroll
                for (int o = 0; o < 16; ++o) acc[o] += v * w[o];
            }
        }
    }
    const int p = (oy + ty)*256 + (ox + tx);
    if (MODE == 0) {
#pragma unroll
        for (int o = 0; o < 16; ++o) out[(n*16 + o)*HW256 + p] = leakyf(acc[o]);
    } else if (MODE == 1) {
#pragma unroll
        for (int o = 0; o < 16; ++o)
            out[(n*16 + o)*HW256 + p] = acc[o] + res[(n*16 + o)*HW256 + p];
    } else {
        unsigned int q[8];
#pragma unroll
        for (int h = 0; h < 8; ++h) {
            float a0 = acc[2*h]     + res[(n*16 + 2*h)*HW256 + p];
            float a1 = acc[2*h + 1] + res[(n*16 + 2*h + 1)*HW256 + p];
            q[h] = (unsigned)f2bf(a0) | ((unsigned)f2bf(a1) << 16);
        }
        uint4* dst = (uint4*)ci + (size_t)(n*65536 + p)*2;
        dst[0] = make_uint4(q[0], q[1], q[2], q[3]);
        dst[1] = make_uint4(q[4], q[5], q[6], q[7]);
    }
}

// ---------------------------------------------------------------------------
// conv7x7 16->64 via MFMA implicit GEMM (verified R4).
// ---------------------------------------------------------------------------
__global__ __launch_bounds__(256) void conv7b_mfma(
    const unsigned short* __restrict__ z_ci,
    const unsigned short* __restrict__ pwB,
    float* __restrict__ out0)
{
    __shared__ __align__(16) unsigned short tile[22*24*16]; // 16,896 B
    const int tid = threadIdx.x;
    const int n = blockIdx.z, ox = blockIdx.x*16, oy = blockIdx.y*16;

    const uint4* zc = (const uint4*)z_ci;
    uint4* tl4 = (uint4*)tile;
    for (int u = tid; u < 1056; u += 256) {
        int r = u / 48, s = u - r*48;
        int y = oy + r - 3, xcol = ox + (s >> 1) - 3;
        uint4 v = make_uint4(0u, 0u, 0u, 0u);
        if (y >= 0 && y < 256 && xcol >= 0 && xcol < 256)
            v = zc[(size_t)((n*256 + y)*256 + xcol)*2 + (s & 1)];
        tl4[u] = v;
    }
    __syncthreads();

    const int w = tid >> 6, l = tid & 63;
    const int lg = l >> 4, ln = l & 15;
    float4v acc[4][4];
#pragma unroll
    for (int mi = 0; mi < 4; ++mi)
#pragma unroll
        for (int nt = 0; nt < 4; ++nt)
            acc[mi][nt] = (float4v){0.f, 0.f, 0.f, 0.f};

    const short8v* Bb = (const short8v*)pwB;
    for (int ks = 0; ks < 28; ++ks) {
        const int ky = ks >> 2, kxp = (ks & 3) << 1;
        short8v a[4], b[4];
#pragma unroll
        for (int mi = 0; mi < 4; ++mi) {
            int row = (4*w + mi) + ky;
            int off = (row*24 + ln + kxp)*16 + lg*8;
            a[mi] = *(const short8v*)(tile + off);
        }
#pragma unroll
        for (int nt = 0; nt < 4; ++nt)
            b[nt] = Bb[ks*256 + nt*64 + ln*4 + lg];
#pragma unroll
        for (int mi = 0; mi < 4; ++mi)
#pragma unroll
            for (int nt = 0; nt < 4; ++nt)
                acc[mi][nt] = __builtin_amdgcn_mfma_f32_16x16x32_bf16(
                    a[mi], b[nt], acc[mi][nt], 0, 0, 0);
    }

#pragma unroll
    for (int mi = 0; mi < 4; ++mi) {
        const int yy = oy + 4*w + mi;
#pragma unroll
        for (int nt = 0; nt < 4; ++nt) {
            const int oc = nt*16 + ln;
            float* dst = out0 + (size_t)(n*64 + oc)*HW256 + yy*256 + ox + lg*4;
            *(float4v*)dst = acc[mi][nt];
        }
    }
}

// ---------------------------------------------------------------------------
// Epilogue: out0 += bias + bilinear(x); emit attention key logit k.
// ---------------------------------------------------------------------------
__global__ __launch_bounds__(256) void bilin_k(
    float* __restrict__ out0, const float* __restrict__ x,
    const float* __restrict__ bias,
    const float* __restrict__ akw, const float* __restrict__ akb,
    float* __restrict__ kbuf)
{
    const int tx = threadIdx.x, ty = threadIdx.y;
    const int n = blockIdx.z;
    const int ohx = blockIdx.x*16 + tx, ohy = blockIdx.y*16 + ty;
    float sy = ohy * (127.f/255.f), sx = ohx * (127.f/255.f);
    int y0 = min((int)sy, 126), x0 = min((int)sx, 126);
    float fy = sy - y0, fx = sx - x0;
    const float* xb = x + n*64*HW128;
    const int p = ohy*256 + ohx;
    float kacc = akb[0];
#pragma unroll
    for (int o = 0; o < 64; ++o) {
        const float* xc = xb + o*HW128;
        float v00 = xc[y0*128 + x0],       v01 = xc[y0*128 + x0 + 1];
        float v10 = xc[y0*128 + 128 + x0], v11 = xc[y0*128 + 128 + x0 + 1];
        float idv = (v00*(1.f-fx) + v01*fx)*(1.f-fy) + (v10*(1.f-fx) + v11*fx)*fy;
        size_t idx = (size_t)(n*64 + o)*HW256 + p;
        float u = out0[idx] + bias[o] + idv;
        out0[idx] = u;
        kacc += akw[o] * u;
    }
    kbuf[n*65536 + p] = kacc;
}

// ---------------------------------------------------------------------------
// Softmax stats per image.
// ---------------------------------------------------------------------------
__global__ __launch_bounds__(1024) void softmax_stats(
    const float* __restrict__ kb, float* __restrict__ st)
{
    __shared__ float red[16];
    __shared__ float bc;
    const int n = blockIdx.x, tid = threadIdx.x;
    const float* kp = kb + n*65536;
    float mx = -3.0e38f;
    for (int i = tid; i < 65536; i += 1024) mx = fmaxf(mx, kp[i]);
#pragma unroll
    for (int off = 1; off < 64; off <<= 1) mx = fmaxf(mx, __shfl_xor(mx, off));
    int w = tid >> 6, l = tid & 63;
    if (l == 0) red[w] = mx;
    __syncthreads();
    if (tid == 0) {
        float m = red[0];
        for (int i = 1; i < 16; ++i) m = fmaxf(m, red[i]);
        bc = m;
    }
    __syncthreads();
    float MX = bc;
    float s = 0.f;
    for (int i = tid; i < 65536; i += 1024) s += __expf(kp[i] - MX);
#pragma unroll
    for (int off = 1; off < 64; off <<= 1) s += __shfl_xor(s, off);
    __syncthreads();
    if (l == 0) red[w] = s;
    __syncthreads();
    if (tid == 0) {
        float S = 0.f;
        for (int i = 0; i < 16; ++i) S += red[i];
        st[n] = MX; st[8 + n] = 1.f / S;
    }
}

// ---------------------------------------------------------------------------
// S[n,c] = sum_p exp(k-mx) * out0[n,c,p].
// ---------------------------------------------------------------------------
__global__ __launch_bounds__(256) void att_wsum(
    const float* __restrict__ out0, const float* __restrict__ kb,
    const float* __restrict__ st, float* __restrict__ S)
{
    const int cg = blockIdx.x, n = blockIdx.y, c0 = cg*8;
    const float mx = st[n];
    const float* kp = kb + n*65536;
    const float* base = out0 + (size_t)(n*64 + c0)*HW256;
    float acc[8];
#pragma unroll
    for (int c = 0; c < 8; ++c) acc[c] = 0.f;
    for (int p = threadIdx.x; p < 65536; p += 256) {
        float e = __expf(kp[p] - mx);
#pragma unroll
        for (int c = 0; c < 8; ++c) acc[c] += e * base[c*HW256 + p];
    }
#pragma unroll
    for (int c = 0; c < 8; ++c)
#pragma unroll
        for (int off = 1; off < 64; off <<= 1) acc[c] += __shfl_xor(acc[c], off);
    __shared__ float red[4][8];
    int w = threadIdx.x >> 6, l = threadIdx.x & 63;
    if (l == 0) {
#pragma unroll
        for (int c = 0; c < 8; ++c) red[w][c] = acc[c];
    }
    __syncthreads();
    if (threadIdx.x < 8)
        S[n*64 + c0 + threadIdx.x] =
            red[0][threadIdx.x] + red[1][threadIdx.x] + red[2][threadIdx.x] + red[3][threadIdx.x];
}

// ---------------------------------------------------------------------------
// context + per-(n,c) attention addend.
// ---------------------------------------------------------------------------
__global__ __launch_bounds__(512) void ctx_addc(
    const float* __restrict__ S, const float* __restrict__ st,
    const float* __restrict__ avw, const float* __restrict__ avb,
    const float* __restrict__ arw, const float* __restrict__ arb,
    float* __restrict__ addc)
{
    __shared__ float ctx[8][8];
    const int tid = threadIdx.x;
    if (tid < 64) {
        int n = tid >> 3, vc = tid & 7;
        float s = 0.f;
        for (int c = 0; c < 64; ++c) s += avw[vc*64 + c] * S[n*64 + c];
        ctx[n][vc] = s * st[8 + n] + avb[vc];
    }
    __syncthreads();
    int n = tid >> 6, c = tid & 63;
    float a = arb[c];
#pragma unroll
    for (int vc = 0; vc < 8; ++vc) a += arw[c*8 + vc] * ctx[n][vc];
    addc[n*64 + c] = a;
}

// ---------------------------------------------------------------------------
// Transformer via MFMA (verified R5).
// ---------------------------------------------------------------------------
__global__ __launch_bounds__(256) void transformer_mfma(
    float* __restrict__ out0, const float* __restrict__ addc,
    const float* __restrict__ lng, const float* __restrict__ lnb,
    const unsigned short* __restrict__ W1b, const float* __restrict__ fc1b,
    const unsigned short* __restrict__ W2b, const float* __restrict__ fc2b)
{
    __shared__ __align__(16) unsigned char lds[53248];
    float*          Xf = (float*)lds;                         // [128][68] f32
    unsigned short* Hb = (unsigned short*)lds;                // [128][72] bf16 (after Xf dead)
    unsigned short* Xb = (unsigned short*)(lds + 34816);      // [128][72] bf16

    const int tid = threadIdx.x;
    const int n = blockIdx.x >> 9;
    const int p0 = (blockIdx.x & 511) << 7;
    const float* ac = addc + n*64;

#pragma unroll
    for (int k = 0; k < 8; ++k) {
        int v = k*256 + tid;
        int c = v >> 5, i4 = (v & 31) << 2;
        float4v q = *(const float4v*)(out0 + (size_t)(n*64 + c)*HW256 + p0 + i4);
        float a = ac[c];
#pragma unroll
        for (int r = 0; r < 4; ++r) Xf[(i4 + r)*68 + c] = q[r] + a;
    }
    __syncthreads();

    if (tid < 128) {
        float t[64];
#pragma unroll
        for (int c4 = 0; c4 < 16; ++c4) {
            float4v q = *(const float4v*)&Xf[tid*68 + c4*4];
#pragma unroll
            for (int r = 0; r < 4; ++r) t[c4*4 + r] = q[r];
        }
        float mu = 0.f;
#pragma unroll
        for (int c = 0; c < 64; ++c) mu += t[c];
        mu *= (1.f/64.f);
        float var = 0.f;
#pragma unroll
        for (int c = 0; c < 64; ++c) { float d = t[c] - mu; var += d*d; }
        var *= (1.f/64.f);
        float rs = rsqrtf(var + 1e-5f);
#pragma unroll
        for (int c8 = 0; c8 < 8; ++c8) {
            short8v pk;
#pragma unroll
            for (int e = 0; e < 8; ++e) {
                int c = c8*8 + e;
                pk[e] = (short)f2bf((t[c] - mu)*rs*lng[c] + lnb[c]);
            }
            *(short8v*)&Xb[tid*72 + c8*8] = pk;
        }
    }
    __syncthreads();

    const int w = tid >> 6, l = tid & 63, lg = l >> 4, ln = l & 15;

    float4v acc1[2][4];
#pragma unroll
    for (int mt = 0; mt < 2; ++mt)
#pragma unroll
        for (int nt = 0; nt < 4; ++nt) acc1[mt][nt] = (float4v){0.f,0.f,0.f,0.f};
#pragma unroll
    for (int kk = 0; kk < 2; ++kk) {
        short8v a[2], b[4];
#pragma unroll
        for (int mt = 0; mt < 2; ++mt)
            a[mt] = *(const short8v*)&Xb[(w*32 + mt*16 + ln)*72 + kk*32 + lg*8];
#pragma unroll
        for (int nt = 0; nt < 4; ++nt)
            b[nt] = *(const short8v*)&W1b[(nt*16 + ln)*64 + kk*32 + lg*8];
#pragma unroll
        for (int mt = 0; mt < 2; ++mt)
#pragma unroll
            for (int nt = 0; nt < 4; ++nt)
                acc1[mt][nt] = __builtin_amdgcn_mfma_f32_16x16x32_bf16(
                    a[mt], b[nt], acc1[mt][nt], 0, 0, 0);
    }
#pragma unroll
    for (int mt = 0; mt < 2; ++mt)
#pragma unroll
        for (int nt = 0; nt < 4; ++nt) {
            int j = nt*16 + ln;
            float bj = fc1b[j];
#pragma unroll
            for (int r = 0; r < 4; ++r) {
                int token = w*32 + mt*16 + lg*4 + r;
                float m = acc1[mt][nt][r] + bj;
                float g = 0.5f*m*(1.f + erff(m*0.70710678118654752f));
                Hb[token*72 + j] = f2bf(g);
            }
        }
    __syncthreads();

    float4v acc2[2][4];
#pragma unroll
    for (int mt = 0; mt < 2; ++mt)
#pragma unroll
        for (int nt = 0; nt < 4; ++nt) acc2[mt][nt] = (float4v){0.f,0.f,0.f,0.f};
#pragma unroll
    for (int kk = 0; kk < 2; ++kk) {
        short8v a[2], b[4];
#pragma unroll
        for (int mt = 0; mt < 2; ++mt)
            a[mt] = *(const short8v*)&Hb[(w*32 + mt*16 + ln)*72 + kk*32 + lg*8];
#pragma unroll
        for (int nt = 0; nt < 4; ++nt)
            b[nt] = *(const short8v*)&W2b[(nt*16 + ln)*64 + kk*32 + lg*8];
#pragma unroll
        for (int mt = 0; mt < 2; ++mt)
#pragma unroll
            for (int nt = 0; nt < 4; ++nt)
                acc2[mt][nt] = __builtin_amdgcn_mfma_f32_16x16x32_bf16(
                    a[mt], b[nt], acc2[mt][nt], 0, 0, 0);
    }
#pragma unroll
    for (int mt = 0; mt < 2; ++mt)
#pragma unroll
        for (int nt = 0; nt < 4; ++nt) {
            int c = nt*16 + ln;
            int tb = w*32 + mt*16 + lg*4;
            float add = fc2b[c] + ac[c];
            float* dst = out0 + (size_t)(n*64 + c)*HW256 + p0 + tb;
            float4v o = *(float4v*)dst;
#pragma unroll
            for (int r = 0; r < 4; ++r) o[r] += acc2[mt][nt][r] + add;
            *(float4v*)dst = o;
        }
}

// ---------------------------------------------------------------------------
extern "C" void kernel_launch(void* const* d_in, const int* in_sizes, int n_in,
                              void* d_out, int out_size, void* d_ws, size_t ws_size,
                              hipStream_t stream)
{
    (void)in_sizes; (void)n_in; (void)out_size; (void)ws_size;
    const float* x    = (const float*)d_in[0];
    const float* w7a  = (const float*)d_in[1];
    const float* b7a  = (const float*)d_in[2];
    const float* w1   = (const float*)d_in[3];
    const float* b1   = (const float*)d_in[4];
    const float* g1   = (const float*)d_in[5];
    const float* be1  = (const float*)d_in[6];
    const float* w3a  = (const float*)d_in[7];
    const float* b3a  = (const float*)d_in[8];
    const float* g3a  = (const float*)d_in[9];
    const float* be3a = (const float*)d_in[10];
    const float* w3b  = (const float*)d_in[11];
    const float* b3b  = (const float*)d_in[12];
    const float* g3b  = (const float*)d_in[13];
    const float* be3b = (const float*)d_in[14];
    const float* w3c  = (const float*)d_in[15];
    const float* b3c  = (const float*)d_in[16];
    const float* g3c  = (const float*)d_in[17];
    const float* be3c = (const float*)d_in[18];
    const float* w7b  = (const float*)d_in[19];
    const float* b7b  = (const float*)d_in[20];
    const float* akw  = (const float*)d_in[21];
    const float* akb  = (const float*)d_in[22];
    const float* avw  = (const float*)d_in[25];
    const float* avb  = (const float*)d_in[26];
    const float* arw  = (const float*)d_in[27];
    const float* arb  = (const float*)d_in[28];
    const float* lng  = (const float*)d_in[29];
    const float* lnb  = (const float*)d_in[30];
    const float* fc1w = (const float*)d_in[31];
    const float* fc1b = (const float*)d_in[32];
    const float* fc2w = (const float*)d_in[33];
    const float* fc2b = (const float*)d_in[34];

    float* ws   = (float*)d_ws;
    float* o_y2 = ws;                       // 2,097,152
    float* o_y  = o_y2 + 2097152;           // 8,388,608
    float* o_z1 = o_y  + 8388608;           // 8,388,608 (f32 z1; later bf16 z_ci)
    float* o_z2 = o_z1 + 8388608;           // 8,388,608 (first xci bf16, then f32 z2)
    float* o_k  = o_z2 + 8388608;           // 524,288
    float* o_st = o_k  + 524288;            // 64
    float* o_S  = o_st + 64;                // 512
    float* o_ad = o_S  + 512;               // 512
    float* p7aS = o_ad + 512;               // 50,176 f32 slot (holds 57,344 bf16)
    float* p1   = p7aS + 50176;             // 256
    float* p3a  = p1   + 256;   float* q3a = p3a + 2304;
    float* p3b  = q3a  + 16;    float* q3b = p3b + 2304;
    float* p3c  = q3b  + 16;    float* q3c = p3c + 2304;
    unsigned short* pwB  = (unsigned short*)(q3c + 16);  // 57,344 bf16
    unsigned short* pwT1 = pwB + 57344;                  // 4,096 bf16
    unsigned short* pwT2 = pwT1 + 4096;                  // 4,096 bf16

    unsigned short* p7aB = (unsigned short*)p7aS;
    unsigned short* xci  = (unsigned short*)o_z2;  // bf16 [8][4][16384][16] = 16.8 MB
    unsigned short* z_ci = (unsigned short*)o_z1;  // bf16 [8][256][256][16] = 16.8 MB

    float* out0 = (float*)d_out;

    prepack<<<224, 256, 0, stream>>>(w7a, w1, w3a,b3a,g3a,be3a, w3b,b3b,g3b,be3b,
                                     w3c,b3c,g3c,be3c, w7b, fc1w, fc2w,
                                     p7aB, p1, p3a,q3a, p3b,q3b, p3c,q3c, pwB, pwT1, pwT2);
    x_to_ci<<<2048, 256, 0, stream>>>(x, xci);
    conv7a_mfma<<<dim3(8,8,8), 256, 0, stream>>>(xci, p7aB, b7a, p1, b1, g1, be1, o_y2);
    resize_128_256<<<dim3(16,16,128), dim3(16,16), 0, stream>>>(o_y2, o_y);
    conv3x3_bn<0><<<dim3(16,16,8), dim3(16,16), 0, stream>>>(o_y,  p3a, q3a, nullptr, o_z1, nullptr);
    conv3x3_bn<1><<<dim3(16,16,8), dim3(16,16), 0, stream>>>(o_z1, p3b, q3b, o_y,     o_z2, nullptr);
    conv3x3_bn<2><<<dim3(16,16,8), dim3(16,16), 0, stream>>>(o_z2, p3c, q3c, o_y,     nullptr, z_ci);
    conv7b_mfma<<<dim3(16,16,8), 256, 0, stream>>>(z_ci, pwB, out0);
    bilin_k<<<dim3(16,16,8), dim3(16,16), 0, stream>>>(out0, x, b7b, akw, akb, o_k);
    softmax_stats<<<8, 1024, 0, stream>>>(o_k, o_st);
    att_wsum<<<dim3(8,8), 256, 0, stream>>>(out0, o_k, o_st, o_S);
    ctx_addc<<<1, 512, 0, stream>>>(o_S, o_st, avw, avb, arw, arb, o_ad);
    transformer_mfma<<<4096, 256, 0, stream>>>(out0, o_ad, lng, lnb, pwT1, fc1b, pwT2, fc2b);
}

// Round 7
// 497.691 us; speedup vs baseline: 7.1765x; 1.2510x over previous
//
#include <hip/hip_runtime.h>
#include <math.h>

#define DI __device__ __forceinline__
#define HW128 (128*128)
#define HW256 (256*256)

__device__ const float BN_RS = 0.9999950000374997f; // 1/sqrt(1+1e-5)

DI float leakyf(float x){ return x >= 0.f ? x : 0.2f*x; }

DI unsigned short f2bf(float f){
    unsigned u = __float_as_uint(f);
    return (unsigned short)((u + 0x7fffu + ((u >> 16) & 1u)) >> 16);
}
DI void unpack2(unsigned u, float& lo, float& hi){
    lo = __uint_as_float(u << 16);
    hi = __uint_as_float(u & 0xffff0000u);
}
DI void load8(const uint4* s, size_t idx, unsigned* d){
    uint4 t0 = s[idx], t1 = s[idx + 1];
    d[0]=t0.x; d[1]=t0.y; d[2]=t0.z; d[3]=t0.w;
    d[4]=t1.x; d[5]=t1.y; d[6]=t1.z; d[7]=t1.w;
}

typedef __attribute__((ext_vector_type(8))) short short8v;
typedef __attribute__((ext_vector_type(4))) float float4v;

// ---------------------------------------------------------------------------
// Prepack: bf16 MFMA weights for conv7a ([g][ks28][oc16][k32]), conv7b
// ([ks28][oc64][k32]), conv3x3 trio ([ks6][oc16][k32], BN-folded, kx=3 pad),
// f32 1x1, q3 biases, bf16 fc1/fc2.
// ---------------------------------------------------------------------------
__global__ __launch_bounds__(256) void prepack(
    const float* __restrict__ w7a, const float* __restrict__ w1,
    const float* __restrict__ w3a, const float* __restrict__ b3a, const float* __restrict__ g3a, const float* __restrict__ be3a,
    const float* __restrict__ w3b, const float* __restrict__ b3b, const float* __restrict__ g3b, const float* __restrict__ be3b,
    const float* __restrict__ w3c, const float* __restrict__ b3c, const float* __restrict__ g3c, const float* __restrict__ be3c,
    const float* __restrict__ w7b, const float* __restrict__ fc1w, const float* __restrict__ fc2w,
    unsigned short* __restrict__ p7aB, float* __restrict__ p1,
    float* __restrict__ q3a, float* __restrict__ q3b, float* __restrict__ q3c,
    unsigned short* __restrict__ w3aB, unsigned short* __restrict__ w3bB, unsigned short* __restrict__ w3cB,
    unsigned short* __restrict__ pwB,
    unsigned short* __restrict__ pwT1, unsigned short* __restrict__ pwT2)
{
    int i = blockIdx.x * 256 + threadIdx.x;
    if (i < 57344) {                                      // conv7a MFMA weights
        int g = i / 14336, rem = i - g*14336;
        int ks = rem >> 9, oc = (rem >> 5) & 15, k = rem & 31;
        int ky = ks >> 2, kx = ((ks & 3) << 1) + (k >> 4), ic = g*16 + (k & 15);
        p7aB[i] = (kx < 7) ? f2bf(w7a[(oc*64 + ic)*49 + ky*7 + kx]) : (unsigned short)0;
    }
    if (i < 57344) {                                      // conv7b MFMA weights
        int ks = i >> 11, oc = (i >> 5) & 63, k = i & 31;
        int ky = ks >> 2, kx = ((ks & 3) << 1) + (k >> 4), ic = k & 15;
        pwB[i] = (kx < 7) ? f2bf(w7b[((oc*16 + ic)*7 + ky)*7 + kx]) : (unsigned short)0;
    }
    if (i < 3072) {                                       // conv3 MFMA weights ×3
        int ks = i >> 9, oc = (i >> 5) & 15, k = i & 31;
        int ky = ks >> 1, kx = ((ks & 1) << 1) + (k >> 4), ic = k & 15;
        if (kx < 3) {
            int src = (oc*16 + ic)*9 + ky*3 + kx;
            w3aB[i] = f2bf(w3a[src] * (g3a[oc]*BN_RS));
            w3bB[i] = f2bf(w3b[src] * (g3b[oc]*BN_RS));
            w3cB[i] = f2bf(w3c[src] * (g3c[oc]*BN_RS));
        } else {
            w3aB[i] = 0; w3bB[i] = 0; w3cB[i] = 0;
        }
    }
    if (i < 256) { int oc = i & 15, ic = i >> 4; p1[i] = w1[oc*16 + ic]; }
    if (i < 16) {
        q3a[i] = b3a[i]*(g3a[i]*BN_RS) + be3a[i];
        q3b[i] = b3b[i]*(g3b[i]*BN_RS) + be3b[i];
        q3c[i] = b3c[i]*(g3c[i]*BN_RS) + be3c[i];
    }
    if (i < 4096) { pwT1[i] = f2bf(fc1w[i]); pwT2[i] = f2bf(fc2w[i]); }
}

// ---------------------------------------------------------------------------
// x (8,64,128,128) f32 -> xci bf16 [n][g=ic/16][y*128+x][16]
// ---------------------------------------------------------------------------
__global__ __launch_bounds__(256) void x_to_ci(
    const float* __restrict__ x, unsigned short* __restrict__ xci)
{
    int idx = blockIdx.x*256 + threadIdx.x;   // 524,288
    int p = idx & 16383, gn = idx >> 14;
    int g = gn & 3, n = gn >> 2;
    const float* xb = x + (size_t)(n*64 + g*16)*HW128 + p;
    unsigned q[8];
#pragma unroll
    for (int h = 0; h < 8; ++h) {
        float a0 = xb[(size_t)(2*h)*HW128];
        float a1 = xb[(size_t)(2*h + 1)*HW128];
        q[h] = (unsigned)f2bf(a0) | ((unsigned)f2bf(a1) << 16);
    }
    uint4* dst = (uint4*)xci + (size_t)idx*2;
    dst[0] = make_uint4(q[0], q[1], q[2], q[3]);
    dst[1] = make_uint4(q[4], q[5], q[6], q[7]);
}

// ---------------------------------------------------------------------------
// conv7x7 64->16 MFMA + f32 1x1 + leaky + BN epilogue -> y2_ci bf16 [n][p][16]
// ---------------------------------------------------------------------------
__global__ __launch_bounds__(256) void conv7a_mfma(
    const unsigned short* __restrict__ xci,
    const unsigned short* __restrict__ pw,
    const float* __restrict__ b7a, const float* __restrict__ p1,
    const float* __restrict__ b1, const float* __restrict__ bng,
    const float* __restrict__ bnb, unsigned short* __restrict__ y2ci)
{
    __shared__ __align__(16) unsigned char lds[17408];
    unsigned short* tile = (unsigned short*)lds;   // [22][24][16] bf16
    float* P16 = (float*)lds;                      // [256][17] f32

    const int tid = threadIdx.x;
    const int n = blockIdx.z, ox = blockIdx.x*16, oy = blockIdx.y*16;
    const int w = tid >> 6, l = tid & 63, lg = l >> 4, ln = l & 15;

    float4v acc[4];
#pragma unroll
    for (int mi = 0; mi < 4; ++mi) acc[mi] = (float4v){0.f,0.f,0.f,0.f};

    const uint4* xc4 = (const uint4*)xci;
    uint4* tl4 = (uint4*)tile;
    const short8v* Bb = (const short8v*)pw;

    for (int g = 0; g < 4; ++g) {
        __syncthreads();
        for (int u = tid; u < 1056; u += 256) {
            int r = u / 48, s = u - r*48;
            int y = oy + r - 3, xcol = ox + (s >> 1) - 3;
            uint4 v = make_uint4(0u,0u,0u,0u);
            if (y >= 0 && y < 128 && xcol >= 0 && xcol < 128)
                v = xc4[((size_t)(n*4 + g)*16384 + y*128 + xcol)*2 + (s & 1)];
            tl4[u] = v;
        }
        __syncthreads();
        for (int ks = 0; ks < 28; ++ks) {
            const int ky = ks >> 2, kxp = (ks & 3) << 1;
            short8v b = Bb[(g*28 + ks)*64 + ln*4 + lg];
            short8v a[4];
#pragma unroll
            for (int mi = 0; mi < 4; ++mi) {
                int row = (4*w + mi) + ky;
                a[mi] = *(const short8v*)(tile + (row*24 + ln + kxp)*16 + lg*8);
            }
#pragma unroll
            for (int mi = 0; mi < 4; ++mi)
                acc[mi] = __builtin_amdgcn_mfma_f32_16x16x32_bf16(a[mi], b, acc[mi], 0, 0, 0);
        }
    }
    __syncthreads();
    const float bo = b7a[ln];
#pragma unroll
    for (int mi = 0; mi < 4; ++mi)
#pragma unroll
        for (int r = 0; r < 4; ++r)
            P16[((4*w + mi)*16 + lg*4 + r)*17 + ln] = leakyf(acc[mi][r] + bo);
    __syncthreads();
    const int py = tid >> 4, pxx = tid & 15;
    float lv[16];
#pragma unroll
    for (int ic = 0; ic < 16; ++ic) lv[ic] = P16[tid*17 + ic];
    float u16[16];
#pragma unroll
    for (int o = 0; o < 16; ++o) {
        float u = b1[o];
#pragma unroll
        for (int ic = 0; ic < 16; ++ic) u += lv[ic] * p1[ic*16 + o];
        u = leakyf(u);
        u16[o] = u * (bng[o]*BN_RS) + bnb[o];
    }
    const int p = (oy + py)*128 + ox + pxx;
    unsigned q[8];
#pragma unroll
    for (int h = 0; h < 8; ++h)
        q[h] = (unsigned)f2bf(u16[2*h]) | ((unsigned)f2bf(u16[2*h+1]) << 16);
    uint4* dst = (uint4*)y2ci + (size_t)(n*16384 + p)*2;
    dst[0] = make_uint4(q[0], q[1], q[2], q[3]);
    dst[1] = make_uint4(q[4], q[5], q[6], q[7]);
}

// ---------------------------------------------------------------------------
// Bilinear resize 128->256 on ci layout: y2_ci [n][16384][16] -> y_ci
// [n][65536][16]. Each neighbor row is 32B contiguous (2x uint4).
// ---------------------------------------------------------------------------
__global__ __launch_bounds__(256) void resize_ci(
    const unsigned short* __restrict__ y2ci, unsigned short* __restrict__ yci)
{
    const int n = blockIdx.z;
    const int ox = blockIdx.x*16 + threadIdx.x;
    const int oy = blockIdx.y*16 + threadIdx.y;
    float sy = oy * (127.f/255.f), sx = ox * (127.f/255.f);
    int y0 = min((int)sy, 126), x0 = min((int)sx, 126);
    float fy = sy - y0, fx = sx - x0;
    const uint4* src = (const uint4*)y2ci;
    size_t i00 = ((size_t)n*16384 + y0*128 + x0)*2;
    unsigned A00[8], A01[8], A10[8], A11[8];
    load8(src, i00,       A00);
    load8(src, i00 + 2,   A01);
    load8(src, i00 + 256, A10);
    load8(src, i00 + 258, A11);
    unsigned q[8];
#pragma unroll
    for (int h = 0; h < 8; ++h) {
        float l00, h00, l01, h01, l10, h10, l11, h11;
        unpack2(A00[h], l00, h00); unpack2(A01[h], l01, h01);
        unpack2(A10[h], l10, h10); unpack2(A11[h], l11, h11);
        float lo = (l00*(1.f-fx) + l01*fx)*(1.f-fy) + (l10*(1.f-fx) + l11*fx)*fy;
        float hi = (h00*(1.f-fx) + h01*fx)*(1.f-fy) + (h10*(1.f-fx) + h11*fx)*fy;
        q[h] = (unsigned)f2bf(lo) | ((unsigned)f2bf(hi) << 16);
    }
    uint4* dst = (uint4*)yci + ((size_t)n*65536 + oy*256 + ox)*2;
    dst[0] = make_uint4(q[0], q[1], q[2], q[3]);
    dst[1] = make_uint4(q[4], q[5], q[6], q[7]);
}

// ---------------------------------------------------------------------------
// 3x3 conv 16->16 via MFMA implicit GEMM on ci layout, BN pre-folded.
// MODE 0: leaky -> ci.  MODE 1: + residual(res_ci) -> ci.
// K: 6 steps = 3 ky x 2 kx-pairs (kx=3 zero-pad).
// ---------------------------------------------------------------------------
template<int MODE>
__global__ __launch_bounds__(256) void conv3_mfma(
    const unsigned short* __restrict__ in_ci,
    const unsigned short* __restrict__ wB, const float* __restrict__ q3,
    const unsigned short* __restrict__ res_ci,
    unsigned short* __restrict__ out_ci)
{
    __shared__ __align__(16) unsigned char lds[17408];
    unsigned short* tile = (unsigned short*)lds;   // [18][20][16] bf16 (11,520 B)
    float* P16 = (float*)lds;                      // [256][17] f32

    const int tid = threadIdx.x;
    const int n = blockIdx.z, ox = blockIdx.x*16, oy = blockIdx.y*16;
    const int w = tid >> 6, l = tid & 63, lg = l >> 4, ln = l & 15;

    const uint4* zc = (const uint4*)in_ci;
    uint4* tl4 = (uint4*)tile;
    for (int u = tid; u < 720; u += 256) {
        int r = u / 40, s = u - r*40;
        int y = oy + r - 1, xcol = ox + (s >> 1) - 1;
        uint4 v = make_uint4(0u,0u,0u,0u);
        if (y >= 0 && y < 256 && xcol >= 0 && xcol < 256)
            v = zc[((size_t)n*65536 + y*256 + xcol)*2 + (s & 1)];
        tl4[u] = v;
    }
    __syncthreads();

    float4v acc[4];
#pragma unroll
    for (int mi = 0; mi < 4; ++mi) acc[mi] = (float4v){0.f,0.f,0.f,0.f};
    const short8v* Bb = (const short8v*)wB;
#pragma unroll
    for (int ks = 0; ks < 6; ++ks) {
        const int ky = ks >> 1, kxp = (ks & 1) << 1;
        short8v b = Bb[(ks*16 + ln)*4 + lg];
        short8v a[4];
#pragma unroll
        for (int mi = 0; mi < 4; ++mi) {
            int row = (4*w + mi) + ky;
            a[mi] = *(const short8v*)(tile + (row*20 + ln + kxp)*16 + lg*8);
        }
#pragma unroll
        for (int mi = 0; mi < 4; ++mi)
            acc[mi] = __builtin_amdgcn_mfma_f32_16x16x32_bf16(a[mi], b, acc[mi], 0, 0, 0);
    }
    __syncthreads();
#pragma unroll
    for (int mi = 0; mi < 4; ++mi)
#pragma unroll
        for (int r = 0; r < 4; ++r)
            P16[((4*w + mi)*16 + lg*4 + r)*17 + ln] = acc[mi][r];
    __syncthreads();

    const int py = tid >> 4, pxx = tid & 15;
    const int p = (oy + py)*256 + ox + pxx;
    float u16[16];
#pragma unroll
    for (int o = 0; o < 16; ++o) u16[o] = P16[tid*17 + o] + q3[o];
    if (MODE == 0) {
#pragma unroll
        for (int o = 0; o < 16; ++o) u16[o] = leakyf(u16[o]);
    } else {
        unsigned R[8];
        load8((const uint4*)res_ci, ((size_t)n*65536 + p)*2, R);
#pragma unroll
        for (int h = 0; h < 8; ++h) {
            float lo, hi; unpack2(R[h], lo, hi);
            u16[2*h] += lo; u16[2*h+1] += hi;
        }
    }
    unsigned q[8];
#pragma unroll
    for (int h = 0; h < 8; ++h)
        q[h] = (unsigned)f2bf(u16[2*h]) | ((unsigned)f2bf(u16[2*h+1]) << 16);
    uint4* dst = (uint4*)out_ci + ((size_t)n*65536 + p)*2;
    dst[0] = make_uint4(q[0], q[1], q[2], q[3]);
    dst[1] = make_uint4(q[4], q[5], q[6], q[7]);
}

// ---------------------------------------------------------------------------
// conv7x7 16->64 via MFMA implicit GEMM (verified R4).
// ---------------------------------------------------------------------------
__global__ __launch_bounds__(256) void conv7b_mfma(
    const unsigned short* __restrict__ z_ci,
    const unsigned short* __restrict__ pwB,
    float* __restrict__ out0)
{
    __shared__ __align__(16) unsigned short tile[22*24*16]; // 16,896 B
    const int tid = threadIdx.x;
    const int n = blockIdx.z, ox = blockIdx.x*16, oy = blockIdx.y*16;

    const uint4* zc = (const uint4*)z_ci;
    uint4* tl4 = (uint4*)tile;
    for (int u = tid; u < 1056; u += 256) {
        int r = u / 48, s = u - r*48;
        int y = oy + r - 3, xcol = ox + (s >> 1) - 3;
        uint4 v = make_uint4(0u, 0u, 0u, 0u);
        if (y >= 0 && y < 256 && xcol >= 0 && xcol < 256)
            v = zc[(size_t)((n*256 + y)*256 + xcol)*2 + (s & 1)];
        tl4[u] = v;
    }
    __syncthreads();

    const int w = tid >> 6, l = tid & 63;
    const int lg = l >> 4, ln = l & 15;
    float4v acc[4][4];
#pragma unroll
    for (int mi = 0; mi < 4; ++mi)
#pragma unroll
        for (int nt = 0; nt < 4; ++nt)
            acc[mi][nt] = (float4v){0.f, 0.f, 0.f, 0.f};

    const short8v* Bb = (const short8v*)pwB;
    for (int ks = 0; ks < 28; ++ks) {
        const int ky = ks >> 2, kxp = (ks & 3) << 1;
        short8v a[4], b[4];
#pragma unroll
        for (int mi = 0; mi < 4; ++mi) {
            int row = (4*w + mi) + ky;
            int off = (row*24 + ln + kxp)*16 + lg*8;
            a[mi] = *(const short8v*)(tile + off);
        }
#pragma unroll
        for (int nt = 0; nt < 4; ++nt)
            b[nt] = Bb[ks*256 + nt*64 + ln*4 + lg];
#pragma unroll
        for (int mi = 0; mi < 4; ++mi)
#pragma unroll
            for (int nt = 0; nt < 4; ++nt)
                acc[mi][nt] = __builtin_amdgcn_mfma_f32_16x16x32_bf16(
                    a[mi], b[nt], acc[mi][nt], 0, 0, 0);
    }

#pragma unroll
    for (int mi = 0; mi < 4; ++mi) {
        const int yy = oy + 4*w + mi;
#pragma unroll
        for (int nt = 0; nt < 4; ++nt) {
            const int oc = nt*16 + ln;
            float* dst = out0 + (size_t)(n*64 + oc)*HW256 + yy*256 + ox + lg*4;
            *(float4v*)dst = acc[mi][nt];
        }
    }
}

// ---------------------------------------------------------------------------
// Epilogue: out0 += bias + bilinear(x); emit attention key logit k.
// ---------------------------------------------------------------------------
__global__ __launch_bounds__(256) void bilin_k(
    float* __restrict__ out0, const float* __restrict__ x,
    const float* __restrict__ bias,
    const float* __restrict__ akw, const float* __restrict__ akb,
    float* __restrict__ kbuf)
{
    const int tx = threadIdx.x, ty = threadIdx.y;
    const int n = blockIdx.z;
    const int ohx = blockIdx.x*16 + tx, ohy = blockIdx.y*16 + ty;
    float sy = ohy * (127.f/255.f), sx = ohx * (127.f/255.f);
    int y0 = min((int)sy, 126), x0 = min((int)sx, 126);
    float fy = sy - y0, fx = sx - x0;
    const float* xb = x + n*64*HW128;
    const int p = ohy*256 + ohx;
    float kacc = akb[0];
#pragma unroll
    for (int o = 0; o < 64; ++o) {
        const float* xc = xb + o*HW128;
        float v00 = xc[y0*128 + x0],       v01 = xc[y0*128 + x0 + 1];
        float v10 = xc[y0*128 + 128 + x0], v11 = xc[y0*128 + 128 + x0 + 1];
        float idv = (v00*(1.f-fx) + v01*fx)*(1.f-fy) + (v10*(1.f-fx) + v11*fx)*fy;
        size_t idx = (size_t)(n*64 + o)*HW256 + p;
        float u = out0[idx] + bias[o] + idv;
        out0[idx] = u;
        kacc += akw[o] * u;
    }
    kbuf[n*65536 + p] = kacc;
}

// ---------------------------------------------------------------------------
// Softmax stats per image.
// ---------------------------------------------------------------------------
__global__ __launch_bounds__(1024) void softmax_stats(
    const float* __restrict__ kb, float* __restrict__ st)
{
    __shared__ float red[16];
    __shared__ float bc;
    const int n = blockIdx.x, tid = threadIdx.x;
    const float* kp = kb + n*65536;
    float mx = -3.0e38f;
    for (int i = tid; i < 65536; i += 1024) mx = fmaxf(mx, kp[i]);
#pragma unroll
    for (int off = 1; off < 64; off <<= 1) mx = fmaxf(mx, __shfl_xor(mx, off));
    int w = tid >> 6, l = tid & 63;
    if (l == 0) red[w] = mx;
    __syncthreads();
    if (tid == 0) {
        float m = red[0];
        for (int i = 1; i < 16; ++i) m = fmaxf(m, red[i]);
        bc = m;
    }
    __syncthreads();
    float MX = bc;
    float s = 0.f;
    for (int i = tid; i < 65536; i += 1024) s += __expf(kp[i] - MX);
#pragma unroll
    for (int off = 1; off < 64; off <<= 1) s += __shfl_xor(s, off);
    __syncthreads();
    if (l == 0) red[w] = s;
    __syncthreads();
    if (tid == 0) {
        float S = 0.f;
        for (int i = 0; i < 16; ++i) S += red[i];
        st[n] = MX; st[8 + n] = 1.f / S;
    }
}

// ---------------------------------------------------------------------------
// S[n,c] = sum_p exp(k-mx) * out0[n,c,p].
// ---------------------------------------------------------------------------
__global__ __launch_bounds__(256) void att_wsum(
    const float* __restrict__ out0, const float* __restrict__ kb,
    const float* __restrict__ st, float* __restrict__ S)
{
    const int cg = blockIdx.x, n = blockIdx.y, c0 = cg*8;
    const float mx = st[n];
    const float* kp = kb + n*65536;
    const float* base = out0 + (size_t)(n*64 + c0)*HW256;
    float acc[8];
#pragma unroll
    for (int c = 0; c < 8; ++c) acc[c] = 0.f;
    for (int p = threadIdx.x; p < 65536; p += 256) {
        float e = __expf(kp[p] - mx);
#pragma unroll
        for (int c = 0; c < 8; ++c) acc[c] += e * base[c*HW256 + p];
    }
#pragma unroll
    for (int c = 0; c < 8; ++c)
#pragma unroll
        for (int off = 1; off < 64; off <<= 1) acc[c] += __shfl_xor(acc[c], off);
    __shared__ float red[4][8];
    int w = threadIdx.x >> 6, l = threadIdx.x & 63;
    if (l == 0) {
#pragma unroll
        for (int c = 0; c < 8; ++c) red[w][c] = acc[c];
    }
    __syncthreads();
    if (threadIdx.x < 8)
        S[n*64 + c0 + threadIdx.x] =
            red[0][threadIdx.x] + red[1][threadIdx.x] + red[2][threadIdx.x] + red[3][threadIdx.x];
}

// ---------------------------------------------------------------------------
// context + per-(n,c) attention addend.
// ---------------------------------------------------------------------------
__global__ __launch_bounds__(512) void ctx_addc(
    const float* __restrict__ S, const float* __restrict__ st,
    const float* __restrict__ avw, const float* __restrict__ avb,
    const float* __restrict__ arw, const float* __restrict__ arb,
    float* __restrict__ addc)
{
    __shared__ float ctx[8][8];
    const int tid = threadIdx.x;
    if (tid < 64) {
        int n = tid >> 3, vc = tid & 7;
        float s = 0.f;
        for (int c = 0; c < 64; ++c) s += avw[vc*64 + c] * S[n*64 + c];
        ctx[n][vc] = s * st[8 + n] + avb[vc];
    }
    __syncthreads();
    int n = tid >> 6, c = tid & 63;
    float a = arb[c];
#pragma unroll
    for (int vc = 0; vc < 8; ++vc) a += arw[c*8 + vc] * ctx[n][vc];
    addc[n*64 + c] = a;
}

// ---------------------------------------------------------------------------
// Transformer via MFMA (verified R5).
// ---------------------------------------------------------------------------
__global__ __launch_bounds__(256) void transformer_mfma(
    float* __restrict__ out0, const float* __restrict__ addc,
    const float* __restrict__ lng, const float* __restrict__ lnb,
    const unsigned short* __restrict__ W1b, const float* __restrict__ fc1b,
    const unsigned short* __restrict__ W2b, const float* __restrict__ fc2b)
{
    __shared__ __align__(16) unsigned char lds[53248];
    float*          Xf = (float*)lds;                         // [128][68] f32
    unsigned short* Hb = (unsigned short*)lds;                // [128][72] bf16
    unsigned short* Xb = (unsigned short*)(lds + 34816);      // [128][72] bf16

    const int tid = threadIdx.x;
    const int n = blockIdx.x >> 9;
    const int p0 = (blockIdx.x & 511) << 7;
    const float* ac = addc + n*64;

#pragma unroll
    for (int k = 0; k < 8; ++k) {
        int v = k*256 + tid;
        int c = v >> 5, i4 = (v & 31) << 2;
        float4v q = *(const float4v*)(out0 + (size_t)(n*64 + c)*HW256 + p0 + i4);
        float a = ac[c];
#pragma unroll
        for (int r = 0; r < 4; ++r) Xf[(i4 + r)*68 + c] = q[r] + a;
    }
    __syncthreads();

    if (tid < 128) {
        float t[64];
#pragma unroll
        for (int c4 = 0; c4 < 16; ++c4) {
            float4v q = *(const float4v*)&Xf[tid*68 + c4*4];
#pragma unroll
            for (int r = 0; r < 4; ++r) t[c4*4 + r] = q[r];
        }
        float mu = 0.f;
#pragma unroll
        for (int c = 0; c < 64; ++c) mu += t[c];
        mu *= (1.f/64.f);
        float var = 0.f;
#pragma unroll
        for (int c = 0; c < 64; ++c) { float d = t[c] - mu; var += d*d; }
        var *= (1.f/64.f);
        float rs = rsqrtf(var + 1e-5f);
#pragma unroll
        for (int c8 = 0; c8 < 8; ++c8) {
            short8v pk;
#pragma unroll
            for (int e = 0; e < 8; ++e) {
                int c = c8*8 + e;
                pk[e] = (short)f2bf((t[c] - mu)*rs*lng[c] + lnb[c]);
            }
            *(short8v*)&Xb[tid*72 + c8*8] = pk;
        }
    }
    __syncthreads();

    const int w = tid >> 6, l = tid & 63, lg = l >> 4, ln = l & 15;

    float4v acc1[2][4];
#pragma unroll
    for (int mt = 0; mt < 2; ++mt)
#pragma unroll
        for (int nt = 0; nt < 4; ++nt) acc1[mt][nt] = (float4v){0.f,0.f,0.f,0.f};
#pragma unroll
    for (int kk = 0; kk < 2; ++kk) {
        short8v a[2], b[4];
#pragma unroll
        for (int mt = 0; mt < 2; ++mt)
            a[mt] = *(const short8v*)&Xb[(w*32 + mt*16 + ln)*72 + kk*32 + lg*8];
#pragma unroll
        for (int nt = 0; nt < 4; ++nt)
            b[nt] = *(const short8v*)&W1b[(nt*16 + ln)*64 + kk*32 + lg*8];
#pragma unroll
        for (int mt = 0; mt < 2; ++mt)
#pragma unroll
            for (int nt = 0; nt < 4; ++nt)
                acc1[mt][nt] = __builtin_amdgcn_mfma_f32_16x16x32_bf16(
                    a[mt], b[nt], acc1[mt][nt], 0, 0, 0);
    }
#pragma unroll
    for (int mt = 0; mt < 2; ++mt)
#pragma unroll
        for (int nt = 0; nt < 4; ++nt) {
            int j = nt*16 + ln;
            float bj = fc1b[j];
#pragma unroll
            for (int r = 0; r < 4; ++r) {
                int token = w*32 + mt*16 + lg*4 + r;
                float m = acc1[mt][nt][r] + bj;
                float g = 0.5f*m*(1.f + erff(m*0.70710678118654752f));
                Hb[token*72 + j] = f2bf(g);
            }
        }
    __syncthreads();

    float4v acc2[2][4];
#pragma unroll
    for (int mt = 0; mt < 2; ++mt)
#pragma unroll
        for (int nt = 0; nt < 4; ++nt) acc2[mt][nt] = (float4v){0.f,0.f,0.f,0.f};
#pragma unroll
    for (int kk = 0; kk < 2; ++kk) {
        short8v a[2], b[4];
#pragma unroll
        for (int mt = 0; mt < 2; ++mt)
            a[mt] = *(const short8v*)&Hb[(w*32 + mt*16 + ln)*72 + kk*32 + lg*8];
#pragma unroll
        for (int nt = 0; nt < 4; ++nt)
            b[nt] = *(const short8v*)&W2b[(nt*16 + ln)*64 + kk*32 + lg*8];
#pragma unroll
        for (int mt = 0; mt < 2; ++mt)
#pragma unroll
            for (int nt = 0; nt < 4; ++nt)
                acc2[mt][nt] = __builtin_amdgcn_mfma_f32_16x16x32_bf16(
                    a[mt], b[nt], acc2[mt][nt], 0, 0, 0);
    }
#pragma unroll
    for (int mt = 0; mt < 2; ++mt)
#pragma unroll
        for (int nt = 0; nt < 4; ++nt) {
            int c = nt*16 + ln;
            int tb = w*32 + mt*16 + lg*4;
            float add = fc2b[c] + ac[c];
            float* dst = out0 + (size_t)(n*64 + c)*HW256 + p0 + tb;
            float4v o = *(float4v*)dst;
#pragma unroll
            for (int r = 0; r < 4; ++r) o[r] += acc2[mt][nt][r] + add;
            *(float4v*)dst = o;
        }
}

// ---------------------------------------------------------------------------
extern "C" void kernel_launch(void* const* d_in, const int* in_sizes, int n_in,
                              void* d_out, int out_size, void* d_ws, size_t ws_size,
                              hipStream_t stream)
{
    (void)in_sizes; (void)n_in; (void)out_size; (void)ws_size;
    const float* x    = (const float*)d_in[0];
    const float* w7a  = (const float*)d_in[1];
    const float* b7a  = (const float*)d_in[2];
    const float* w1   = (const float*)d_in[3];
    const float* b1   = (const float*)d_in[4];
    const float* g1   = (const float*)d_in[5];
    const float* be1  = (const float*)d_in[6];
    const float* w3a  = (const float*)d_in[7];
    const float* b3a  = (const float*)d_in[8];
    const float* g3a  = (const float*)d_in[9];
    const float* be3a = (const float*)d_in[10];
    const float* w3b  = (const float*)d_in[11];
    const float* b3b  = (const float*)d_in[12];
    const float* g3b  = (const float*)d_in[13];
    const float* be3b = (const float*)d_in[14];
    const float* w3c  = (const float*)d_in[15];
    const float* b3c  = (const float*)d_in[16];
    const float* g3c  = (const float*)d_in[17];
    const float* be3c = (const float*)d_in[18];
    const float* w7b  = (const float*)d_in[19];
    const float* b7b  = (const float*)d_in[20];
    const float* akw  = (const float*)d_in[21];
    const float* akb  = (const float*)d_in[22];
    const float* avw  = (const float*)d_in[25];
    const float* avb  = (const float*)d_in[26];
    const float* arw  = (const float*)d_in[27];
    const float* arb  = (const float*)d_in[28];
    const float* lng  = (const float*)d_in[29];
    const float* lnb  = (const float*)d_in[30];
    const float* fc1w = (const float*)d_in[31];
    const float* fc1b = (const float*)d_in[32];
    const float* fc2w = (const float*)d_in[33];
    const float* fc2b = (const float*)d_in[34];

    float* ws   = (float*)d_ws;
    float* o_y2 = ws;                       // y2_ci bf16 (slot 2,097,152 f32)
    float* o_y  = o_y2 + 2097152;           // y_ci bf16 (slot 8,388,608 f32)
    float* o_z1 = o_y  + 8388608;           // z1_ci, then z3_ci bf16
    float* o_z2 = o_z1 + 8388608;           // xci bf16, then z2_ci bf16
    float* o_k  = o_z2 + 8388608;           // 524,288
    float* o_st = o_k  + 524288;            // 64
    float* o_S  = o_st + 64;                // 512
    float* o_ad = o_S  + 512;               // 512
    float* p7aS = o_ad + 512;               // 50,176 f32 slot (holds 57,344 bf16)
    float* p1   = p7aS + 50176;             // 256
    float* q3a  = p1   + 256;               // 16
    float* q3b  = q3a  + 16;
    float* q3c  = q3b  + 16;
    unsigned short* w3aB = (unsigned short*)(q3c + 16);  // 3,072 bf16
    unsigned short* w3bB = w3aB + 3072;
    unsigned short* w3cB = w3bB + 3072;
    unsigned short* pwB  = w3cB + 3072;                  // 57,344 bf16
    unsigned short* pwT1 = pwB + 57344;                  // 4,096 bf16
    unsigned short* pwT2 = pwT1 + 4096;                  // 4,096 bf16

    unsigned short* p7aB = (unsigned short*)p7aS;
    unsigned short* y2ci = (unsigned short*)o_y2;  // [8][16384][16]
    unsigned short* yci  = (unsigned short*)o_y;   // [8][65536][16]
    unsigned short* z1ci = (unsigned short*)o_z1;
    unsigned short* xci  = (unsigned short*)o_z2;  // [8][4][16384][16]
    unsigned short* z2ci = (unsigned short*)o_z2;  // after conv7a consumed xci
    unsigned short* z3ci = (unsigned short*)o_z1;  // overwrites dead z1

    float* out0 = (float*)d_out;

    prepack<<<224, 256, 0, stream>>>(w7a, w1, w3a,b3a,g3a,be3a, w3b,b3b,g3b,be3b,
                                     w3c,b3c,g3c,be3c, w7b, fc1w, fc2w,
                                     p7aB, p1, q3a, q3b, q3c, w3aB, w3bB, w3cB,
                                     pwB, pwT1, pwT2);
    x_to_ci<<<2048, 256, 0, stream>>>(x, xci);
    conv7a_mfma<<<dim3(8,8,8), 256, 0, stream>>>(xci, p7aB, b7a, p1, b1, g1, be1, y2ci);
    resize_ci<<<dim3(16,16,8), dim3(16,16), 0, stream>>>(y2ci, yci);
    conv3_mfma<0><<<dim3(16,16,8), 256, 0, stream>>>(yci,  w3aB, q3a, nullptr, z1ci);
    conv3_mfma<1><<<dim3(16,16,8), 256, 0, stream>>>(z1ci, w3bB, q3b, yci,     z2ci);
    conv3_mfma<1><<<dim3(16,16,8), 256, 0, stream>>>(z2ci, w3cB, q3c, yci,     z3ci);
    conv7b_mfma<<<dim3(16,16,8), 256, 0, stream>>>(z3ci, pwB, out0);
    bilin_k<<<dim3(16,16,8), dim3(16,16), 0, stream>>>(out0, x, b7b, akw, akb, o_k);
    softmax_stats<<<8, 1024, 0, stream>>>(o_k, o_st);
    att_wsum<<<dim3(8,8), 256, 0, stream>>>(out0, o_k, o_st, o_S);
    ctx_addc<<<1, 512, 0, stream>>>(o_S, o_st, avw, avb, arw, arb, o_ad);
    transformer_mfma<<<4096, 256, 0, stream>>>(out0, o_ad, lng, lnb, pwT1, fc1b, pwT2, fc2b);
}

// Round 8
// 489.644 us; speedup vs baseline: 7.2944x; 1.0164x over previous
//
#include <hip/hip_runtime.h>
#include <math.h>

#define DI __device__ __forceinline__
#define HW128 (128*128)
#define HW256 (256*256)

__device__ const float BN_RS = 0.9999950000374997f; // 1/sqrt(1+1e-5)

DI float leakyf(float x){ return x >= 0.f ? x : 0.2f*x; }

DI unsigned short f2bf(float f){
    unsigned u = __float_as_uint(f);
    return (unsigned short)((u + 0x7fffu + ((u >> 16) & 1u)) >> 16);
}
DI void unpack2(unsigned u, float& lo, float& hi){
    lo = __uint_as_float(u << 16);
    hi = __uint_as_float(u & 0xffff0000u);
}
DI void load8(const uint4* s, size_t idx, unsigned* d){
    uint4 t0 = s[idx], t1 = s[idx + 1];
    d[0]=t0.x; d[1]=t0.y; d[2]=t0.z; d[3]=t0.w;
    d[4]=t1.x; d[5]=t1.y; d[6]=t1.z; d[7]=t1.w;
}

typedef __attribute__((ext_vector_type(8))) short short8v;
typedef __attribute__((ext_vector_type(4))) float float4v;

// ---------------------------------------------------------------------------
// Prepack: bf16 MFMA weights for conv7a ([g][ks28][oc16][k32]), conv7b
// ([ks28][oc64][k32]), conv3x3 trio ([ks6][oc16][k32], BN-folded, kx=3 pad),
// f32 1x1, q3 biases, bf16 fc1/fc2.
// ---------------------------------------------------------------------------
__global__ __launch_bounds__(256) void prepack(
    const float* __restrict__ w7a, const float* __restrict__ w1,
    const float* __restrict__ w3a, const float* __restrict__ b3a, const float* __restrict__ g3a, const float* __restrict__ be3a,
    const float* __restrict__ w3b, const float* __restrict__ b3b, const float* __restrict__ g3b, const float* __restrict__ be3b,
    const float* __restrict__ w3c, const float* __restrict__ b3c, const float* __restrict__ g3c, const float* __restrict__ be3c,
    const float* __restrict__ w7b, const float* __restrict__ fc1w, const float* __restrict__ fc2w,
    unsigned short* __restrict__ p7aB, float* __restrict__ p1,
    float* __restrict__ q3a, float* __restrict__ q3b, float* __restrict__ q3c,
    unsigned short* __restrict__ w3aB, unsigned short* __restrict__ w3bB, unsigned short* __restrict__ w3cB,
    unsigned short* __restrict__ pwB,
    unsigned short* __restrict__ pwT1, unsigned short* __restrict__ pwT2)
{
    int i = blockIdx.x * 256 + threadIdx.x;
    if (i < 57344) {                                      // conv7a MFMA weights
        int g = i / 14336, rem = i - g*14336;
        int ks = rem >> 9, oc = (rem >> 5) & 15, k = rem & 31;
        int ky = ks >> 2, kx = ((ks & 3) << 1) + (k >> 4), ic = g*16 + (k & 15);
        p7aB[i] = (kx < 7) ? f2bf(w7a[(oc*64 + ic)*49 + ky*7 + kx]) : (unsigned short)0;
    }
    if (i < 57344) {                                      // conv7b MFMA weights
        int ks = i >> 11, oc = (i >> 5) & 63, k = i & 31;
        int ky = ks >> 2, kx = ((ks & 3) << 1) + (k >> 4), ic = k & 15;
        pwB[i] = (kx < 7) ? f2bf(w7b[((oc*16 + ic)*7 + ky)*7 + kx]) : (unsigned short)0;
    }
    if (i < 3072) {                                       // conv3 MFMA weights ×3
        int ks = i >> 9, oc = (i >> 5) & 15, k = i & 31;
        int ky = ks >> 1, kx = ((ks & 1) << 1) + (k >> 4), ic = k & 15;
        if (kx < 3) {
            int src = (oc*16 + ic)*9 + ky*3 + kx;
            w3aB[i] = f2bf(w3a[src] * (g3a[oc]*BN_RS));
            w3bB[i] = f2bf(w3b[src] * (g3b[oc]*BN_RS));
            w3cB[i] = f2bf(w3c[src] * (g3c[oc]*BN_RS));
        } else {
            w3aB[i] = 0; w3bB[i] = 0; w3cB[i] = 0;
        }
    }
    if (i < 256) { int oc = i & 15, ic = i >> 4; p1[i] = w1[oc*16 + ic]; }
    if (i < 16) {
        q3a[i] = b3a[i]*(g3a[i]*BN_RS) + be3a[i];
        q3b[i] = b3b[i]*(g3b[i]*BN_RS) + be3b[i];
        q3c[i] = b3c[i]*(g3c[i]*BN_RS) + be3c[i];
    }
    if (i < 4096) { pwT1[i] = f2bf(fc1w[i]); pwT2[i] = f2bf(fc2w[i]); }
}

// ---------------------------------------------------------------------------
// x (8,64,128,128) f32 -> xci bf16 [n][g=ic/16][y*128+x][16]
// ---------------------------------------------------------------------------
__global__ __launch_bounds__(256) void x_to_ci(
    const float* __restrict__ x, unsigned short* __restrict__ xci)
{
    int idx = blockIdx.x*256 + threadIdx.x;   // 524,288
    int p = idx & 16383, gn = idx >> 14;
    int g = gn & 3, n = gn >> 2;
    const float* xb = x + (size_t)(n*64 + g*16)*HW128 + p;
    unsigned q[8];
#pragma unroll
    for (int h = 0; h < 8; ++h) {
        float a0 = xb[(size_t)(2*h)*HW128];
        float a1 = xb[(size_t)(2*h + 1)*HW128];
        q[h] = (unsigned)f2bf(a0) | ((unsigned)f2bf(a1) << 16);
    }
    uint4* dst = (uint4*)xci + (size_t)idx*2;
    dst[0] = make_uint4(q[0], q[1], q[2], q[3]);
    dst[1] = make_uint4(q[4], q[5], q[6], q[7]);
}

// ---------------------------------------------------------------------------
// conv7x7 64->16 MFMA + f32 1x1 + leaky + BN epilogue -> y2_ci bf16 [n][p][16]
// ---------------------------------------------------------------------------
__global__ __launch_bounds__(256) void conv7a_mfma(
    const unsigned short* __restrict__ xci,
    const unsigned short* __restrict__ pw,
    const float* __restrict__ b7a, const float* __restrict__ p1,
    const float* __restrict__ b1, const float* __restrict__ bng,
    const float* __restrict__ bnb, unsigned short* __restrict__ y2ci)
{
    __shared__ __align__(16) unsigned char lds[17408];
    unsigned short* tile = (unsigned short*)lds;   // [22][24][16] bf16
    float* P16 = (float*)lds;                      // [256][17] f32

    const int tid = threadIdx.x;
    const int n = blockIdx.z, ox = blockIdx.x*16, oy = blockIdx.y*16;
    const int w = tid >> 6, l = tid & 63, lg = l >> 4, ln = l & 15;

    float4v acc[4];
#pragma unroll
    for (int mi = 0; mi < 4; ++mi) acc[mi] = (float4v){0.f,0.f,0.f,0.f};

    const uint4* xc4 = (const uint4*)xci;
    uint4* tl4 = (uint4*)tile;
    const short8v* Bb = (const short8v*)pw;

    for (int g = 0; g < 4; ++g) {
        __syncthreads();
        for (int u = tid; u < 1056; u += 256) {
            int r = u / 48, s = u - r*48;
            int y = oy + r - 3, xcol = ox + (s >> 1) - 3;
            uint4 v = make_uint4(0u,0u,0u,0u);
            if (y >= 0 && y < 128 && xcol >= 0 && xcol < 128)
                v = xc4[((size_t)(n*4 + g)*16384 + y*128 + xcol)*2 + (s & 1)];
            tl4[u] = v;
        }
        __syncthreads();
        for (int ks = 0; ks < 28; ++ks) {
            const int ky = ks >> 2, kxp = (ks & 3) << 1;
            short8v b = Bb[(g*28 + ks)*64 + ln*4 + lg];
            short8v a[4];
#pragma unroll
            for (int mi = 0; mi < 4; ++mi) {
                int row = (4*w + mi) + ky;
                a[mi] = *(const short8v*)(tile + (row*24 + ln + kxp)*16 + lg*8);
            }
#pragma unroll
            for (int mi = 0; mi < 4; ++mi)
                acc[mi] = __builtin_amdgcn_mfma_f32_16x16x32_bf16(a[mi], b, acc[mi], 0, 0, 0);
        }
    }
    __syncthreads();
    const float bo = b7a[ln];
#pragma unroll
    for (int mi = 0; mi < 4; ++mi)
#pragma unroll
        for (int r = 0; r < 4; ++r)
            P16[((4*w + mi)*16 + lg*4 + r)*17 + ln] = leakyf(acc[mi][r] + bo);
    __syncthreads();
    const int py = tid >> 4, pxx = tid & 15;
    float lv[16];
#pragma unroll
    for (int ic = 0; ic < 16; ++ic) lv[ic] = P16[tid*17 + ic];
    float u16[16];
#pragma unroll
    for (int o = 0; o < 16; ++o) {
        float u = b1[o];
#pragma unroll
        for (int ic = 0; ic < 16; ++ic) u += lv[ic] * p1[ic*16 + o];
        u = leakyf(u);
        u16[o] = u * (bng[o]*BN_RS) + bnb[o];
    }
    const int p = (oy + py)*128 + ox + pxx;
    unsigned q[8];
#pragma unroll
    for (int h = 0; h < 8; ++h)
        q[h] = (unsigned)f2bf(u16[2*h]) | ((unsigned)f2bf(u16[2*h+1]) << 16);
    uint4* dst = (uint4*)y2ci + (size_t)(n*16384 + p)*2;
    dst[0] = make_uint4(q[0], q[1], q[2], q[3]);
    dst[1] = make_uint4(q[4], q[5], q[6], q[7]);
}

// ---------------------------------------------------------------------------
// Bilinear resize 128->256 on ci layout.
// ---------------------------------------------------------------------------
__global__ __launch_bounds__(256) void resize_ci(
    const unsigned short* __restrict__ y2ci, unsigned short* __restrict__ yci)
{
    const int n = blockIdx.z;
    const int ox = blockIdx.x*16 + threadIdx.x;
    const int oy = blockIdx.y*16 + threadIdx.y;
    float sy = oy * (127.f/255.f), sx = ox * (127.f/255.f);
    int y0 = min((int)sy, 126), x0 = min((int)sx, 126);
    float fy = sy - y0, fx = sx - x0;
    const uint4* src = (const uint4*)y2ci;
    size_t i00 = ((size_t)n*16384 + y0*128 + x0)*2;
    unsigned A00[8], A01[8], A10[8], A11[8];
    load8(src, i00,       A00);
    load8(src, i00 + 2,   A01);
    load8(src, i00 + 256, A10);
    load8(src, i00 + 258, A11);
    unsigned q[8];
#pragma unroll
    for (int h = 0; h < 8; ++h) {
        float l00, h00, l01, h01, l10, h10, l11, h11;
        unpack2(A00[h], l00, h00); unpack2(A01[h], l01, h01);
        unpack2(A10[h], l10, h10); unpack2(A11[h], l11, h11);
        float lo = (l00*(1.f-fx) + l01*fx)*(1.f-fy) + (l10*(1.f-fx) + l11*fx)*fy;
        float hi = (h00*(1.f-fx) + h01*fx)*(1.f-fy) + (h10*(1.f-fx) + h11*fx)*fy;
        q[h] = (unsigned)f2bf(lo) | ((unsigned)f2bf(hi) << 16);
    }
    uint4* dst = (uint4*)yci + ((size_t)n*65536 + oy*256 + ox)*2;
    dst[0] = make_uint4(q[0], q[1], q[2], q[3]);
    dst[1] = make_uint4(q[4], q[5], q[6], q[7]);
}

// ---------------------------------------------------------------------------
// 3x3 conv 16->16 via MFMA implicit GEMM on ci layout, BN pre-folded.
// MODE 0: leaky -> ci.  MODE 1: + residual(res_ci) -> ci.
// ---------------------------------------------------------------------------
template<int MODE>
__global__ __launch_bounds__(256) void conv3_mfma(
    const unsigned short* __restrict__ in_ci,
    const unsigned short* __restrict__ wB, const float* __restrict__ q3,
    const unsigned short* __restrict__ res_ci,
    unsigned short* __restrict__ out_ci)
{
    __shared__ __align__(16) unsigned char lds[17408];
    unsigned short* tile = (unsigned short*)lds;   // [18][20][16] bf16 (11,520 B)
    float* P16 = (float*)lds;                      // [256][17] f32

    const int tid = threadIdx.x;
    const int n = blockIdx.z, ox = blockIdx.x*16, oy = blockIdx.y*16;
    const int w = tid >> 6, l = tid & 63, lg = l >> 4, ln = l & 15;

    const uint4* zc = (const uint4*)in_ci;
    uint4* tl4 = (uint4*)tile;
    for (int u = tid; u < 720; u += 256) {
        int r = u / 40, s = u - r*40;
        int y = oy + r - 1, xcol = ox + (s >> 1) - 1;
        uint4 v = make_uint4(0u,0u,0u,0u);
        if (y >= 0 && y < 256 && xcol >= 0 && xcol < 256)
            v = zc[((size_t)n*65536 + y*256 + xcol)*2 + (s & 1)];
        tl4[u] = v;
    }
    __syncthreads();

    float4v acc[4];
#pragma unroll
    for (int mi = 0; mi < 4; ++mi) acc[mi] = (float4v){0.f,0.f,0.f,0.f};
    const short8v* Bb = (const short8v*)wB;
#pragma unroll
    for (int ks = 0; ks < 6; ++ks) {
        const int ky = ks >> 1, kxp = (ks & 1) << 1;
        short8v b = Bb[(ks*16 + ln)*4 + lg];
        short8v a[4];
#pragma unroll
        for (int mi = 0; mi < 4; ++mi) {
            int row = (4*w + mi) + ky;
            a[mi] = *(const short8v*)(tile + (row*20 + ln + kxp)*16 + lg*8);
        }
#pragma unroll
        for (int mi = 0; mi < 4; ++mi)
            acc[mi] = __builtin_amdgcn_mfma_f32_16x16x32_bf16(a[mi], b, acc[mi], 0, 0, 0);
    }
    __syncthreads();
#pragma unroll
    for (int mi = 0; mi < 4; ++mi)
#pragma unroll
        for (int r = 0; r < 4; ++r)
            P16[((4*w + mi)*16 + lg*4 + r)*17 + ln] = acc[mi][r];
    __syncthreads();

    const int py = tid >> 4, pxx = tid & 15;
    const int p = (oy + py)*256 + ox + pxx;
    float u16[16];
#pragma unroll
    for (int o = 0; o < 16; ++o) u16[o] = P16[tid*17 + o] + q3[o];
    if (MODE == 0) {
#pragma unroll
        for (int o = 0; o < 16; ++o) u16[o] = leakyf(u16[o]);
    } else {
        unsigned R[8];
        load8((const uint4*)res_ci, ((size_t)n*65536 + p)*2, R);
#pragma unroll
        for (int h = 0; h < 8; ++h) {
            float lo, hi; unpack2(R[h], lo, hi);
            u16[2*h] += lo; u16[2*h+1] += hi;
        }
    }
    unsigned q[8];
#pragma unroll
    for (int h = 0; h < 8; ++h)
        q[h] = (unsigned)f2bf(u16[2*h]) | ((unsigned)f2bf(u16[2*h+1]) << 16);
    uint4* dst = (uint4*)out_ci + ((size_t)n*65536 + p)*2;
    dst[0] = make_uint4(q[0], q[1], q[2], q[3]);
    dst[1] = make_uint4(q[4], q[5], q[6], q[7]);
}

// ---------------------------------------------------------------------------
// conv7x7 16->64 via MFMA implicit GEMM (verified R4).
// ---------------------------------------------------------------------------
__global__ __launch_bounds__(256) void conv7b_mfma(
    const unsigned short* __restrict__ z_ci,
    const unsigned short* __restrict__ pwB,
    float* __restrict__ out0)
{
    __shared__ __align__(16) unsigned short tile[22*24*16]; // 16,896 B
    const int tid = threadIdx.x;
    const int n = blockIdx.z, ox = blockIdx.x*16, oy = blockIdx.y*16;

    const uint4* zc = (const uint4*)z_ci;
    uint4* tl4 = (uint4*)tile;
    for (int u = tid; u < 1056; u += 256) {
        int r = u / 48, s = u - r*48;
        int y = oy + r - 3, xcol = ox + (s >> 1) - 3;
        uint4 v = make_uint4(0u, 0u, 0u, 0u);
        if (y >= 0 && y < 256 && xcol >= 0 && xcol < 256)
            v = zc[(size_t)((n*256 + y)*256 + xcol)*2 + (s & 1)];
        tl4[u] = v;
    }
    __syncthreads();

    const int w = tid >> 6, l = tid & 63;
    const int lg = l >> 4, ln = l & 15;
    float4v acc[4][4];
#pragma unroll
    for (int mi = 0; mi < 4; ++mi)
#pragma unroll
        for (int nt = 0; nt < 4; ++nt)
            acc[mi][nt] = (float4v){0.f, 0.f, 0.f, 0.f};

    const short8v* Bb = (const short8v*)pwB;
    for (int ks = 0; ks < 28; ++ks) {
        const int ky = ks >> 2, kxp = (ks & 3) << 1;
        short8v a[4], b[4];
#pragma unroll
        for (int mi = 0; mi < 4; ++mi) {
            int row = (4*w + mi) + ky;
            int off = (row*24 + ln + kxp)*16 + lg*8;
            a[mi] = *(const short8v*)(tile + off);
        }
#pragma unroll
        for (int nt = 0; nt < 4; ++nt)
            b[nt] = Bb[ks*256 + nt*64 + ln*4 + lg];
#pragma unroll
        for (int mi = 0; mi < 4; ++mi)
#pragma unroll
            for (int nt = 0; nt < 4; ++nt)
                acc[mi][nt] = __builtin_amdgcn_mfma_f32_16x16x32_bf16(
                    a[mi], b[nt], acc[mi][nt], 0, 0, 0);
    }

#pragma unroll
    for (int mi = 0; mi < 4; ++mi) {
        const int yy = oy + 4*w + mi;
#pragma unroll
        for (int nt = 0; nt < 4; ++nt) {
            const int oc = nt*16 + ln;
            float* dst = out0 + (size_t)(n*64 + oc)*HW256 + yy*256 + ox + lg*4;
            *(float4v*)dst = acc[mi][nt];
        }
    }
}

// ---------------------------------------------------------------------------
// Epilogue: out0 += bias + bilinear(x); emit attention key logit k.
// ---------------------------------------------------------------------------
__global__ __launch_bounds__(256) void bilin_k(
    float* __restrict__ out0, const float* __restrict__ x,
    const float* __restrict__ bias,
    const float* __restrict__ akw, const float* __restrict__ akb,
    float* __restrict__ kbuf)
{
    const int tx = threadIdx.x, ty = threadIdx.y;
    const int n = blockIdx.z;
    const int ohx = blockIdx.x*16 + tx, ohy = blockIdx.y*16 + ty;
    float sy = ohy * (127.f/255.f), sx = ohx * (127.f/255.f);
    int y0 = min((int)sy, 126), x0 = min((int)sx, 126);
    float fy = sy - y0, fx = sx - x0;
    const float* xb = x + n*64*HW128;
    const int p = ohy*256 + ohx;
    float kacc = akb[0];
#pragma unroll
    for (int o = 0; o < 64; ++o) {
        const float* xc = xb + o*HW128;
        float v00 = xc[y0*128 + x0],       v01 = xc[y0*128 + x0 + 1];
        float v10 = xc[y0*128 + 128 + x0], v11 = xc[y0*128 + 128 + x0 + 1];
        float idv = (v00*(1.f-fx) + v01*fx)*(1.f-fy) + (v10*(1.f-fx) + v11*fx)*fy;
        size_t idx = (size_t)(n*64 + o)*HW256 + p;
        float u = out0[idx] + bias[o] + idv;
        out0[idx] = u;
        kacc += akw[o] * u;
    }
    kbuf[n*65536 + p] = kacc;
}

// ---------------------------------------------------------------------------
// Softmax stats per image.
// ---------------------------------------------------------------------------
__global__ __launch_bounds__(1024) void softmax_stats(
    const float* __restrict__ kb, float* __restrict__ st)
{
    __shared__ float red[16];
    __shared__ float bc;
    const int n = blockIdx.x, tid = threadIdx.x;
    const float* kp = kb + n*65536;
    float mx = -3.0e38f;
    for (int i = tid; i < 65536; i += 1024) mx = fmaxf(mx, kp[i]);
#pragma unroll
    for (int off = 1; off < 64; off <<= 1) mx = fmaxf(mx, __shfl_xor(mx, off));
    int w = tid >> 6, l = tid & 63;
    if (l == 0) red[w] = mx;
    __syncthreads();
    if (tid == 0) {
        float m = red[0];
        for (int i = 1; i < 16; ++i) m = fmaxf(m, red[i]);
        bc = m;
    }
    __syncthreads();
    float MX = bc;
    float s = 0.f;
    for (int i = tid; i < 65536; i += 1024) s += __expf(kp[i] - MX);
#pragma unroll
    for (int off = 1; off < 64; off <<= 1) s += __shfl_xor(s, off);
    __syncthreads();
    if (l == 0) red[w] = s;
    __syncthreads();
    if (tid == 0) {
        float S = 0.f;
        for (int i = 0; i < 16; ++i) S += red[i];
        st[n] = MX; st[8 + n] = 1.f / S;
    }
}

// ---------------------------------------------------------------------------
// S[n,c] = sum_p exp(k-mx) * out0[n,c,p].
// ---------------------------------------------------------------------------
__global__ __launch_bounds__(256) void att_wsum(
    const float* __restrict__ out0, const float* __restrict__ kb,
    const float* __restrict__ st, float* __restrict__ S)
{
    const int cg = blockIdx.x, n = blockIdx.y, c0 = cg*8;
    const float mx = st[n];
    const float* kp = kb + n*65536;
    const float* base = out0 + (size_t)(n*64 + c0)*HW256;
    float acc[8];
#pragma unroll
    for (int c = 0; c < 8; ++c) acc[c] = 0.f;
    for (int p = threadIdx.x; p < 65536; p += 256) {
        float e = __expf(kp[p] - mx);
#pragma unroll
        for (int c = 0; c < 8; ++c) acc[c] += e * base[c*HW256 + p];
    }
#pragma unroll
    for (int c = 0; c < 8; ++c)
#pragma unroll
        for (int off = 1; off < 64; off <<= 1) acc[c] += __shfl_xor(acc[c], off);
    __shared__ float red[4][8];
    int w = threadIdx.x >> 6, l = threadIdx.x & 63;
    if (l == 0) {
#pragma unroll
        for (int c = 0; c < 8; ++c) red[w][c] = acc[c];
    }
    __syncthreads();
    if (threadIdx.x < 8)
        S[n*64 + c0 + threadIdx.x] =
            red[0][threadIdx.x] + red[1][threadIdx.x] + red[2][threadIdx.x] + red[3][threadIdx.x];
}

// ---------------------------------------------------------------------------
// context + per-(n,c) attention addend.
// ---------------------------------------------------------------------------
__global__ __launch_bounds__(512) void ctx_addc(
    const float* __restrict__ S, const float* __restrict__ st,
    const float* __restrict__ avw, const float* __restrict__ avb,
    const float* __restrict__ arw, const float* __restrict__ arb,
    float* __restrict__ addc)
{
    __shared__ float ctx[8][8];
    const int tid = threadIdx.x;
    if (tid < 64) {
        int n = tid >> 3, vc = tid & 7;
        float s = 0.f;
        for (int c = 0; c < 64; ++c) s += avw[vc*64 + c] * S[n*64 + c];
        ctx[n][vc] = s * st[8 + n] + avb[vc];
    }
    __syncthreads();
    int n = tid >> 6, c = tid & 63;
    float a = arb[c];
#pragma unroll
    for (int vc = 0; vc < 8; ++vc) a += arw[c*8 + vc] * ctx[n][vc];
    addc[n*64 + c] = a;
}

// ---------------------------------------------------------------------------
// Transformer via MFMA. R8: conflict-free transpose staging.
// Phase 1: float4 loads of out0+addc -> Xt[c][132] f32 via aligned b128
//          writes (contiguous lane partitions -> no bank conflicts).
// Phase 2: thread t = token: reads Xt[c][t] (consecutive lanes -> no
//          conflicts), LN in registers -> Xb[128][72] bf16.
// Phase 3: GEMM1 + GELU -> Hb (aliases Xt).  Phase 4: GEMM2 + RMW epilogue.
// ---------------------------------------------------------------------------
__global__ __launch_bounds__(256) void transformer_mfma(
    float* __restrict__ out0, const float* __restrict__ addc,
    const float* __restrict__ lng, const float* __restrict__ lnb,
    const unsigned short* __restrict__ W1b, const float* __restrict__ fc1b,
    const unsigned short* __restrict__ W2b, const float* __restrict__ fc2b)
{
    __shared__ __align__(16) unsigned char lds[52224];
    float*          Xt = (float*)lds;                         // [64][132] f32 (33,792 B)
    unsigned short* Hb = (unsigned short*)lds;                // [128][72] bf16 (aliases Xt)
    unsigned short* Xb = (unsigned short*)(lds + 33792);      // [128][72] bf16 (18,432 B)

    const int tid = threadIdx.x;
    const int n = blockIdx.x >> 9;
    const int p0 = (blockIdx.x & 511) << 7;
    const float* ac = addc + n*64;

    // Phase 1: 8 x (float4 global load -> single aligned b128 LDS store)
#pragma unroll
    for (int k = 0; k < 8; ++k) {
        int v = k*256 + tid;
        int c = v >> 5, i4 = (v & 31) << 2;
        float4v q = *(const float4v*)(out0 + (size_t)(n*64 + c)*HW256 + p0 + i4);
        float a = ac[c];
#pragma unroll
        for (int r = 0; r < 4; ++r) q[r] += a;
        *(float4v*)&Xt[c*132 + i4] = q;
    }
    __syncthreads();

    // Phase 2: LN per token (threads 0..127), conflict-free column reads
    if (tid < 128) {
        float t[64];
#pragma unroll
        for (int c = 0; c < 64; ++c) t[c] = Xt[c*132 + tid];
        float mu = 0.f;
#pragma unroll
        for (int c = 0; c < 64; ++c) mu += t[c];
        mu *= (1.f/64.f);
        float var = 0.f;
#pragma unroll
        for (int c = 0; c < 64; ++c) { float d = t[c] - mu; var += d*d; }
        var *= (1.f/64.f);
        float rs = rsqrtf(var + 1e-5f);
#pragma unroll
        for (int c8 = 0; c8 < 8; ++c8) {
            short8v pk;
#pragma unroll
            for (int e = 0; e < 8; ++e) {
                int c = c8*8 + e;
                pk[e] = (short)f2bf((t[c] - mu)*rs*lng[c] + lnb[c]);
            }
            *(short8v*)&Xb[tid*72 + c8*8] = pk;
        }
    }
    __syncthreads();

    const int w = tid >> 6, l = tid & 63, lg = l >> 4, ln = l & 15;

    // Phase 3: GEMM1 + GELU -> Hb
    float4v acc1[2][4];
#pragma unroll
    for (int mt = 0; mt < 2; ++mt)
#pragma unroll
        for (int nt = 0; nt < 4; ++nt) acc1[mt][nt] = (float4v){0.f,0.f,0.f,0.f};
#pragma unroll
    for (int kk = 0; kk < 2; ++kk) {
        short8v a[2], b[4];
#pragma unroll
        for (int mt = 0; mt < 2; ++mt)
            a[mt] = *(const short8v*)&Xb[(w*32 + mt*16 + ln)*72 + kk*32 + lg*8];
#pragma unroll
        for (int nt = 0; nt < 4; ++nt)
            b[nt] = *(const short8v*)&W1b[(nt*16 + ln)*64 + kk*32 + lg*8];
#pragma unroll
        for (int mt = 0; mt < 2; ++mt)
#pragma unroll
            for (int nt = 0; nt < 4; ++nt)
                acc1[mt][nt] = __builtin_amdgcn_mfma_f32_16x16x32_bf16(
                    a[mt], b[nt], acc1[mt][nt], 0, 0, 0);
    }
#pragma unroll
    for (int mt = 0; mt < 2; ++mt)
#pragma unroll
        for (int nt = 0; nt < 4; ++nt) {
            int j = nt*16 + ln;
            float bj = fc1b[j];
#pragma unroll
            for (int r = 0; r < 4; ++r) {
                int token = w*32 + mt*16 + lg*4 + r;
                float m = acc1[mt][nt][r] + bj;
                float g = 0.5f*m*(1.f + erff(m*0.70710678118654752f));
                Hb[token*72 + j] = f2bf(g);
            }
        }
    __syncthreads();

    // Phase 4: GEMM2 + RMW epilogue
    float4v acc2[2][4];
#pragma unroll
    for (int mt = 0; mt < 2; ++mt)
#pragma unroll
        for (int nt = 0; nt < 4; ++nt) acc2[mt][nt] = (float4v){0.f,0.f,0.f,0.f};
#pragma unroll
    for (int kk = 0; kk < 2; ++kk) {
        short8v a[2], b[4];
#pragma unroll
        for (int mt = 0; mt < 2; ++mt)
            a[mt] = *(const short8v*)&Hb[(w*32 + mt*16 + ln)*72 + kk*32 + lg*8];
#pragma unroll
        for (int nt = 0; nt < 4; ++nt)
            b[nt] = *(const short8v*)&W2b[(nt*16 + ln)*64 + kk*32 + lg*8];
#pragma unroll
        for (int mt = 0; mt < 2; ++mt)
#pragma unroll
            for (int nt = 0; nt < 4; ++nt)
                acc2[mt][nt] = __builtin_amdgcn_mfma_f32_16x16x32_bf16(
                    a[mt], b[nt], acc2[mt][nt], 0, 0, 0);
    }
#pragma unroll
    for (int mt = 0; mt < 2; ++mt)
#pragma unroll
        for (int nt = 0; nt < 4; ++nt) {
            int c = nt*16 + ln;
            int tb = w*32 + mt*16 + lg*4;
            float add = fc2b[c] + ac[c];
            float* dst = out0 + (size_t)(n*64 + c)*HW256 + p0 + tb;
            float4v o = *(float4v*)dst;
#pragma unroll
            for (int r = 0; r < 4; ++r) o[r] += acc2[mt][nt][r] + add;
            *(float4v*)dst = o;
        }
}

// ---------------------------------------------------------------------------
extern "C" void kernel_launch(void* const* d_in, const int* in_sizes, int n_in,
                              void* d_out, int out_size, void* d_ws, size_t ws_size,
                              hipStream_t stream)
{
    (void)in_sizes; (void)n_in; (void)out_size; (void)ws_size;
    const float* x    = (const float*)d_in[0];
    const float* w7a  = (const float*)d_in[1];
    const float* b7a  = (const float*)d_in[2];
    const float* w1   = (const float*)d_in[3];
    const float* b1   = (const float*)d_in[4];
    const float* g1   = (const float*)d_in[5];
    const float* be1  = (const float*)d_in[6];
    const float* w3a  = (const float*)d_in[7];
    const float* b3a  = (const float*)d_in[8];
    const float* g3a  = (const float*)d_in[9];
    const float* be3a = (const float*)d_in[10];
    const float* w3b  = (const float*)d_in[11];
    const float* b3b  = (const float*)d_in[12];
    const float* g3b  = (const float*)d_in[13];
    const float* be3b = (const float*)d_in[14];
    const float* w3c  = (const float*)d_in[15];
    const float* b3c  = (const float*)d_in[16];
    const float* g3c  = (const float*)d_in[17];
    const float* be3c = (const float*)d_in[18];
    const float* w7b  = (const float*)d_in[19];
    const float* b7b  = (const float*)d_in[20];
    const float* akw  = (const float*)d_in[21];
    const float* akb  = (const float*)d_in[22];
    const float* avw  = (const float*)d_in[25];
    const float* avb  = (const float*)d_in[26];
    const float* arw  = (const float*)d_in[27];
    const float* arb  = (const float*)d_in[28];
    const float* lng  = (const float*)d_in[29];
    const float* lnb  = (const float*)d_in[30];
    const float* fc1w = (const float*)d_in[31];
    const float* fc1b = (const float*)d_in[32];
    const float* fc2w = (const float*)d_in[33];
    const float* fc2b = (const float*)d_in[34];

    float* ws   = (float*)d_ws;
    float* o_y2 = ws;                       // y2_ci bf16
    float* o_y  = o_y2 + 2097152;           // y_ci bf16
    float* o_z1 = o_y  + 8388608;           // z1_ci, then z3_ci bf16
    float* o_z2 = o_z1 + 8388608;           // xci bf16, then z2_ci bf16
    float* o_k  = o_z2 + 8388608;           // 524,288
    float* o_st = o_k  + 524288;            // 64
    float* o_S  = o_st + 64;                // 512
    float* o_ad = o_S  + 512;               // 512
    float* p7aS = o_ad + 512;               // 50,176 f32 slot (holds 57,344 bf16)
    float* p1   = p7aS + 50176;             // 256
    float* q3a  = p1   + 256;               // 16
    float* q3b  = q3a  + 16;
    float* q3c  = q3b  + 16;
    unsigned short* w3aB = (unsigned short*)(q3c + 16);  // 3,072 bf16
    unsigned short* w3bB = w3aB + 3072;
    unsigned short* w3cB = w3bB + 3072;
    unsigned short* pwB  = w3cB + 3072;                  // 57,344 bf16
    unsigned short* pwT1 = pwB + 57344;                  // 4,096 bf16
    unsigned short* pwT2 = pwT1 + 4096;                  // 4,096 bf16

    unsigned short* p7aB = (unsigned short*)p7aS;
    unsigned short* y2ci = (unsigned short*)o_y2;  // [8][16384][16]
    unsigned short* yci  = (unsigned short*)o_y;   // [8][65536][16]
    unsigned short* z1ci = (unsigned short*)o_z1;
    unsigned short* xci  = (unsigned short*)o_z2;  // [8][4][16384][16]
    unsigned short* z2ci = (unsigned short*)o_z2;  // after conv7a consumed xci
    unsigned short* z3ci = (unsigned short*)o_z1;  // overwrites dead z1

    float* out0 = (float*)d_out;

    prepack<<<224, 256, 0, stream>>>(w7a, w1, w3a,b3a,g3a,be3a, w3b,b3b,g3b,be3b,
                                     w3c,b3c,g3c,be3c, w7b, fc1w, fc2w,
                                     p7aB, p1, q3a, q3b, q3c, w3aB, w3bB, w3cB,
                                     pwB, pwT1, pwT2);
    x_to_ci<<<2048, 256, 0, stream>>>(x, xci);
    conv7a_mfma<<<dim3(8,8,8), 256, 0, stream>>>(xci, p7aB, b7a, p1, b1, g1, be1, y2ci);
    resize_ci<<<dim3(16,16,8), dim3(16,16), 0, stream>>>(y2ci, yci);
    conv3_mfma<0><<<dim3(16,16,8), 256, 0, stream>>>(yci,  w3aB, q3a, nullptr, z1ci);
    conv3_mfma<1><<<dim3(16,16,8), 256, 0, stream>>>(z1ci, w3bB, q3b, yci,     z2ci);
    conv3_mfma<1><<<dim3(16,16,8), 256, 0, stream>>>(z2ci, w3cB, q3c, yci,     z3ci);
    conv7b_mfma<<<dim3(16,16,8), 256, 0, stream>>>(z3ci, pwB, out0);
    bilin_k<<<dim3(16,16,8), dim3(16,16), 0, stream>>>(out0, x, b7b, akw, akb, o_k);
    softmax_stats<<<8, 1024, 0, stream>>>(o_k, o_st);
    att_wsum<<<dim3(8,8), 256, 0, stream>>>(out0, o_k, o_st, o_S);
    ctx_addc<<<1, 512, 0, stream>>>(o_S, o_st, avw, avb, arw, arb, o_ad);
    transformer_mfma<<<4096, 256, 0, stream>>>(out0, o_ad, lng, lnb, pwT1, fc1b, pwT2, fc2b);
}

// Round 9
// 370.191 us; speedup vs baseline: 9.6482x; 1.3227x over previous
//
#include <hip/hip_runtime.h>
#include <math.h>

#define DI __device__ __forceinline__
#define HW128 (128*128)
#define HW256 (256*256)

__device__ const float BN_RS = 0.9999950000374997f; // 1/sqrt(1+1e-5)

DI float leakyf(float x){ return x >= 0.f ? x : 0.2f*x; }

DI unsigned short f2bf(float f){
    unsigned u = __float_as_uint(f);
    return (unsigned short)((u + 0x7fffu + ((u >> 16) & 1u)) >> 16);
}
DI void unpack2(unsigned u, float& lo, float& hi){
    lo = __uint_as_float(u << 16);
    hi = __uint_as_float(u & 0xffff0000u);
}
DI void load8(const uint4* s, size_t idx, unsigned* d){
    uint4 t0 = s[idx], t1 = s[idx + 1];
    d[0]=t0.x; d[1]=t0.y; d[2]=t0.z; d[3]=t0.w;
    d[4]=t1.x; d[5]=t1.y; d[6]=t1.z; d[7]=t1.w;
}

typedef __attribute__((ext_vector_type(8))) short short8v;
typedef __attribute__((ext_vector_type(4))) float float4v;

// ---------------------------------------------------------------------------
// Prepack (unchanged from R7/R8).
// ---------------------------------------------------------------------------
__global__ __launch_bounds__(256) void prepack(
    const float* __restrict__ w7a, const float* __restrict__ w1,
    const float* __restrict__ w3a, const float* __restrict__ b3a, const float* __restrict__ g3a, const float* __restrict__ be3a,
    const float* __restrict__ w3b, const float* __restrict__ b3b, const float* __restrict__ g3b, const float* __restrict__ be3b,
    const float* __restrict__ w3c, const float* __restrict__ b3c, const float* __restrict__ g3c, const float* __restrict__ be3c,
    const float* __restrict__ w7b, const float* __restrict__ fc1w, const float* __restrict__ fc2w,
    unsigned short* __restrict__ p7aB, float* __restrict__ p1,
    float* __restrict__ q3a, float* __restrict__ q3b, float* __restrict__ q3c,
    unsigned short* __restrict__ w3aB, unsigned short* __restrict__ w3bB, unsigned short* __restrict__ w3cB,
    unsigned short* __restrict__ pwB,
    unsigned short* __restrict__ pwT1, unsigned short* __restrict__ pwT2)
{
    int i = blockIdx.x * 256 + threadIdx.x;
    if (i < 57344) {                                      // conv7a MFMA weights
        int g = i / 14336, rem = i - g*14336;
        int ks = rem >> 9, oc = (rem >> 5) & 15, k = rem & 31;
        int ky = ks >> 2, kx = ((ks & 3) << 1) + (k >> 4), ic = g*16 + (k & 15);
        p7aB[i] = (kx < 7) ? f2bf(w7a[(oc*64 + ic)*49 + ky*7 + kx]) : (unsigned short)0;
    }
    if (i < 57344) {                                      // conv7b MFMA weights
        int ks = i >> 11, oc = (i >> 5) & 63, k = i & 31;
        int ky = ks >> 2, kx = ((ks & 3) << 1) + (k >> 4), ic = k & 31 & 15;
        ic = k & 15;
        pwB[i] = (kx < 7) ? f2bf(w7b[((oc*16 + ic)*7 + ky)*7 + kx]) : (unsigned short)0;
    }
    if (i < 3072) {                                       // conv3 MFMA weights ×3
        int ks = i >> 9, oc = (i >> 5) & 15, k = i & 31;
        int ky = ks >> 1, kx = ((ks & 1) << 1) + (k >> 4), ic = k & 15;
        if (kx < 3) {
            int src = (oc*16 + ic)*9 + ky*3 + kx;
            w3aB[i] = f2bf(w3a[src] * (g3a[oc]*BN_RS));
            w3bB[i] = f2bf(w3b[src] * (g3b[oc]*BN_RS));
            w3cB[i] = f2bf(w3c[src] * (g3c[oc]*BN_RS));
        } else {
            w3aB[i] = 0; w3bB[i] = 0; w3cB[i] = 0;
        }
    }
    if (i < 256) { int oc = i & 15, ic = i >> 4; p1[i] = w1[oc*16 + ic]; }
    if (i < 16) {
        q3a[i] = b3a[i]*(g3a[i]*BN_RS) + be3a[i];
        q3b[i] = b3b[i]*(g3b[i]*BN_RS) + be3b[i];
        q3c[i] = b3c[i]*(g3c[i]*BN_RS) + be3c[i];
    }
    if (i < 4096) { pwT1[i] = f2bf(fc1w[i]); pwT2[i] = f2bf(fc2w[i]); }
}

// ---------------------------------------------------------------------------
// x (8,64,128,128) f32 -> xci bf16 [n][g=ic/16][y*128+x][16]
// ---------------------------------------------------------------------------
__global__ __launch_bounds__(256) void x_to_ci(
    const float* __restrict__ x, unsigned short* __restrict__ xci)
{
    int idx = blockIdx.x*256 + threadIdx.x;   // 524,288
    int p = idx & 16383, gn = idx >> 14;
    int g = gn & 3, n = gn >> 2;
    const float* xb = x + (size_t)(n*64 + g*16)*HW128 + p;
    unsigned q[8];
#pragma unroll
    for (int h = 0; h < 8; ++h) {
        float a0 = xb[(size_t)(2*h)*HW128];
        float a1 = xb[(size_t)(2*h + 1)*HW128];
        q[h] = (unsigned)f2bf(a0) | ((unsigned)f2bf(a1) << 16);
    }
    uint4* dst = (uint4*)xci + (size_t)idx*2;
    dst[0] = make_uint4(q[0], q[1], q[2], q[3]);
    dst[1] = make_uint4(q[4], q[5], q[6], q[7]);
}

// ---------------------------------------------------------------------------
// conv7x7 64->16 MFMA + f32 1x1 + leaky + BN epilogue -> y2_ci bf16
// ---------------------------------------------------------------------------
__global__ __launch_bounds__(256) void conv7a_mfma(
    const unsigned short* __restrict__ xci,
    const unsigned short* __restrict__ pw,
    const float* __restrict__ b7a, const float* __restrict__ p1,
    const float* __restrict__ b1, const float* __restrict__ bng,
    const float* __restrict__ bnb, unsigned short* __restrict__ y2ci)
{
    __shared__ __align__(16) unsigned char lds[17408];
    unsigned short* tile = (unsigned short*)lds;   // [22][24][16] bf16
    float* P16 = (float*)lds;                      // [256][17] f32

    const int tid = threadIdx.x;
    const int n = blockIdx.z, ox = blockIdx.x*16, oy = blockIdx.y*16;
    const int w = tid >> 6, l = tid & 63, lg = l >> 4, ln = l & 15;

    float4v acc[4];
#pragma unroll
    for (int mi = 0; mi < 4; ++mi) acc[mi] = (float4v){0.f,0.f,0.f,0.f};

    const uint4* xc4 = (const uint4*)xci;
    uint4* tl4 = (uint4*)tile;
    const short8v* Bb = (const short8v*)pw;

    for (int g = 0; g < 4; ++g) {
        __syncthreads();
        for (int u = tid; u < 1056; u += 256) {
            int r = u / 48, s = u - r*48;
            int y = oy + r - 3, xcol = ox + (s >> 1) - 3;
            uint4 v = make_uint4(0u,0u,0u,0u);
            if (y >= 0 && y < 128 && xcol >= 0 && xcol < 128)
                v = xc4[((size_t)(n*4 + g)*16384 + y*128 + xcol)*2 + (s & 1)];
            tl4[u] = v;
        }
        __syncthreads();
        for (int ks = 0; ks < 28; ++ks) {
            const int ky = ks >> 2, kxp = (ks & 3) << 1;
            short8v b = Bb[(g*28 + ks)*64 + ln*4 + lg];
            short8v a[4];
#pragma unroll
            for (int mi = 0; mi < 4; ++mi) {
                int row = (4*w + mi) + ky;
                a[mi] = *(const short8v*)(tile + (row*24 + ln + kxp)*16 + lg*8);
            }
#pragma unroll
            for (int mi = 0; mi < 4; ++mi)
                acc[mi] = __builtin_amdgcn_mfma_f32_16x16x32_bf16(a[mi], b, acc[mi], 0, 0, 0);
        }
    }
    __syncthreads();
    const float bo = b7a[ln];
#pragma unroll
    for (int mi = 0; mi < 4; ++mi)
#pragma unroll
        for (int r = 0; r < 4; ++r)
            P16[((4*w + mi)*16 + lg*4 + r)*17 + ln] = leakyf(acc[mi][r] + bo);
    __syncthreads();
    const int py = tid >> 4, pxx = tid & 15;
    float lv[16];
#pragma unroll
    for (int ic = 0; ic < 16; ++ic) lv[ic] = P16[tid*17 + ic];
    float u16[16];
#pragma unroll
    for (int o = 0; o < 16; ++o) {
        float u = b1[o];
#pragma unroll
        for (int ic = 0; ic < 16; ++ic) u += lv[ic] * p1[ic*16 + o];
        u = leakyf(u);
        u16[o] = u * (bng[o]*BN_RS) + bnb[o];
    }
    const int p = (oy + py)*128 + ox + pxx;
    unsigned q[8];
#pragma unroll
    for (int h = 0; h < 8; ++h)
        q[h] = (unsigned)f2bf(u16[2*h]) | ((unsigned)f2bf(u16[2*h+1]) << 16);
    uint4* dst = (uint4*)y2ci + (size_t)(n*16384 + p)*2;
    dst[0] = make_uint4(q[0], q[1], q[2], q[3]);
    dst[1] = make_uint4(q[4], q[5], q[6], q[7]);
}

// ---------------------------------------------------------------------------
// Bilinear resize 128->256 on ci layout.
// ---------------------------------------------------------------------------
__global__ __launch_bounds__(256) void resize_ci(
    const unsigned short* __restrict__ y2ci, unsigned short* __restrict__ yci)
{
    const int n = blockIdx.z;
    const int ox = blockIdx.x*16 + threadIdx.x;
    const int oy = blockIdx.y*16 + threadIdx.y;
    float sy = oy * (127.f/255.f), sx = ox * (127.f/255.f);
    int y0 = min((int)sy, 126), x0 = min((int)sx, 126);
    float fy = sy - y0, fx = sx - x0;
    const uint4* src = (const uint4*)y2ci;
    size_t i00 = ((size_t)n*16384 + y0*128 + x0)*2;
    unsigned A00[8], A01[8], A10[8], A11[8];
    load8(src, i00,       A00);
    load8(src, i00 + 2,   A01);
    load8(src, i00 + 256, A10);
    load8(src, i00 + 258, A11);
    unsigned q[8];
#pragma unroll
    for (int h = 0; h < 8; ++h) {
        float l00, h00, l01, h01, l10, h10, l11, h11;
        unpack2(A00[h], l00, h00); unpack2(A01[h], l01, h01);
        unpack2(A10[h], l10, h10); unpack2(A11[h], l11, h11);
        float lo = (l00*(1.f-fx) + l01*fx)*(1.f-fy) + (l10*(1.f-fx) + l11*fx)*fy;
        float hi = (h00*(1.f-fx) + h01*fx)*(1.f-fy) + (h10*(1.f-fx) + h11*fx)*fy;
        q[h] = (unsigned)f2bf(lo) | ((unsigned)f2bf(hi) << 16);
    }
    uint4* dst = (uint4*)yci + ((size_t)n*65536 + oy*256 + ox)*2;
    dst[0] = make_uint4(q[0], q[1], q[2], q[3]);
    dst[1] = make_uint4(q[4], q[5], q[6], q[7]);
}

// ---------------------------------------------------------------------------
// 3x3 conv 16->16 via MFMA implicit GEMM on ci layout, BN pre-folded.
// ---------------------------------------------------------------------------
template<int MODE>
__global__ __launch_bounds__(256) void conv3_mfma(
    const unsigned short* __restrict__ in_ci,
    const unsigned short* __restrict__ wB, const float* __restrict__ q3,
    const unsigned short* __restrict__ res_ci,
    unsigned short* __restrict__ out_ci)
{
    __shared__ __align__(16) unsigned char lds[17408];
    unsigned short* tile = (unsigned short*)lds;   // [18][20][16] bf16
    float* P16 = (float*)lds;                      // [256][17] f32

    const int tid = threadIdx.x;
    const int n = blockIdx.z, ox = blockIdx.x*16, oy = blockIdx.y*16;
    const int w = tid >> 6, l = tid & 63, lg = l >> 4, ln = l & 15;

    const uint4* zc = (const uint4*)in_ci;
    uint4* tl4 = (uint4*)tile;
    for (int u = tid; u < 720; u += 256) {
        int r = u / 40, s = u - r*40;
        int y = oy + r - 1, xcol = ox + (s >> 1) - 1;
        uint4 v = make_uint4(0u,0u,0u,0u);
        if (y >= 0 && y < 256 && xcol >= 0 && xcol < 256)
            v = zc[((size_t)n*65536 + y*256 + xcol)*2 + (s & 1)];
        tl4[u] = v;
    }
    __syncthreads();

    float4v acc[4];
#pragma unroll
    for (int mi = 0; mi < 4; ++mi) acc[mi] = (float4v){0.f,0.f,0.f,0.f};
    const short8v* Bb = (const short8v*)wB;
#pragma unroll
    for (int ks = 0; ks < 6; ++ks) {
        const int ky = ks >> 1, kxp = (ks & 1) << 1;
        short8v b = Bb[(ks*16 + ln)*4 + lg];
        short8v a[4];
#pragma unroll
        for (int mi = 0; mi < 4; ++mi) {
            int row = (4*w + mi) + ky;
            a[mi] = *(const short8v*)(tile + (row*20 + ln + kxp)*16 + lg*8);
        }
#pragma unroll
        for (int mi = 0; mi < 4; ++mi)
            acc[mi] = __builtin_amdgcn_mfma_f32_16x16x32_bf16(a[mi], b, acc[mi], 0, 0, 0);
    }
    __syncthreads();
#pragma unroll
    for (int mi = 0; mi < 4; ++mi)
#pragma unroll
        for (int r = 0; r < 4; ++r)
            P16[((4*w + mi)*16 + lg*4 + r)*17 + ln] = acc[mi][r];
    __syncthreads();

    const int py = tid >> 4, pxx = tid & 15;
    const int p = (oy + py)*256 + ox + pxx;
    float u16[16];
#pragma unroll
    for (int o = 0; o < 16; ++o) u16[o] = P16[tid*17 + o] + q3[o];
    if (MODE == 0) {
#pragma unroll
        for (int o = 0; o < 16; ++o) u16[o] = leakyf(u16[o]);
    } else {
        unsigned R[8];
        load8((const uint4*)res_ci, ((size_t)n*65536 + p)*2, R);
#pragma unroll
        for (int h = 0; h < 8; ++h) {
            float lo, hi; unpack2(R[h], lo, hi);
            u16[2*h] += lo; u16[2*h+1] += hi;
        }
    }
    unsigned q[8];
#pragma unroll
    for (int h = 0; h < 8; ++h)
        q[h] = (unsigned)f2bf(u16[2*h]) | ((unsigned)f2bf(u16[2*h+1]) << 16);
    uint4* dst = (uint4*)out_ci + ((size_t)n*65536 + p)*2;
    dst[0] = make_uint4(q[0], q[1], q[2], q[3]);
    dst[1] = make_uint4(q[4], q[5], q[6], q[7]);
}

// ---------------------------------------------------------------------------
// conv7x7 16->64 MFMA + FUSED epilogue: bias + bilinear identity + k logit.
// x-tile (10x10x64ch) staged as bf16 in LDS; C transposed via P16 in 4
// oc-chunks (P16 aliases the conv tile); out0 written once.
// ---------------------------------------------------------------------------
__global__ __launch_bounds__(256) void conv7b_mfma(
    const unsigned short* __restrict__ z_ci,
    const unsigned short* __restrict__ pwB,
    const float* __restrict__ x,
    const float* __restrict__ bias,
    const float* __restrict__ akw, const float* __restrict__ akb,
    float* __restrict__ out0, float* __restrict__ kbuf)
{
    __shared__ __align__(16) unsigned char lds[17408 + 12800];
    unsigned short* tile = (unsigned short*)lds;          // [22][24][16] bf16
    float* P16 = (float*)lds;                             // [256][17] f32 (aliases tile)
    unsigned short* xt16 = (unsigned short*)(lds + 17408);// [100][64] bf16 x-tile

    const int tid = threadIdx.x;
    const int n = blockIdx.z, ox = blockIdx.x*16, oy = blockIdx.y*16;
    const float SC = 127.f/255.f;
    const int ybase = (int)(oy*SC), xbase = (int)(ox*SC);

    // stage conv input tile
    const uint4* zc = (const uint4*)z_ci;
    uint4* tl4 = (uint4*)tile;
    for (int u = tid; u < 1056; u += 256) {
        int r = u / 48, s = u - r*48;
        int y = oy + r - 3, xcol = ox + (s >> 1) - 3;
        uint4 v = make_uint4(0u, 0u, 0u, 0u);
        if (y >= 0 && y < 256 && xcol >= 0 && xcol < 256)
            v = zc[(size_t)((n*256 + y)*256 + xcol)*2 + (s & 1)];
        tl4[u] = v;
    }
    // stage x tile for bilinear (bf16): rows ybase..+9, cols xbase..+9
    for (int u = tid; u < 6400; u += 256) {
        int ch = u / 100, rem = u - ch*100;
        int r = rem / 10, c = rem - r*10;
        int y = ybase + r, xc = xbase + c;
        float v = 0.f;
        if (y < 128 && xc < 128) v = x[(size_t)(n*64 + ch)*HW128 + y*128 + xc];
        xt16[(r*10 + c)*64 + ch] = f2bf(v);
    }
    __syncthreads();

    const int w = tid >> 6, l = tid & 63;
    const int lg = l >> 4, ln = l & 15;
    float4v acc[4][4];
#pragma unroll
    for (int mi = 0; mi < 4; ++mi)
#pragma unroll
        for (int nt = 0; nt < 4; ++nt)
            acc[mi][nt] = (float4v){0.f, 0.f, 0.f, 0.f};

    const short8v* Bb = (const short8v*)pwB;
    for (int ks = 0; ks < 28; ++ks) {
        const int ky = ks >> 2, kxp = (ks & 3) << 1;
        short8v a[4], b[4];
#pragma unroll
        for (int mi = 0; mi < 4; ++mi) {
            int row = (4*w + mi) + ky;
            a[mi] = *(const short8v*)(tile + (row*24 + ln + kxp)*16 + lg*8);
        }
#pragma unroll
        for (int nt = 0; nt < 4; ++nt)
            b[nt] = Bb[ks*256 + nt*64 + ln*4 + lg];
#pragma unroll
        for (int mi = 0; mi < 4; ++mi)
#pragma unroll
            for (int nt = 0; nt < 4; ++nt)
                acc[mi][nt] = __builtin_amdgcn_mfma_f32_16x16x32_bf16(
                    a[mi], b[nt], acc[mi][nt], 0, 0, 0);
    }

    // epilogue: per-thread pixel
    const int py = tid >> 4, pxx = tid & 15;
    const int ohy = oy + py, ohx = ox + pxx;
    float sy = ohy*SC, sx = ohx*SC;
    int y0 = min((int)sy, 126), x0 = min((int)sx, 126);
    float fy = sy - y0, fx = sx - x0;
    const int ly = y0 - ybase, lx = x0 - xbase;
    const int p = ohy*256 + ohx;
    const uint4* xt4 = (const uint4*)xt16;
    const size_t q00 = ((size_t)(ly*10 + lx)*64) >> 3;   // uint4 units, +nt*2 later
    float kacc = akb[0];

    for (int nt = 0; nt < 4; ++nt) {
        __syncthreads();
#pragma unroll
        for (int mi = 0; mi < 4; ++mi)
#pragma unroll
            for (int r = 0; r < 4; ++r)
                P16[((4*w + mi)*16 + lg*4 + r)*17 + ln] = acc[mi][nt][r];
        __syncthreads();
        unsigned A00[8], A01[8], A10[8], A11[8];
        size_t qb = q00 + nt*2;
        load8(xt4, qb,      A00);
        load8(xt4, qb + 8,  A01);
        load8(xt4, qb + 80, A10);
        load8(xt4, qb + 88, A11);
        float u16[16];
#pragma unroll
        for (int h = 0; h < 8; ++h) {
            float l00, h00, l01, h01, l10, h10, l11, h11;
            unpack2(A00[h], l00, h00); unpack2(A01[h], l01, h01);
            unpack2(A10[h], l10, h10); unpack2(A11[h], l11, h11);
            u16[2*h]   = (l00*(1.f-fx) + l01*fx)*(1.f-fy) + (l10*(1.f-fx) + l11*fx)*fy;
            u16[2*h+1] = (h00*(1.f-fx) + h01*fx)*(1.f-fy) + (h10*(1.f-fx) + h11*fx)*fy;
        }
#pragma unroll
        for (int o = 0; o < 16; ++o) {
            int oc = nt*16 + o;
            float u = P16[tid*17 + o] + bias[oc] + u16[o];
            out0[(size_t)(n*64 + oc)*HW256 + p] = u;
            kacc += akw[oc] * u;
        }
    }
    kbuf[n*65536 + p] = kacc;
}

// ---------------------------------------------------------------------------
// Softmax stats per image.
// ---------------------------------------------------------------------------
__global__ __launch_bounds__(1024) void softmax_stats(
    const float* __restrict__ kb, float* __restrict__ st)
{
    __shared__ float red[16];
    __shared__ float bc;
    const int n = blockIdx.x, tid = threadIdx.x;
    const float* kp = kb + n*65536;
    float mx = -3.0e38f;
    for (int i = tid; i < 65536; i += 1024) mx = fmaxf(mx, kp[i]);
#pragma unroll
    for (int off = 1; off < 64; off <<= 1) mx = fmaxf(mx, __shfl_xor(mx, off));
    int w = tid >> 6, l = tid & 63;
    if (l == 0) red[w] = mx;
    __syncthreads();
    if (tid == 0) {
        float m = red[0];
        for (int i = 1; i < 16; ++i) m = fmaxf(m, red[i]);
        bc = m;
    }
    __syncthreads();
    float MX = bc;
    float s = 0.f;
    for (int i = tid; i < 65536; i += 1024) s += __expf(kp[i] - MX);
#pragma unroll
    for (int off = 1; off < 64; off <<= 1) s += __shfl_xor(s, off);
    __syncthreads();
    if (l == 0) red[w] = s;
    __syncthreads();
    if (tid == 0) {
        float S = 0.f;
        for (int i = 0; i < 16; ++i) S += red[i];
        st[n] = MX; st[8 + n] = 1.f / S;
    }
}

// ---------------------------------------------------------------------------
// Partial S: Sp[n][pc][c] = sum over p-chunk of exp(k-mx)*out0[n,c,p].
// grid (8 cg, 4 pc, 8 n).
// ---------------------------------------------------------------------------
__global__ __launch_bounds__(256) void att_wsum(
    const float* __restrict__ out0, const float* __restrict__ kb,
    const float* __restrict__ st, float* __restrict__ Sp)
{
    const int cg = blockIdx.x, pc = blockIdx.y, n = blockIdx.z, c0 = cg*8;
    const float mx = st[n];
    const float* kp = kb + n*65536 + pc*16384;
    const float* base = out0 + (size_t)(n*64 + c0)*HW256 + pc*16384;
    float acc[8];
#pragma unroll
    for (int c = 0; c < 8; ++c) acc[c] = 0.f;
    for (int p = threadIdx.x; p < 16384; p += 256) {
        float e = __expf(kp[p] - mx);
#pragma unroll
        for (int c = 0; c < 8; ++c) acc[c] += e * base[c*HW256 + p];
    }
#pragma unroll
    for (int c = 0; c < 8; ++c)
#pragma unroll
        for (int off = 1; off < 64; off <<= 1) acc[c] += __shfl_xor(acc[c], off);
    __shared__ float red[4][8];
    int w = threadIdx.x >> 6, l = threadIdx.x & 63;
    if (l == 0) {
#pragma unroll
        for (int c = 0; c < 8; ++c) red[w][c] = acc[c];
    }
    __syncthreads();
    if (threadIdx.x < 8)
        Sp[n*256 + pc*64 + c0 + threadIdx.x] =
            red[0][threadIdx.x] + red[1][threadIdx.x] + red[2][threadIdx.x] + red[3][threadIdx.x];
}

// ---------------------------------------------------------------------------
// context + per-(n,c) attention addend (reduces the 4 p-chunks).
// ---------------------------------------------------------------------------
__global__ __launch_bounds__(512) void ctx_addc(
    const float* __restrict__ Sp, const float* __restrict__ st,
    const float* __restrict__ avw, const float* __restrict__ avb,
    const float* __restrict__ arw, const float* __restrict__ arb,
    float* __restrict__ addc)
{
    __shared__ float ctx[8][8];
    const int tid = threadIdx.x;
    if (tid < 64) {
        int n = tid >> 3, vc = tid & 7;
        float s = 0.f;
        for (int c = 0; c < 64; ++c) {
            float Sv = Sp[n*256 + c] + Sp[n*256 + 64 + c]
                     + Sp[n*256 + 128 + c] + Sp[n*256 + 192 + c];
            s += avw[vc*64 + c] * Sv;
        }
        ctx[n][vc] = s * st[8 + n] + avb[vc];
    }
    __syncthreads();
    int n = tid >> 6, c = tid & 63;
    float a = arb[c];
#pragma unroll
    for (int vc = 0; vc < 8; ++vc) a += arw[c*8 + vc] * ctx[n][vc];
    addc[n*64 + c] = a;
}

// ---------------------------------------------------------------------------
// Transformer via MFMA. R9: epilogue residual from LDS Xt (no global
// re-read); Hb aliases Xb (extra barrier); stride 136 for aligned b128.
// ---------------------------------------------------------------------------
__global__ __launch_bounds__(256) void transformer_mfma(
    float* __restrict__ out0, const float* __restrict__ addc,
    const float* __restrict__ lng, const float* __restrict__ lnb,
    const unsigned short* __restrict__ W1b, const float* __restrict__ fc1b,
    const unsigned short* __restrict__ W2b, const float* __restrict__ fc2b)
{
    __shared__ __align__(16) unsigned char lds[34816 + 18432];
    float*          Xt = (float*)lds;                         // [64][136] f32
    unsigned short* Xb = (unsigned short*)(lds + 34816);      // [128][72] bf16
    unsigned short* Hb = Xb;                                  // aliases Xb

    const int tid = threadIdx.x;
    const int n = blockIdx.x >> 9;
    const int p0 = (blockIdx.x & 511) << 7;
    const float* ac = addc + n*64;

    // Phase 1: float4 loads -> aligned b128 stores, t = out0 + addc
#pragma unroll
    for (int k = 0; k < 8; ++k) {
        int v = k*256 + tid;
        int c = v >> 5, i4 = (v & 31) << 2;
        float4v q = *(const float4v*)(out0 + (size_t)(n*64 + c)*HW256 + p0 + i4);
        float a = ac[c];
#pragma unroll
        for (int r = 0; r < 4; ++r) q[r] += a;
        *(float4v*)&Xt[c*136 + i4] = q;
    }
    __syncthreads();

    // Phase 2: LN per token (threads 0..127)
    if (tid < 128) {
        float t[64];
#pragma unroll
        for (int c = 0; c < 64; ++c) t[c] = Xt[c*136 + tid];
        float mu = 0.f;
#pragma unroll
        for (int c = 0; c < 64; ++c) mu += t[c];
        mu *= (1.f/64.f);
        float var = 0.f;
#pragma unroll
        for (int c = 0; c < 64; ++c) { float d = t[c] - mu; var += d*d; }
        var *= (1.f/64.f);
        float rs = rsqrtf(var + 1e-5f);
#pragma unroll
        for (int c8 = 0; c8 < 8; ++c8) {
            short8v pk;
#pragma unroll
            for (int e = 0; e < 8; ++e) {
                int c = c8*8 + e;
                pk[e] = (short)f2bf((t[c] - mu)*rs*lng[c] + lnb[c]);
            }
            *(short8v*)&Xb[tid*72 + c8*8] = pk;
        }
    }
    __syncthreads();

    const int w = tid >> 6, l = tid & 63, lg = l >> 4, ln = l & 15;

    // Phase 3: GEMM1
    float4v acc1[2][4];
#pragma unroll
    for (int mt = 0; mt < 2; ++mt)
#pragma unroll
        for (int nt = 0; nt < 4; ++nt) acc1[mt][nt] = (float4v){0.f,0.f,0.f,0.f};
#pragma unroll
    for (int kk = 0; kk < 2; ++kk) {
        short8v a[2], b[4];
#pragma unroll
        for (int mt = 0; mt < 2; ++mt)
            a[mt] = *(const short8v*)&Xb[(w*32 + mt*16 + ln)*72 + kk*32 + lg*8];
#pragma unroll
        for (int nt = 0; nt < 4; ++nt)
            b[nt] = *(const short8v*)&W1b[(nt*16 + ln)*64 + kk*32 + lg*8];
#pragma unroll
        for (int mt = 0; mt < 2; ++mt)
#pragma unroll
            for (int nt = 0; nt < 4; ++nt)
                acc1[mt][nt] = __builtin_amdgcn_mfma_f32_16x16x32_bf16(
                    a[mt], b[nt], acc1[mt][nt], 0, 0, 0);
    }
    __syncthreads();   // all waves done reading Xb before Hb (=Xb) writes
#pragma unroll
    for (int mt = 0; mt < 2; ++mt)
#pragma unroll
        for (int nt = 0; nt < 4; ++nt) {
            int j = nt*16 + ln;
            float bj = fc1b[j];
#pragma unroll
            for (int r = 0; r < 4; ++r) {
                int token = w*32 + mt*16 + lg*4 + r;
                float m = acc1[mt][nt][r] + bj;
                float g = 0.5f*m*(1.f + erff(m*0.70710678118654752f));
                Hb[token*72 + j] = f2bf(g);
            }
        }
    __syncthreads();

    // Phase 4: GEMM2 + epilogue (residual from Xt)
    float4v acc2[2][4];
#pragma unroll
    for (int mt = 0; mt < 2; ++mt)
#pragma unroll
        for (int nt = 0; nt < 4; ++nt) acc2[mt][nt] = (float4v){0.f,0.f,0.f,0.f};
#pragma unroll
    for (int kk = 0; kk < 2; ++kk) {
        short8v a[2], b[4];
#pragma unroll
        for (int mt = 0; mt < 2; ++mt)
            a[mt] = *(const short8v*)&Hb[(w*32 + mt*16 + ln)*72 + kk*32 + lg*8];
#pragma unroll
        for (int nt = 0; nt < 4; ++nt)
            b[nt] = *(const short8v*)&W2b[(nt*16 + ln)*64 + kk*32 + lg*8];
#pragma unroll
        for (int mt = 0; mt < 2; ++mt)
#pragma unroll
            for (int nt = 0; nt < 4; ++nt)
                acc2[mt][nt] = __builtin_amdgcn_mfma_f32_16x16x32_bf16(
                    a[mt], b[nt], acc2[mt][nt], 0, 0, 0);
    }
#pragma unroll
    for (int mt = 0; mt < 2; ++mt)
#pragma unroll
        for (int nt = 0; nt < 4; ++nt) {
            int c = nt*16 + ln;
            int tb = w*32 + mt*16 + lg*4;
            float add = fc2b[c];
            float4v t4 = *(const float4v*)&Xt[c*136 + tb];
            float* dst = out0 + (size_t)(n*64 + c)*HW256 + p0 + tb;
            float4v o;
#pragma unroll
            for (int r = 0; r < 4; ++r) o[r] = t4[r] + acc2[mt][nt][r] + add;
            *(float4v*)dst = o;
        }
}

// ---------------------------------------------------------------------------
extern "C" void kernel_launch(void* const* d_in, const int* in_sizes, int n_in,
                              void* d_out, int out_size, void* d_ws, size_t ws_size,
                              hipStream_t stream)
{
    (void)in_sizes; (void)n_in; (void)out_size; (void)ws_size;
    const float* x    = (const float*)d_in[0];
    const float* w7a  = (const float*)d_in[1];
    const float* b7a  = (const float*)d_in[2];
    const float* w1   = (const float*)d_in[3];
    const float* b1   = (const float*)d_in[4];
    const float* g1   = (const float*)d_in[5];
    const float* be1  = (const float*)d_in[6];
    const float* w3a  = (const float*)d_in[7];
    const float* b3a  = (const float*)d_in[8];
    const float* g3a  = (const float*)d_in[9];
    const float* be3a = (const float*)d_in[10];
    const float* w3b  = (const float*)d_in[11];
    const float* b3b  = (const float*)d_in[12];
    const float* g3b  = (const float*)d_in[13];
    const float* be3b = (const float*)d_in[14];
    const float* w3c  = (const float*)d_in[15];
    const float* b3c  = (const float*)d_in[16];
    const float* g3c  = (const float*)d_in[17];
    const float* be3c = (const float*)d_in[18];
    const float* w7b  = (const float*)d_in[19];
    const float* b7b  = (const float*)d_in[20];
    const float* akw  = (const float*)d_in[21];
    const float* akb  = (const float*)d_in[22];
    const float* avw  = (const float*)d_in[25];
    const float* avb  = (const float*)d_in[26];
    const float* arw  = (const float*)d_in[27];
    const float* arb  = (const float*)d_in[28];
    const float* lng  = (const float*)d_in[29];
    const float* lnb  = (const float*)d_in[30];
    const float* fc1w = (const float*)d_in[31];
    const float* fc1b = (const float*)d_in[32];
    const float* fc2w = (const float*)d_in[33];
    const float* fc2b = (const float*)d_in[34];

    float* ws = (float*)d_ws;
    // bf16 activation buffers (sizes in f32 units)
    unsigned short* y2ci = (unsigned short*)ws;                         // 2,097,152 sh
    unsigned short* yci  = (unsigned short*)(ws + 1048576);             // 8,388,608 sh
    unsigned short* z1ci = (unsigned short*)(ws + 1048576 + 4194304);   // 8,388,608 sh (z1/z3)
    unsigned short* z2ci = (unsigned short*)(ws + 1048576 + 2*4194304); // 8,388,608 sh
    unsigned short* xci  = (unsigned short*)(ws + 1048576 + 3*4194304); // 8,388,608 sh (persists!)
    float* o_k  = ws + 1048576 + 4*4194304;     // 524,288
    float* o_st = o_k + 524288;                 // 64
    float* o_Sp = o_st + 64;                    // 2,048
    float* o_ad = o_Sp + 2048;                  // 512
    unsigned short* p7aB = (unsigned short*)(o_ad + 512);   // 57,344 sh (28,672 f32)
    float* p1   = o_ad + 512 + 28672;           // 256
    float* q3a  = p1 + 256;
    float* q3b  = q3a + 16;
    float* q3c  = q3b + 16;
    unsigned short* w3aB = (unsigned short*)(q3c + 16);     // 3,072 sh each
    unsigned short* w3bB = w3aB + 3072;
    unsigned short* w3cB = w3bB + 3072;
    unsigned short* pwB  = w3cB + 3072;                     // 57,344 sh
    unsigned short* pwT1 = pwB + 57344;                     // 4,096 sh
    unsigned short* pwT2 = pwT1 + 4096;                     // 4,096 sh

    unsigned short* z3ci = z1ci;   // overwrites dead z1
    float* out0 = (float*)d_out;

    prepack<<<224, 256, 0, stream>>>(w7a, w1, w3a,b3a,g3a,be3a, w3b,b3b,g3b,be3b,
                                     w3c,b3c,g3c,be3c, w7b, fc1w, fc2w,
                                     p7aB, p1, q3a, q3b, q3c, w3aB, w3bB, w3cB,
                                     pwB, pwT1, pwT2);
    x_to_ci<<<2048, 256, 0, stream>>>(x, xci);
    conv7a_mfma<<<dim3(8,8,8), 256, 0, stream>>>(xci, p7aB, b7a, p1, b1, g1, be1, y2ci);
    resize_ci<<<dim3(16,16,8), dim3(16,16), 0, stream>>>(y2ci, yci);
    conv3_mfma<0><<<dim3(16,16,8), 256, 0, stream>>>(yci,  w3aB, q3a, nullptr, z1ci);
    conv3_mfma<1><<<dim3(16,16,8), 256, 0, stream>>>(z1ci, w3bB, q3b, yci,     z2ci);
    conv3_mfma<1><<<dim3(16,16,8), 256, 0, stream>>>(z2ci, w3cB, q3c, yci,     z3ci);
    conv7b_mfma<<<dim3(16,16,8), 256, 0, stream>>>(z3ci, pwB, x, b7b, akw, akb, out0, o_k);
    softmax_stats<<<8, 1024, 0, stream>>>(o_k, o_st);
    att_wsum<<<dim3(8,4,8), 256, 0, stream>>>(out0, o_k, o_st, o_Sp);
    ctx_addc<<<1, 512, 0, stream>>>(o_Sp, o_st, avw, avb, arw, arb, o_ad);
    transformer_mfma<<<4096, 256, 0, stream>>>(out0, o_ad, lng, lnb, pwT1, fc1b, pwT2, fc2b);
}

// Round 10
// 324.222 us; speedup vs baseline: 11.0161x; 1.1418x over previous
//
#include <hip/hip_runtime.h>
#include <math.h>

#define DI __device__ __forceinline__
#define HW128 (128*128)
#define HW256 (256*256)

__device__ const float BN_RS = 0.9999950000374997f; // 1/sqrt(1+1e-5)

DI float leakyf(float x){ return x >= 0.f ? x : 0.2f*x; }

DI unsigned short f2bf(float f){
    unsigned u = __float_as_uint(f);
    return (unsigned short)((u + 0x7fffu + ((u >> 16) & 1u)) >> 16);
}
DI void unpack2(unsigned u, float& lo, float& hi){
    lo = __uint_as_float(u << 16);
    hi = __uint_as_float(u & 0xffff0000u);
}
DI void load8(const uint4* s, size_t idx, unsigned* d){
    uint4 t0 = s[idx], t1 = s[idx + 1];
    d[0]=t0.x; d[1]=t0.y; d[2]=t0.z; d[3]=t0.w;
    d[4]=t1.x; d[5]=t1.y; d[6]=t1.z; d[7]=t1.w;
}

typedef __attribute__((ext_vector_type(8))) short short8v;
typedef __attribute__((ext_vector_type(4))) float float4v;

// ---------------------------------------------------------------------------
// Prepack.
// ---------------------------------------------------------------------------
__global__ __launch_bounds__(256) void prepack(
    const float* __restrict__ w7a, const float* __restrict__ w1,
    const float* __restrict__ w3a, const float* __restrict__ b3a, const float* __restrict__ g3a, const float* __restrict__ be3a,
    const float* __restrict__ w3b, const float* __restrict__ b3b, const float* __restrict__ g3b, const float* __restrict__ be3b,
    const float* __restrict__ w3c, const float* __restrict__ b3c, const float* __restrict__ g3c, const float* __restrict__ be3c,
    const float* __restrict__ w7b, const float* __restrict__ fc1w, const float* __restrict__ fc2w,
    unsigned short* __restrict__ p7aB, float* __restrict__ p1,
    float* __restrict__ q3a, float* __restrict__ q3b, float* __restrict__ q3c,
    unsigned short* __restrict__ w3aB, unsigned short* __restrict__ w3bB, unsigned short* __restrict__ w3cB,
    unsigned short* __restrict__ pwB,
    unsigned short* __restrict__ pwT1, unsigned short* __restrict__ pwT2)
{
    int i = blockIdx.x * 256 + threadIdx.x;
    if (i < 57344) {                                      // conv7a MFMA weights
        int g = i / 14336, rem = i - g*14336;
        int ks = rem >> 9, oc = (rem >> 5) & 15, k = rem & 31;
        int ky = ks >> 2, kx = ((ks & 3) << 1) + (k >> 4), ic = g*16 + (k & 15);
        p7aB[i] = (kx < 7) ? f2bf(w7a[(oc*64 + ic)*49 + ky*7 + kx]) : (unsigned short)0;
    }
    if (i < 57344) {                                      // conv7b MFMA weights
        int ks = i >> 11, oc = (i >> 5) & 63, k = i & 31;
        int ky = ks >> 2, kx = ((ks & 3) << 1) + (k >> 4), ic = k & 15;
        pwB[i] = (kx < 7) ? f2bf(w7b[((oc*16 + ic)*7 + ky)*7 + kx]) : (unsigned short)0;
    }
    if (i < 3072) {                                       // conv3 MFMA weights ×3
        int ks = i >> 9, oc = (i >> 5) & 15, k = i & 31;
        int ky = ks >> 1, kx = ((ks & 1) << 1) + (k >> 4), ic = k & 15;
        if (kx < 3) {
            int src = (oc*16 + ic)*9 + ky*3 + kx;
            w3aB[i] = f2bf(w3a[src] * (g3a[oc]*BN_RS));
            w3bB[i] = f2bf(w3b[src] * (g3b[oc]*BN_RS));
            w3cB[i] = f2bf(w3c[src] * (g3c[oc]*BN_RS));
        } else {
            w3aB[i] = 0; w3bB[i] = 0; w3cB[i] = 0;
        }
    }
    if (i < 256) { int oc = i & 15, ic = i >> 4; p1[i] = w1[oc*16 + ic]; }
    if (i < 16) {
        q3a[i] = b3a[i]*(g3a[i]*BN_RS) + be3a[i];
        q3b[i] = b3b[i]*(g3b[i]*BN_RS) + be3b[i];
        q3c[i] = b3c[i]*(g3c[i]*BN_RS) + be3c[i];
    }
    if (i < 4096) { pwT1[i] = f2bf(fc1w[i]); pwT2[i] = f2bf(fc2w[i]); }
}

// ---------------------------------------------------------------------------
// x (8,64,128,128) f32 -> xci bf16 [n][g=ic/16][y*128+x][16]
// ---------------------------------------------------------------------------
__global__ __launch_bounds__(256) void x_to_ci(
    const float* __restrict__ x, unsigned short* __restrict__ xci)
{
    int idx = blockIdx.x*256 + threadIdx.x;   // 524,288
    int p = idx & 16383, gn = idx >> 14;
    int g = gn & 3, n = gn >> 2;
    const float* xb = x + (size_t)(n*64 + g*16)*HW128 + p;
    unsigned q[8];
#pragma unroll
    for (int h = 0; h < 8; ++h) {
        float a0 = xb[(size_t)(2*h)*HW128];
        float a1 = xb[(size_t)(2*h + 1)*HW128];
        q[h] = (unsigned)f2bf(a0) | ((unsigned)f2bf(a1) << 16);
    }
    uint4* dst = (uint4*)xci + (size_t)idx*2;
    dst[0] = make_uint4(q[0], q[1], q[2], q[3]);
    dst[1] = make_uint4(q[4], q[5], q[6], q[7]);
}

// ---------------------------------------------------------------------------
// conv7x7 64->16 MFMA + f32 1x1 + leaky + BN epilogue -> y2_ci bf16
// ---------------------------------------------------------------------------
__global__ __launch_bounds__(256) void conv7a_mfma(
    const unsigned short* __restrict__ xci,
    const unsigned short* __restrict__ pw,
    const float* __restrict__ b7a, const float* __restrict__ p1,
    const float* __restrict__ b1, const float* __restrict__ bng,
    const float* __restrict__ bnb, unsigned short* __restrict__ y2ci)
{
    __shared__ __align__(16) unsigned char lds[17408];
    unsigned short* tile = (unsigned short*)lds;   // [22][24][16] bf16
    float* P16 = (float*)lds;                      // [256][17] f32

    const int tid = threadIdx.x;
    const int n = blockIdx.z, ox = blockIdx.x*16, oy = blockIdx.y*16;
    const int w = tid >> 6, l = tid & 63, lg = l >> 4, ln = l & 15;

    float4v acc[4];
#pragma unroll
    for (int mi = 0; mi < 4; ++mi) acc[mi] = (float4v){0.f,0.f,0.f,0.f};

    const uint4* xc4 = (const uint4*)xci;
    uint4* tl4 = (uint4*)tile;
    const short8v* Bb = (const short8v*)pw;

    for (int g = 0; g < 4; ++g) {
        __syncthreads();
        for (int u = tid; u < 1056; u += 256) {
            int r = u / 48, s = u - r*48;
            int y = oy + r - 3, xcol = ox + (s >> 1) - 3;
            uint4 v = make_uint4(0u,0u,0u,0u);
            if (y >= 0 && y < 128 && xcol >= 0 && xcol < 128)
                v = xc4[((size_t)(n*4 + g)*16384 + y*128 + xcol)*2 + (s & 1)];
            tl4[u] = v;
        }
        __syncthreads();
        for (int ks = 0; ks < 28; ++ks) {
            const int ky = ks >> 2, kxp = (ks & 3) << 1;
            short8v b = Bb[(g*28 + ks)*64 + ln*4 + lg];
            short8v a[4];
#pragma unroll
            for (int mi = 0; mi < 4; ++mi) {
                int row = (4*w + mi) + ky;
                a[mi] = *(const short8v*)(tile + (row*24 + ln + kxp)*16 + lg*8);
            }
#pragma unroll
            for (int mi = 0; mi < 4; ++mi)
                acc[mi] = __builtin_amdgcn_mfma_f32_16x16x32_bf16(a[mi], b, acc[mi], 0, 0, 0);
        }
    }
    __syncthreads();
    const float bo = b7a[ln];
#pragma unroll
    for (int mi = 0; mi < 4; ++mi)
#pragma unroll
        for (int r = 0; r < 4; ++r)
            P16[((4*w + mi)*16 + lg*4 + r)*17 + ln] = leakyf(acc[mi][r] + bo);
    __syncthreads();
    const int py = tid >> 4, pxx = tid & 15;
    float lv[16];
#pragma unroll
    for (int ic = 0; ic < 16; ++ic) lv[ic] = P16[tid*17 + ic];
    float u16[16];
#pragma unroll
    for (int o = 0; o < 16; ++o) {
        float u = b1[o];
#pragma unroll
        for (int ic = 0; ic < 16; ++ic) u += lv[ic] * p1[ic*16 + o];
        u = leakyf(u);
        u16[o] = u * (bng[o]*BN_RS) + bnb[o];
    }
    const int p = (oy + py)*128 + ox + pxx;
    unsigned q[8];
#pragma unroll
    for (int h = 0; h < 8; ++h)
        q[h] = (unsigned)f2bf(u16[2*h]) | ((unsigned)f2bf(u16[2*h+1]) << 16);
    uint4* dst = (uint4*)y2ci + (size_t)(n*16384 + p)*2;
    dst[0] = make_uint4(q[0], q[1], q[2], q[3]);
    dst[1] = make_uint4(q[4], q[5], q[6], q[7]);
}

// ---------------------------------------------------------------------------
// Bilinear resize 128->256 on ci layout.
// ---------------------------------------------------------------------------
__global__ __launch_bounds__(256) void resize_ci(
    const unsigned short* __restrict__ y2ci, unsigned short* __restrict__ yci)
{
    const int n = blockIdx.z;
    const int ox = blockIdx.x*16 + threadIdx.x;
    const int oy = blockIdx.y*16 + threadIdx.y;
    float sy = oy * (127.f/255.f), sx = ox * (127.f/255.f);
    int y0 = min((int)sy, 126), x0 = min((int)sx, 126);
    float fy = sy - y0, fx = sx - x0;
    const uint4* src = (const uint4*)y2ci;
    size_t i00 = ((size_t)n*16384 + y0*128 + x0)*2;
    unsigned A00[8], A01[8], A10[8], A11[8];
    load8(src, i00,       A00);
    load8(src, i00 + 2,   A01);
    load8(src, i00 + 256, A10);
    load8(src, i00 + 258, A11);
    unsigned q[8];
#pragma unroll
    for (int h = 0; h < 8; ++h) {
        float l00, h00, l01, h01, l10, h10, l11, h11;
        unpack2(A00[h], l00, h00); unpack2(A01[h], l01, h01);
        unpack2(A10[h], l10, h10); unpack2(A11[h], l11, h11);
        float lo = (l00*(1.f-fx) + l01*fx)*(1.f-fy) + (l10*(1.f-fx) + l11*fx)*fy;
        float hi = (h00*(1.f-fx) + h01*fx)*(1.f-fy) + (h10*(1.f-fx) + h11*fx)*fy;
        q[h] = (unsigned)f2bf(lo) | ((unsigned)f2bf(hi) << 16);
    }
    uint4* dst = (uint4*)yci + ((size_t)n*65536 + oy*256 + ox)*2;
    dst[0] = make_uint4(q[0], q[1], q[2], q[3]);
    dst[1] = make_uint4(q[4], q[5], q[6], q[7]);
}

// ---------------------------------------------------------------------------
// 3x3 conv 16->16 via MFMA implicit GEMM on ci layout, BN pre-folded.
// ---------------------------------------------------------------------------
template<int MODE>
__global__ __launch_bounds__(256) void conv3_mfma(
    const unsigned short* __restrict__ in_ci,
    const unsigned short* __restrict__ wB, const float* __restrict__ q3,
    const unsigned short* __restrict__ res_ci,
    unsigned short* __restrict__ out_ci)
{
    __shared__ __align__(16) unsigned char lds[17408];
    unsigned short* tile = (unsigned short*)lds;   // [18][20][16] bf16
    float* P16 = (float*)lds;                      // [256][17] f32

    const int tid = threadIdx.x;
    const int n = blockIdx.z, ox = blockIdx.x*16, oy = blockIdx.y*16;
    const int w = tid >> 6, l = tid & 63, lg = l >> 4, ln = l & 15;

    const uint4* zc = (const uint4*)in_ci;
    uint4* tl4 = (uint4*)tile;
    for (int u = tid; u < 720; u += 256) {
        int r = u / 40, s = u - r*40;
        int y = oy + r - 1, xcol = ox + (s >> 1) - 1;
        uint4 v = make_uint4(0u,0u,0u,0u);
        if (y >= 0 && y < 256 && xcol >= 0 && xcol < 256)
            v = zc[((size_t)n*65536 + y*256 + xcol)*2 + (s & 1)];
        tl4[u] = v;
    }
    __syncthreads();

    float4v acc[4];
#pragma unroll
    for (int mi = 0; mi < 4; ++mi) acc[mi] = (float4v){0.f,0.f,0.f,0.f};
    const short8v* Bb = (const short8v*)wB;
#pragma unroll
    for (int ks = 0; ks < 6; ++ks) {
        const int ky = ks >> 1, kxp = (ks & 1) << 1;
        short8v b = Bb[(ks*16 + ln)*4 + lg];
        short8v a[4];
#pragma unroll
        for (int mi = 0; mi < 4; ++mi) {
            int row = (4*w + mi) + ky;
            a[mi] = *(const short8v*)(tile + (row*20 + ln + kxp)*16 + lg*8);
        }
#pragma unroll
        for (int mi = 0; mi < 4; ++mi)
            acc[mi] = __builtin_amdgcn_mfma_f32_16x16x32_bf16(a[mi], b, acc[mi], 0, 0, 0);
    }
    __syncthreads();
#pragma unroll
    for (int mi = 0; mi < 4; ++mi)
#pragma unroll
        for (int r = 0; r < 4; ++r)
            P16[((4*w + mi)*16 + lg*4 + r)*17 + ln] = acc[mi][r];
    __syncthreads();

    const int py = tid >> 4, pxx = tid & 15;
    const int p = (oy + py)*256 + ox + pxx;
    float u16[16];
#pragma unroll
    for (int o = 0; o < 16; ++o) u16[o] = P16[tid*17 + o] + q3[o];
    if (MODE == 0) {
#pragma unroll
        for (int o = 0; o < 16; ++o) u16[o] = leakyf(u16[o]);
    } else {
        unsigned R[8];
        load8((const uint4*)res_ci, ((size_t)n*65536 + p)*2, R);
#pragma unroll
        for (int h = 0; h < 8; ++h) {
            float lo, hi; unpack2(R[h], lo, hi);
            u16[2*h] += lo; u16[2*h+1] += hi;
        }
    }
    unsigned q[8];
#pragma unroll
    for (int h = 0; h < 8; ++h)
        q[h] = (unsigned)f2bf(u16[2*h]) | ((unsigned)f2bf(u16[2*h+1]) << 16);
    uint4* dst = (uint4*)out_ci + ((size_t)n*65536 + p)*2;
    dst[0] = make_uint4(q[0], q[1], q[2], q[3]);
    dst[1] = make_uint4(q[4], q[5], q[6], q[7]);
}

// ---------------------------------------------------------------------------
// conv7x7 16->64 MFMA + fused epilogue (bias + bilinear identity + k logit).
// R10: x-tile staged from xci with unit-linear (conflict-free) writes and
// pixel stride padded to 72 shorts (9 uint4) to spread epilogue reads.
// ---------------------------------------------------------------------------
__global__ __launch_bounds__(256) void conv7b_mfma(
    const unsigned short* __restrict__ z_ci,
    const unsigned short* __restrict__ pwB,
    const unsigned short* __restrict__ xci,
    const float* __restrict__ bias,
    const float* __restrict__ akw, const float* __restrict__ akb,
    float* __restrict__ out0, float* __restrict__ kbuf)
{
    __shared__ __align__(16) unsigned char lds[17408 + 14400];
    unsigned short* tile = (unsigned short*)lds;          // [22][24][16] bf16
    float* P16 = (float*)lds;                             // [256][17] f32 (aliases tile)
    unsigned short* xt16 = (unsigned short*)(lds + 17408);// [100 px][72] bf16 (pad 8)

    const int tid = threadIdx.x;
    const int n = blockIdx.z, ox = blockIdx.x*16, oy = blockIdx.y*16;
    const float SC = 127.f/255.f;
    const int ybase = (int)(oy*SC), xbase = (int)(ox*SC);

    // stage conv input tile
    const uint4* zc = (const uint4*)z_ci;
    uint4* tl4 = (uint4*)tile;
    for (int u = tid; u < 1056; u += 256) {
        int r = u / 48, s = u - r*48;
        int y = oy + r - 3, xcol = ox + (s >> 1) - 3;
        uint4 v = make_uint4(0u, 0u, 0u, 0u);
        if (y >= 0 && y < 256 && xcol >= 0 && xcol < 256)
            v = zc[(size_t)((n*256 + y)*256 + xcol)*2 + (s & 1)];
        tl4[u] = v;
    }
    // stage x tile from xci: 100 px x 9 uint4 (unit-linear -> conflict-free)
    const uint4* xc4 = (const uint4*)xci;
    uint4* xt4 = (uint4*)xt16;
    for (int u = tid; u < 900; u += 256) {
        int p = u / 9, s = u - p*9;
        uint4 v = make_uint4(0u, 0u, 0u, 0u);
        if (s < 8) {
            int g = s >> 1, half = s & 1;
            int r = p / 10, c = p - r*10;
            int y = ybase + r, xcc = xbase + c;
            if (y < 128 && xcc < 128)
                v = xc4[((size_t)(n*4 + g)*16384 + y*128 + xcc)*2 + half];
        }
        xt4[u] = v;
    }
    __syncthreads();

    const int w = tid >> 6, l = tid & 63;
    const int lg = l >> 4, ln = l & 15;
    float4v acc[4][4];
#pragma unroll
    for (int mi = 0; mi < 4; ++mi)
#pragma unroll
        for (int nt = 0; nt < 4; ++nt)
            acc[mi][nt] = (float4v){0.f, 0.f, 0.f, 0.f};

    const short8v* Bb = (const short8v*)pwB;
    for (int ks = 0; ks < 28; ++ks) {
        const int ky = ks >> 2, kxp = (ks & 3) << 1;
        short8v a[4], b[4];
#pragma unroll
        for (int mi = 0; mi < 4; ++mi) {
            int row = (4*w + mi) + ky;
            a[mi] = *(const short8v*)(tile + (row*24 + ln + kxp)*16 + lg*8);
        }
#pragma unroll
        for (int nt = 0; nt < 4; ++nt)
            b[nt] = Bb[ks*256 + nt*64 + ln*4 + lg];
#pragma unroll
        for (int mi = 0; mi < 4; ++mi)
#pragma unroll
            for (int nt = 0; nt < 4; ++nt)
                acc[mi][nt] = __builtin_amdgcn_mfma_f32_16x16x32_bf16(
                    a[mi], b[nt], acc[mi][nt], 0, 0, 0);
    }

    // epilogue: per-thread pixel
    const int py = tid >> 4, pxx = tid & 15;
    const int ohy = oy + py, ohx = ox + pxx;
    float sy = ohy*SC, sx = ohx*SC;
    int y0 = min((int)sy, 126), x0 = min((int)sx, 126);
    float fy = sy - y0, fx = sx - x0;
    const int ly = y0 - ybase, lx = x0 - xbase;
    const int p = ohy*256 + ohx;
    const uint4* xt4c = (const uint4*)xt16;
    const size_t q00 = (size_t)(ly*10 + lx)*9;
    float kacc = akb[0];

    for (int nt = 0; nt < 4; ++nt) {
        __syncthreads();
#pragma unroll
        for (int mi = 0; mi < 4; ++mi)
#pragma unroll
            for (int r = 0; r < 4; ++r)
                P16[((4*w + mi)*16 + lg*4 + r)*17 + ln] = acc[mi][nt][r];
        __syncthreads();
        unsigned A00[8], A01[8], A10[8], A11[8];
        size_t qb = q00 + nt*2;
        load8(xt4c, qb,      A00);
        load8(xt4c, qb + 9,  A01);
        load8(xt4c, qb + 90, A10);
        load8(xt4c, qb + 99, A11);
        float u16[16];
#pragma unroll
        for (int h = 0; h < 8; ++h) {
            float l00, h00, l01, h01, l10, h10, l11, h11;
            unpack2(A00[h], l00, h00); unpack2(A01[h], l01, h01);
            unpack2(A10[h], l10, h10); unpack2(A11[h], l11, h11);
            u16[2*h]   = (l00*(1.f-fx) + l01*fx)*(1.f-fy) + (l10*(1.f-fx) + l11*fx)*fy;
            u16[2*h+1] = (h00*(1.f-fx) + h01*fx)*(1.f-fy) + (h10*(1.f-fx) + h11*fx)*fy;
        }
#pragma unroll
        for (int o = 0; o < 16; ++o) {
            int oc = nt*16 + o;
            float u = P16[tid*17 + o] + bias[oc] + u16[o];
            out0[(size_t)(n*64 + oc)*HW256 + p] = u;
            kacc += akw[oc] * u;
        }
    }
    kbuf[n*65536 + p] = kacc;
}

// ---------------------------------------------------------------------------
// Softmax stats, stage 1: per-chunk max + sum(exp(k - chunk_max)).
// grid (8 pc, 8 n), 256 thr; chunk = 8192.
// ---------------------------------------------------------------------------
__global__ __launch_bounds__(256) void softmax_part(
    const float* __restrict__ kb, float* __restrict__ pst)
{
    __shared__ float red[4];
    __shared__ float bcast;
    const int pc = blockIdx.x, n = blockIdx.y, tid = threadIdx.x;
    const float* kp = kb + n*65536 + pc*8192;
    float mx = -3.0e38f;
    for (int i = tid; i < 8192; i += 256) mx = fmaxf(mx, kp[i]);
#pragma unroll
    for (int off = 1; off < 64; off <<= 1) mx = fmaxf(mx, __shfl_xor(mx, off));
    int w = tid >> 6, l = tid & 63;
    if (l == 0) red[w] = mx;
    __syncthreads();
    if (tid == 0) bcast = fmaxf(fmaxf(red[0], red[1]), fmaxf(red[2], red[3]));
    __syncthreads();
    float BM = bcast;
    float s = 0.f;
    for (int i = tid; i < 8192; i += 256) s += __expf(kp[i] - BM);
#pragma unroll
    for (int off = 1; off < 64; off <<= 1) s += __shfl_xor(s, off);
    __syncthreads();
    if (l == 0) red[w] = s;
    __syncthreads();
    if (tid == 0) {
        pst[(n*8 + pc)*2]     = BM;
        pst[(n*8 + pc)*2 + 1] = red[0] + red[1] + red[2] + red[3];
    }
}

// ---------------------------------------------------------------------------
// Softmax stats, stage 2: logsumexp merge of the 8 chunks per image.
// ---------------------------------------------------------------------------
__global__ __launch_bounds__(64) void softmax_comb(
    const float* __restrict__ pst, float* __restrict__ st)
{
    int tid = threadIdx.x;
    if (tid < 8) {
        int n = tid;
        float MX = -3.0e38f;
        for (int c = 0; c < 8; ++c) MX = fmaxf(MX, pst[(n*8 + c)*2]);
        float S = 0.f;
        for (int c = 0; c < 8; ++c)
            S += pst[(n*8 + c)*2 + 1] * __expf(pst[(n*8 + c)*2] - MX);
        st[n] = MX; st[8 + n] = 1.f / S;
    }
}

// ---------------------------------------------------------------------------
// Partial S: Sp[n][pc][c] = sum over p-chunk of exp(k-mx)*out0[n,c,p].
// ---------------------------------------------------------------------------
__global__ __launch_bounds__(256) void att_wsum(
    const float* __restrict__ out0, const float* __restrict__ kb,
    const float* __restrict__ st, float* __restrict__ Sp)
{
    const int cg = blockIdx.x, pc = blockIdx.y, n = blockIdx.z, c0 = cg*8;
    const float mx = st[n];
    const float* kp = kb + n*65536 + pc*16384;
    const float* base = out0 + (size_t)(n*64 + c0)*HW256 + pc*16384;
    float acc[8];
#pragma unroll
    for (int c = 0; c < 8; ++c) acc[c] = 0.f;
    for (int p = threadIdx.x; p < 16384; p += 256) {
        float e = __expf(kp[p] - mx);
#pragma unroll
        for (int c = 0; c < 8; ++c) acc[c] += e * base[c*HW256 + p];
    }
#pragma unroll
    for (int c = 0; c < 8; ++c)
#pragma unroll
        for (int off = 1; off < 64; off <<= 1) acc[c] += __shfl_xor(acc[c], off);
    __shared__ float red[4][8];
    int w = threadIdx.x >> 6, l = threadIdx.x & 63;
    if (l == 0) {
#pragma unroll
        for (int c = 0; c < 8; ++c) red[w][c] = acc[c];
    }
    __syncthreads();
    if (threadIdx.x < 8)
        Sp[n*256 + pc*64 + c0 + threadIdx.x] =
            red[0][threadIdx.x] + red[1][threadIdx.x] + red[2][threadIdx.x] + red[3][threadIdx.x];
}

// ---------------------------------------------------------------------------
// context + per-(n,c) attention addend (reduces the 4 p-chunks).
// ---------------------------------------------------------------------------
__global__ __launch_bounds__(512) void ctx_addc(
    const float* __restrict__ Sp, const float* __restrict__ st,
    const float* __restrict__ avw, const float* __restrict__ avb,
    const float* __restrict__ arw, const float* __restrict__ arb,
    float* __restrict__ addc)
{
    __shared__ float ctx[8][8];
    const int tid = threadIdx.x;
    if (tid < 64) {
        int n = tid >> 3, vc = tid & 7;
        float s = 0.f;
        for (int c = 0; c < 64; ++c) {
            float Sv = Sp[n*256 + c] + Sp[n*256 + 64 + c]
                     + Sp[n*256 + 128 + c] + Sp[n*256 + 192 + c];
            s += avw[vc*64 + c] * Sv;
        }
        ctx[n][vc] = s * st[8 + n] + avb[vc];
    }
    __syncthreads();
    int n = tid >> 6, c = tid & 63;
    float a = arb[c];
#pragma unroll
    for (int vc = 0; vc < 8; ++vc) a += arw[c*8 + vc] * ctx[n][vc];
    addc[n*64 + c] = a;
}

// ---------------------------------------------------------------------------
// Transformer via MFMA (R9 verified: Xt residual, conflict-free staging).
// ---------------------------------------------------------------------------
__global__ __launch_bounds__(256) void transformer_mfma(
    float* __restrict__ out0, const float* __restrict__ addc,
    const float* __restrict__ lng, const float* __restrict__ lnb,
    const unsigned short* __restrict__ W1b, const float* __restrict__ fc1b,
    const unsigned short* __restrict__ W2b, const float* __restrict__ fc2b)
{
    __shared__ __align__(16) unsigned char lds[34816 + 18432];
    float*          Xt = (float*)lds;                         // [64][136] f32
    unsigned short* Xb = (unsigned short*)(lds + 34816);      // [128][72] bf16
    unsigned short* Hb = Xb;                                  // aliases Xb

    const int tid = threadIdx.x;
    const int n = blockIdx.x >> 9;
    const int p0 = (blockIdx.x & 511) << 7;
    const float* ac = addc + n*64;

#pragma unroll
    for (int k = 0; k < 8; ++k) {
        int v = k*256 + tid;
        int c = v >> 5, i4 = (v & 31) << 2;
        float4v q = *(const float4v*)(out0 + (size_t)(n*64 + c)*HW256 + p0 + i4);
        float a = ac[c];
#pragma unroll
        for (int r = 0; r < 4; ++r) q[r] += a;
        *(float4v*)&Xt[c*136 + i4] = q;
    }
    __syncthreads();

    if (tid < 128) {
        float t[64];
#pragma unroll
        for (int c = 0; c < 64; ++c) t[c] = Xt[c*136 + tid];
        float mu = 0.f;
#pragma unroll
        for (int c = 0; c < 64; ++c) mu += t[c];
        mu *= (1.f/64.f);
        float var = 0.f;
#pragma unroll
        for (int c = 0; c < 64; ++c) { float d = t[c] - mu; var += d*d; }
        var *= (1.f/64.f);
        float rs = rsqrtf(var + 1e-5f);
#pragma unroll
        for (int c8 = 0; c8 < 8; ++c8) {
            short8v pk;
#pragma unroll
            for (int e = 0; e < 8; ++e) {
                int c = c8*8 + e;
                pk[e] = (short)f2bf((t[c] - mu)*rs*lng[c] + lnb[c]);
            }
            *(short8v*)&Xb[tid*72 + c8*8] = pk;
        }
    }
    __syncthreads();

    const int w = tid >> 6, l = tid & 63, lg = l >> 4, ln = l & 15;

    float4v acc1[2][4];
#pragma unroll
    for (int mt = 0; mt < 2; ++mt)
#pragma unroll
        for (int nt = 0; nt < 4; ++nt) acc1[mt][nt] = (float4v){0.f,0.f,0.f,0.f};
#pragma unroll
    for (int kk = 0; kk < 2; ++kk) {
        short8v a[2], b[4];
#pragma unroll
        for (int mt = 0; mt < 2; ++mt)
            a[mt] = *(const short8v*)&Xb[(w*32 + mt*16 + ln)*72 + kk*32 + lg*8];
#pragma unroll
        for (int nt = 0; nt < 4; ++nt)
            b[nt] = *(const short8v*)&W1b[(nt*16 + ln)*64 + kk*32 + lg*8];
#pragma unroll
        for (int mt = 0; mt < 2; ++mt)
#pragma unroll
            for (int nt = 0; nt < 4; ++nt)
                acc1[mt][nt] = __builtin_amdgcn_mfma_f32_16x16x32_bf16(
                    a[mt], b[nt], acc1[mt][nt], 0, 0, 0);
    }
    __syncthreads();
#pragma unroll
    for (int mt = 0; mt < 2; ++mt)
#pragma unroll
        for (int nt = 0; nt < 4; ++nt) {
            int j = nt*16 + ln;
            float bj = fc1b[j];
#pragma unroll
            for (int r = 0; r < 4; ++r) {
                int token = w*32 + mt*16 + lg*4 + r;
                float m = acc1[mt][nt][r] + bj;
                float g = 0.5f*m*(1.f + erff(m*0.70710678118654752f));
                Hb[token*72 + j] = f2bf(g);
            }
        }
    __syncthreads();

    float4v acc2[2][4];
#pragma unroll
    for (int mt = 0; mt < 2; ++mt)
#pragma unroll
        for (int nt = 0; nt < 4; ++nt) acc2[mt][nt] = (float4v){0.f,0.f,0.f,0.f};
#pragma unroll
    for (int kk = 0; kk < 2; ++kk) {
        short8v a[2], b[4];
#pragma unroll
        for (int mt = 0; mt < 2; ++mt)
            a[mt] = *(const short8v*)&Hb[(w*32 + mt*16 + ln)*72 + kk*32 + lg*8];
#pragma unroll
        for (int nt = 0; nt < 4; ++nt)
            b[nt] = *(const short8v*)&W2b[(nt*16 + ln)*64 + kk*32 + lg*8];
#pragma unroll
        for (int mt = 0; mt < 2; ++mt)
#pragma unroll
            for (int nt = 0; nt < 4; ++nt)
                acc2[mt][nt] = __builtin_amdgcn_mfma_f32_16x16x32_bf16(
                    a[mt], b[nt], acc2[mt][nt], 0, 0, 0);
    }
#pragma unroll
    for (int mt = 0; mt < 2; ++mt)
#pragma unroll
        for (int nt = 0; nt < 4; ++nt) {
            int c = nt*16 + ln;
            int tb = w*32 + mt*16 + lg*4;
            float add = fc2b[c];
            float4v t4 = *(const float4v*)&Xt[c*136 + tb];
            float* dst = out0 + (size_t)(n*64 + c)*HW256 + p0 + tb;
            float4v o;
#pragma unroll
            for (int r = 0; r < 4; ++r) o[r] = t4[r] + acc2[mt][nt][r] + add;
            *(float4v*)dst = o;
        }
}

// ---------------------------------------------------------------------------
extern "C" void kernel_launch(void* const* d_in, const int* in_sizes, int n_in,
                              void* d_out, int out_size, void* d_ws, size_t ws_size,
                              hipStream_t stream)
{
    (void)in_sizes; (void)n_in; (void)out_size; (void)ws_size;
    const float* x    = (const float*)d_in[0];
    const float* w7a  = (const float*)d_in[1];
    const float* b7a  = (const float*)d_in[2];
    const float* w1   = (const float*)d_in[3];
    const float* b1   = (const float*)d_in[4];
    const float* g1   = (const float*)d_in[5];
    const float* be1  = (const float*)d_in[6];
    const float* w3a  = (const float*)d_in[7];
    const float* b3a  = (const float*)d_in[8];
    const float* g3a  = (const float*)d_in[9];
    const float* be3a = (const float*)d_in[10];
    const float* w3b  = (const float*)d_in[11];
    const float* b3b  = (const float*)d_in[12];
    const float* g3b  = (const float*)d_in[13];
    const float* be3b = (const float*)d_in[14];
    const float* w3c  = (const float*)d_in[15];
    const float* b3c  = (const float*)d_in[16];
    const float* g3c  = (const float*)d_in[17];
    const float* be3c = (const float*)d_in[18];
    const float* w7b  = (const float*)d_in[19];
    const float* b7b  = (const float*)d_in[20];
    const float* akw  = (const float*)d_in[21];
    const float* akb  = (const float*)d_in[22];
    const float* avw  = (const float*)d_in[25];
    const float* avb  = (const float*)d_in[26];
    const float* arw  = (const float*)d_in[27];
    const float* arb  = (const float*)d_in[28];
    const float* lng  = (const float*)d_in[29];
    const float* lnb  = (const float*)d_in[30];
    const float* fc1w = (const float*)d_in[31];
    const float* fc1b = (const float*)d_in[32];
    const float* fc2w = (const float*)d_in[33];
    const float* fc2b = (const float*)d_in[34];

    float* ws = (float*)d_ws;
    unsigned short* y2ci = (unsigned short*)ws;                         // 2,097,152 sh
    unsigned short* yci  = (unsigned short*)(ws + 1048576);             // 8,388,608 sh
    unsigned short* z1ci = (unsigned short*)(ws + 1048576 + 4194304);   // 8,388,608 sh (z1/z3)
    unsigned short* z2ci = (unsigned short*)(ws + 1048576 + 2*4194304); // 8,388,608 sh
    unsigned short* xci  = (unsigned short*)(ws + 1048576 + 3*4194304); // 8,388,608 sh (persists)
    float* o_k   = ws + 1048576 + 4*4194304;    // 524,288
    float* o_st  = o_k + 524288;                // 64
    float* o_pst = o_st + 64;                   // 128
    float* o_Sp  = o_pst + 128;                 // 2,048
    float* o_ad  = o_Sp + 2048;                 // 512
    unsigned short* p7aB = (unsigned short*)(o_ad + 512);   // 57,344 sh
    float* p1   = o_ad + 512 + 28672;           // 256
    float* q3a  = p1 + 256;
    float* q3b  = q3a + 16;
    float* q3c  = q3b + 16;
    unsigned short* w3aB = (unsigned short*)(q3c + 16);     // 3,072 sh each
    unsigned short* w3bB = w3aB + 3072;
    unsigned short* w3cB = w3bB + 3072;
    unsigned short* pwB  = w3cB + 3072;                     // 57,344 sh
    unsigned short* pwT1 = pwB + 57344;                     // 4,096 sh
    unsigned short* pwT2 = pwT1 + 4096;                     // 4,096 sh

    unsigned short* z3ci = z1ci;
    float* out0 = (float*)d_out;

    prepack<<<224, 256, 0, stream>>>(w7a, w1, w3a,b3a,g3a,be3a, w3b,b3b,g3b,be3b,
                                     w3c,b3c,g3c,be3c, w7b, fc1w, fc2w,
                                     p7aB, p1, q3a, q3b, q3c, w3aB, w3bB, w3cB,
                                     pwB, pwT1, pwT2);
    x_to_ci<<<2048, 256, 0, stream>>>(x, xci);
    conv7a_mfma<<<dim3(8,8,8), 256, 0, stream>>>(xci, p7aB, b7a, p1, b1, g1, be1, y2ci);
    resize_ci<<<dim3(16,16,8), dim3(16,16), 0, stream>>>(y2ci, yci);
    conv3_mfma<0><<<dim3(16,16,8), 256, 0, stream>>>(yci,  w3aB, q3a, nullptr, z1ci);
    conv3_mfma<1><<<dim3(16,16,8), 256, 0, stream>>>(z1ci, w3bB, q3b, yci,     z2ci);
    conv3_mfma<1><<<dim3(16,16,8), 256, 0, stream>>>(z2ci, w3cB, q3c, yci,     z3ci);
    conv7b_mfma<<<dim3(16,16,8), 256, 0, stream>>>(z3ci, pwB, xci, b7b, akw, akb, out0, o_k);
    softmax_part<<<dim3(8,8), 256, 0, stream>>>(o_k, o_pst);
    softmax_comb<<<1, 64, 0, stream>>>(o_pst, o_st);
    att_wsum<<<dim3(8,4,8), 256, 0, stream>>>(out0, o_k, o_st, o_Sp);
    ctx_addc<<<1, 512, 0, stream>>>(o_Sp, o_st, avw, avb, arw, arb, o_ad);
    transformer_mfma<<<4096, 256, 0, stream>>>(out0, o_ad, lng, lnb, pwT1, fc1b, pwT2, fc2b);
}

// Round 11
// 322.723 us; speedup vs baseline: 11.0673x; 1.0046x over previous
//
#include <hip/hip_runtime.h>
#include <math.h>

#define DI __device__ __forceinline__
#define HW128 (128*128)
#define HW256 (256*256)

__device__ const float BN_RS = 0.9999950000374997f; // 1/sqrt(1+1e-5)

DI float leakyf(float x){ return x >= 0.f ? x : 0.2f*x; }

DI unsigned short f2bf(float f){
    unsigned u = __float_as_uint(f);
    return (unsigned short)((u + 0x7fffu + ((u >> 16) & 1u)) >> 16);
}
DI void unpack2(unsigned u, float& lo, float& hi){
    lo = __uint_as_float(u << 16);
    hi = __uint_as_float(u & 0xffff0000u);
}
DI void load8(const uint4* s, size_t idx, unsigned* d){
    uint4 t0 = s[idx], t1 = s[idx + 1];
    d[0]=t0.x; d[1]=t0.y; d[2]=t0.z; d[3]=t0.w;
    d[4]=t1.x; d[5]=t1.y; d[6]=t1.z; d[7]=t1.w;
}

typedef __attribute__((ext_vector_type(8))) short short8v;
typedef __attribute__((ext_vector_type(4))) float float4v;

// ---------------------------------------------------------------------------
// Prepack.
// ---------------------------------------------------------------------------
__global__ __launch_bounds__(256) void prepack(
    const float* __restrict__ w7a, const float* __restrict__ w1,
    const float* __restrict__ w3a, const float* __restrict__ b3a, const float* __restrict__ g3a, const float* __restrict__ be3a,
    const float* __restrict__ w3b, const float* __restrict__ b3b, const float* __restrict__ g3b, const float* __restrict__ be3b,
    const float* __restrict__ w3c, const float* __restrict__ b3c, const float* __restrict__ g3c, const float* __restrict__ be3c,
    const float* __restrict__ w7b, const float* __restrict__ fc1w, const float* __restrict__ fc2w,
    unsigned short* __restrict__ p7aB, float* __restrict__ p1,
    float* __restrict__ q3a, float* __restrict__ q3b, float* __restrict__ q3c,
    unsigned short* __restrict__ w3aB, unsigned short* __restrict__ w3bB, unsigned short* __restrict__ w3cB,
    unsigned short* __restrict__ pwB,
    unsigned short* __restrict__ pwT1, unsigned short* __restrict__ pwT2)
{
    int i = blockIdx.x * 256 + threadIdx.x;
    if (i < 57344) {                                      // conv7a MFMA weights
        int g = i / 14336, rem = i - g*14336;
        int ks = rem >> 9, oc = (rem >> 5) & 15, k = rem & 31;
        int ky = ks >> 2, kx = ((ks & 3) << 1) + (k >> 4), ic = g*16 + (k & 15);
        p7aB[i] = (kx < 7) ? f2bf(w7a[(oc*64 + ic)*49 + ky*7 + kx]) : (unsigned short)0;
    }
    if (i < 57344) {                                      // conv7b MFMA weights
        int ks = i >> 11, oc = (i >> 5) & 63, k = i & 31;
        int ky = ks >> 2, kx = ((ks & 3) << 1) + (k >> 4), ic = k & 15;
        pwB[i] = (kx < 7) ? f2bf(w7b[((oc*16 + ic)*7 + ky)*7 + kx]) : (unsigned short)0;
    }
    if (i < 3072) {                                       // conv3 MFMA weights ×3
        int ks = i >> 9, oc = (i >> 5) & 15, k = i & 31;
        int ky = ks >> 1, kx = ((ks & 1) << 1) + (k >> 4), ic = k & 15;
        if (kx < 3) {
            int src = (oc*16 + ic)*9 + ky*3 + kx;
            w3aB[i] = f2bf(w3a[src] * (g3a[oc]*BN_RS));
            w3bB[i] = f2bf(w3b[src] * (g3b[oc]*BN_RS));
            w3cB[i] = f2bf(w3c[src] * (g3c[oc]*BN_RS));
        } else {
            w3aB[i] = 0; w3bB[i] = 0; w3cB[i] = 0;
        }
    }
    if (i < 256) { int oc = i & 15, ic = i >> 4; p1[i] = w1[oc*16 + ic]; }
    if (i < 16) {
        q3a[i] = b3a[i]*(g3a[i]*BN_RS) + be3a[i];
        q3b[i] = b3b[i]*(g3b[i]*BN_RS) + be3b[i];
        q3c[i] = b3c[i]*(g3c[i]*BN_RS) + be3c[i];
    }
    if (i < 4096) { pwT1[i] = f2bf(fc1w[i]); pwT2[i] = f2bf(fc2w[i]); }
}

// ---------------------------------------------------------------------------
// x (8,64,128,128) f32 -> xci bf16 [n][g=ic/16][y*128+x][16]
// ---------------------------------------------------------------------------
__global__ __launch_bounds__(256) void x_to_ci(
    const float* __restrict__ x, unsigned short* __restrict__ xci)
{
    int idx = blockIdx.x*256 + threadIdx.x;   // 524,288
    int p = idx & 16383, gn = idx >> 14;
    int g = gn & 3, n = gn >> 2;
    const float* xb = x + (size_t)(n*64 + g*16)*HW128 + p;
    unsigned q[8];
#pragma unroll
    for (int h = 0; h < 8; ++h) {
        float a0 = xb[(size_t)(2*h)*HW128];
        float a1 = xb[(size_t)(2*h + 1)*HW128];
        q[h] = (unsigned)f2bf(a0) | ((unsigned)f2bf(a1) << 16);
    }
    uint4* dst = (uint4*)xci + (size_t)idx*2;
    dst[0] = make_uint4(q[0], q[1], q[2], q[3]);
    dst[1] = make_uint4(q[4], q[5], q[6], q[7]);
}

// ---------------------------------------------------------------------------
// conv7x7 64->16 MFMA + f32 1x1 + leaky + BN epilogue -> y2_ci bf16
// ---------------------------------------------------------------------------
__global__ __launch_bounds__(256) void conv7a_mfma(
    const unsigned short* __restrict__ xci,
    const unsigned short* __restrict__ pw,
    const float* __restrict__ b7a, const float* __restrict__ p1,
    const float* __restrict__ b1, const float* __restrict__ bng,
    const float* __restrict__ bnb, unsigned short* __restrict__ y2ci)
{
    __shared__ __align__(16) unsigned char lds[17408];
    unsigned short* tile = (unsigned short*)lds;   // [22][24][16] bf16
    float* P16 = (float*)lds;                      // [256][17] f32

    const int tid = threadIdx.x;
    const int n = blockIdx.z, ox = blockIdx.x*16, oy = blockIdx.y*16;
    const int w = tid >> 6, l = tid & 63, lg = l >> 4, ln = l & 15;

    float4v acc[4];
#pragma unroll
    for (int mi = 0; mi < 4; ++mi) acc[mi] = (float4v){0.f,0.f,0.f,0.f};

    const uint4* xc4 = (const uint4*)xci;
    uint4* tl4 = (uint4*)tile;
    const short8v* Bb = (const short8v*)pw;

    for (int g = 0; g < 4; ++g) {
        __syncthreads();
        for (int u = tid; u < 1056; u += 256) {
            int r = u / 48, s = u - r*48;
            int y = oy + r - 3, xcol = ox + (s >> 1) - 3;
            uint4 v = make_uint4(0u,0u,0u,0u);
            if (y >= 0 && y < 128 && xcol >= 0 && xcol < 128)
                v = xc4[((size_t)(n*4 + g)*16384 + y*128 + xcol)*2 + (s & 1)];
            tl4[u] = v;
        }
        __syncthreads();
        for (int ks = 0; ks < 28; ++ks) {
            const int ky = ks >> 2, kxp = (ks & 3) << 1;
            short8v b = Bb[(g*28 + ks)*64 + ln*4 + lg];
            short8v a[4];
#pragma unroll
            for (int mi = 0; mi < 4; ++mi) {
                int row = (4*w + mi) + ky;
                a[mi] = *(const short8v*)(tile + (row*24 + ln + kxp)*16 + lg*8);
            }
#pragma unroll
            for (int mi = 0; mi < 4; ++mi)
                acc[mi] = __builtin_amdgcn_mfma_f32_16x16x32_bf16(a[mi], b, acc[mi], 0, 0, 0);
        }
    }
    __syncthreads();
    const float bo = b7a[ln];
#pragma unroll
    for (int mi = 0; mi < 4; ++mi)
#pragma unroll
        for (int r = 0; r < 4; ++r)
            P16[((4*w + mi)*16 + lg*4 + r)*17 + ln] = leakyf(acc[mi][r] + bo);
    __syncthreads();
    const int py = tid >> 4, pxx = tid & 15;
    float lv[16];
#pragma unroll
    for (int ic = 0; ic < 16; ++ic) lv[ic] = P16[tid*17 + ic];
    float u16[16];
#pragma unroll
    for (int o = 0; o < 16; ++o) {
        float u = b1[o];
#pragma unroll
        for (int ic = 0; ic < 16; ++ic) u += lv[ic] * p1[ic*16 + o];
        u = leakyf(u);
        u16[o] = u * (bng[o]*BN_RS) + bnb[o];
    }
    const int p = (oy + py)*128 + ox + pxx;
    unsigned q[8];
#pragma unroll
    for (int h = 0; h < 8; ++h)
        q[h] = (unsigned)f2bf(u16[2*h]) | ((unsigned)f2bf(u16[2*h+1]) << 16);
    uint4* dst = (uint4*)y2ci + (size_t)(n*16384 + p)*2;
    dst[0] = make_uint4(q[0], q[1], q[2], q[3]);
    dst[1] = make_uint4(q[4], q[5], q[6], q[7]);
}

// ---------------------------------------------------------------------------
// Bilinear resize 128->256 on ci layout.
// ---------------------------------------------------------------------------
__global__ __launch_bounds__(256) void resize_ci(
    const unsigned short* __restrict__ y2ci, unsigned short* __restrict__ yci)
{
    const int n = blockIdx.z;
    const int ox = blockIdx.x*16 + threadIdx.x;
    const int oy = blockIdx.y*16 + threadIdx.y;
    float sy = oy * (127.f/255.f), sx = ox * (127.f/255.f);
    int y0 = min((int)sy, 126), x0 = min((int)sx, 126);
    float fy = sy - y0, fx = sx - x0;
    const uint4* src = (const uint4*)y2ci;
    size_t i00 = ((size_t)n*16384 + y0*128 + x0)*2;
    unsigned A00[8], A01[8], A10[8], A11[8];
    load8(src, i00,       A00);
    load8(src, i00 + 2,   A01);
    load8(src, i00 + 256, A10);
    load8(src, i00 + 258, A11);
    unsigned q[8];
#pragma unroll
    for (int h = 0; h < 8; ++h) {
        float l00, h00, l01, h01, l10, h10, l11, h11;
        unpack2(A00[h], l00, h00); unpack2(A01[h], l01, h01);
        unpack2(A10[h], l10, h10); unpack2(A11[h], l11, h11);
        float lo = (l00*(1.f-fx) + l01*fx)*(1.f-fy) + (l10*(1.f-fx) + l11*fx)*fy;
        float hi = (h00*(1.f-fx) + h01*fx)*(1.f-fy) + (h10*(1.f-fx) + h11*fx)*fy;
        q[h] = (unsigned)f2bf(lo) | ((unsigned)f2bf(hi) << 16);
    }
    uint4* dst = (uint4*)yci + ((size_t)n*65536 + oy*256 + ox)*2;
    dst[0] = make_uint4(q[0], q[1], q[2], q[3]);
    dst[1] = make_uint4(q[4], q[5], q[6], q[7]);
}

// ---------------------------------------------------------------------------
// 3x3 conv 16->16 via MFMA implicit GEMM on ci layout, BN pre-folded.
// ---------------------------------------------------------------------------
template<int MODE>
__global__ __launch_bounds__(256) void conv3_mfma(
    const unsigned short* __restrict__ in_ci,
    const unsigned short* __restrict__ wB, const float* __restrict__ q3,
    const unsigned short* __restrict__ res_ci,
    unsigned short* __restrict__ out_ci)
{
    __shared__ __align__(16) unsigned char lds[17408];
    unsigned short* tile = (unsigned short*)lds;   // [18][20][16] bf16
    float* P16 = (float*)lds;                      // [256][17] f32

    const int tid = threadIdx.x;
    const int n = blockIdx.z, ox = blockIdx.x*16, oy = blockIdx.y*16;
    const int w = tid >> 6, l = tid & 63, lg = l >> 4, ln = l & 15;

    const uint4* zc = (const uint4*)in_ci;
    uint4* tl4 = (uint4*)tile;
    for (int u = tid; u < 720; u += 256) {
        int r = u / 40, s = u - r*40;
        int y = oy + r - 1, xcol = ox + (s >> 1) - 1;
        uint4 v = make_uint4(0u,0u,0u,0u);
        if (y >= 0 && y < 256 && xcol >= 0 && xcol < 256)
            v = zc[((size_t)n*65536 + y*256 + xcol)*2 + (s & 1)];
        tl4[u] = v;
    }
    __syncthreads();

    float4v acc[4];
#pragma unroll
    for (int mi = 0; mi < 4; ++mi) acc[mi] = (float4v){0.f,0.f,0.f,0.f};
    const short8v* Bb = (const short8v*)wB;
#pragma unroll
    for (int ks = 0; ks < 6; ++ks) {
        const int ky = ks >> 1, kxp = (ks & 1) << 1;
        short8v b = Bb[(ks*16 + ln)*4 + lg];
        short8v a[4];
#pragma unroll
        for (int mi = 0; mi < 4; ++mi) {
            int row = (4*w + mi) + ky;
            a[mi] = *(const short8v*)(tile + (row*20 + ln + kxp)*16 + lg*8);
        }
#pragma unroll
        for (int mi = 0; mi < 4; ++mi)
            acc[mi] = __builtin_amdgcn_mfma_f32_16x16x32_bf16(a[mi], b, acc[mi], 0, 0, 0);
    }
    __syncthreads();
#pragma unroll
    for (int mi = 0; mi < 4; ++mi)
#pragma unroll
        for (int r = 0; r < 4; ++r)
            P16[((4*w + mi)*16 + lg*4 + r)*17 + ln] = acc[mi][r];
    __syncthreads();

    const int py = tid >> 4, pxx = tid & 15;
    const int p = (oy + py)*256 + ox + pxx;
    float u16[16];
#pragma unroll
    for (int o = 0; o < 16; ++o) u16[o] = P16[tid*17 + o] + q3[o];
    if (MODE == 0) {
#pragma unroll
        for (int o = 0; o < 16; ++o) u16[o] = leakyf(u16[o]);
    } else {
        unsigned R[8];
        load8((const uint4*)res_ci, ((size_t)n*65536 + p)*2, R);
#pragma unroll
        for (int h = 0; h < 8; ++h) {
            float lo, hi; unpack2(R[h], lo, hi);
            u16[2*h] += lo; u16[2*h+1] += hi;
        }
    }
    unsigned q[8];
#pragma unroll
    for (int h = 0; h < 8; ++h)
        q[h] = (unsigned)f2bf(u16[2*h]) | ((unsigned)f2bf(u16[2*h+1]) << 16);
    uint4* dst = (uint4*)out_ci + ((size_t)n*65536 + p)*2;
    dst[0] = make_uint4(q[0], q[1], q[2], q[3]);
    dst[1] = make_uint4(q[4], q[5], q[6], q[7]);
}

// ---------------------------------------------------------------------------
// conv7x7 16->64 MFMA + fused epilogue (bias + bilinear identity + k logit).
// ---------------------------------------------------------------------------
__global__ __launch_bounds__(256) void conv7b_mfma(
    const unsigned short* __restrict__ z_ci,
    const unsigned short* __restrict__ pwB,
    const unsigned short* __restrict__ xci,
    const float* __restrict__ bias,
    const float* __restrict__ akw, const float* __restrict__ akb,
    float* __restrict__ out0, float* __restrict__ kbuf)
{
    __shared__ __align__(16) unsigned char lds[17408 + 14400];
    unsigned short* tile = (unsigned short*)lds;          // [22][24][16] bf16
    float* P16 = (float*)lds;                             // [256][17] f32 (aliases tile)
    unsigned short* xt16 = (unsigned short*)(lds + 17408);// [100 px][72] bf16 (pad 8)

    const int tid = threadIdx.x;
    const int n = blockIdx.z, ox = blockIdx.x*16, oy = blockIdx.y*16;
    const float SC = 127.f/255.f;
    const int ybase = (int)(oy*SC), xbase = (int)(ox*SC);

    const uint4* zc = (const uint4*)z_ci;
    uint4* tl4 = (uint4*)tile;
    for (int u = tid; u < 1056; u += 256) {
        int r = u / 48, s = u - r*48;
        int y = oy + r - 3, xcol = ox + (s >> 1) - 3;
        uint4 v = make_uint4(0u, 0u, 0u, 0u);
        if (y >= 0 && y < 256 && xcol >= 0 && xcol < 256)
            v = zc[(size_t)((n*256 + y)*256 + xcol)*2 + (s & 1)];
        tl4[u] = v;
    }
    const uint4* xc4 = (const uint4*)xci;
    uint4* xt4 = (uint4*)xt16;
    for (int u = tid; u < 900; u += 256) {
        int p = u / 9, s = u - p*9;
        uint4 v = make_uint4(0u, 0u, 0u, 0u);
        if (s < 8) {
            int g = s >> 1, half = s & 1;
            int r = p / 10, c = p - r*10;
            int y = ybase + r, xcc = xbase + c;
            if (y < 128 && xcc < 128)
                v = xc4[((size_t)(n*4 + g)*16384 + y*128 + xcc)*2 + half];
        }
        xt4[u] = v;
    }
    __syncthreads();

    const int w = tid >> 6, l = tid & 63;
    const int lg = l >> 4, ln = l & 15;
    float4v acc[4][4];
#pragma unroll
    for (int mi = 0; mi < 4; ++mi)
#pragma unroll
        for (int nt = 0; nt < 4; ++nt)
            acc[mi][nt] = (float4v){0.f, 0.f, 0.f, 0.f};

    const short8v* Bb = (const short8v*)pwB;
    for (int ks = 0; ks < 28; ++ks) {
        const int ky = ks >> 2, kxp = (ks & 3) << 1;
        short8v a[4], b[4];
#pragma unroll
        for (int mi = 0; mi < 4; ++mi) {
            int row = (4*w + mi) + ky;
            a[mi] = *(const short8v*)(tile + (row*24 + ln + kxp)*16 + lg*8);
        }
#pragma unroll
        for (int nt = 0; nt < 4; ++nt)
            b[nt] = Bb[ks*256 + nt*64 + ln*4 + lg];
#pragma unroll
        for (int mi = 0; mi < 4; ++mi)
#pragma unroll
            for (int nt = 0; nt < 4; ++nt)
                acc[mi][nt] = __builtin_amdgcn_mfma_f32_16x16x32_bf16(
                    a[mi], b[nt], acc[mi][nt], 0, 0, 0);
    }

    const int py = tid >> 4, pxx = tid & 15;
    const int ohy = oy + py, ohx = ox + pxx;
    float sy = ohy*SC, sx = ohx*SC;
    int y0 = min((int)sy, 126), x0 = min((int)sx, 126);
    float fy = sy - y0, fx = sx - x0;
    const int ly = y0 - ybase, lx = x0 - xbase;
    const int p = ohy*256 + ohx;
    const uint4* xt4c = (const uint4*)xt16;
    const size_t q00 = (size_t)(ly*10 + lx)*9;
    float kacc = akb[0];

    for (int nt = 0; nt < 4; ++nt) {
        __syncthreads();
#pragma unroll
        for (int mi = 0; mi < 4; ++mi)
#pragma unroll
            for (int r = 0; r < 4; ++r)
                P16[((4*w + mi)*16 + lg*4 + r)*17 + ln] = acc[mi][nt][r];
        __syncthreads();
        unsigned A00[8], A01[8], A10[8], A11[8];
        size_t qb = q00 + nt*2;
        load8(xt4c, qb,      A00);
        load8(xt4c, qb + 9,  A01);
        load8(xt4c, qb + 90, A10);
        load8(xt4c, qb + 99, A11);
        float u16[16];
#pragma unroll
        for (int h = 0; h < 8; ++h) {
            float l00, h00, l01, h01, l10, h10, l11, h11;
            unpack2(A00[h], l00, h00); unpack2(A01[h], l01, h01);
            unpack2(A10[h], l10, h10); unpack2(A11[h], l11, h11);
            u16[2*h]   = (l00*(1.f-fx) + l01*fx)*(1.f-fy) + (l10*(1.f-fx) + l11*fx)*fy;
            u16[2*h+1] = (h00*(1.f-fx) + h01*fx)*(1.f-fy) + (h10*(1.f-fx) + h11*fx)*fy;
        }
#pragma unroll
        for (int o = 0; o < 16; ++o) {
            int oc = nt*16 + o;
            float u = P16[tid*17 + o] + bias[oc] + u16[o];
            out0[(size_t)(n*64 + oc)*HW256 + p] = u;
            kacc += akw[oc] * u;
        }
    }
    kbuf[n*65536 + p] = kacc;
}

// ---------------------------------------------------------------------------
// Softmax stats, stage 1 + stage 2.
// ---------------------------------------------------------------------------
__global__ __launch_bounds__(256) void softmax_part(
    const float* __restrict__ kb, float* __restrict__ pst)
{
    __shared__ float red[4];
    __shared__ float bcast;
    const int pc = blockIdx.x, n = blockIdx.y, tid = threadIdx.x;
    const float* kp = kb + n*65536 + pc*8192;
    float mx = -3.0e38f;
    for (int i = tid; i < 8192; i += 256) mx = fmaxf(mx, kp[i]);
#pragma unroll
    for (int off = 1; off < 64; off <<= 1) mx = fmaxf(mx, __shfl_xor(mx, off));
    int w = tid >> 6, l = tid & 63;
    if (l == 0) red[w] = mx;
    __syncthreads();
    if (tid == 0) bcast = fmaxf(fmaxf(red[0], red[1]), fmaxf(red[2], red[3]));
    __syncthreads();
    float BM = bcast;
    float s = 0.f;
    for (int i = tid; i < 8192; i += 256) s += __expf(kp[i] - BM);
#pragma unroll
    for (int off = 1; off < 64; off <<= 1) s += __shfl_xor(s, off);
    __syncthreads();
    if (l == 0) red[w] = s;
    __syncthreads();
    if (tid == 0) {
        pst[(n*8 + pc)*2]     = BM;
        pst[(n*8 + pc)*2 + 1] = red[0] + red[1] + red[2] + red[3];
    }
}

__global__ __launch_bounds__(64) void softmax_comb(
    const float* __restrict__ pst, float* __restrict__ st)
{
    int tid = threadIdx.x;
    if (tid < 8) {
        int n = tid;
        float MX = -3.0e38f;
        for (int c = 0; c < 8; ++c) MX = fmaxf(MX, pst[(n*8 + c)*2]);
        float S = 0.f;
        for (int c = 0; c < 8; ++c)
            S += pst[(n*8 + c)*2 + 1] * __expf(pst[(n*8 + c)*2] - MX);
        st[n] = MX; st[8 + n] = 1.f / S;
    }
}

// ---------------------------------------------------------------------------
// Partial S: Sp[n][pc][c] = sum over p-chunk of exp(k-mx)*out0[n,c,p].
// ---------------------------------------------------------------------------
__global__ __launch_bounds__(256) void att_wsum(
    const float* __restrict__ out0, const float* __restrict__ kb,
    const float* __restrict__ st, float* __restrict__ Sp)
{
    const int cg = blockIdx.x, pc = blockIdx.y, n = blockIdx.z, c0 = cg*8;
    const float mx = st[n];
    const float* kp = kb + n*65536 + pc*16384;
    const float* base = out0 + (size_t)(n*64 + c0)*HW256 + pc*16384;
    float acc[8];
#pragma unroll
    for (int c = 0; c < 8; ++c) acc[c] = 0.f;
    for (int p = threadIdx.x; p < 16384; p += 256) {
        float e = __expf(kp[p] - mx);
#pragma unroll
        for (int c = 0; c < 8; ++c) acc[c] += e * base[c*HW256 + p];
    }
#pragma unroll
    for (int c = 0; c < 8; ++c)
#pragma unroll
        for (int off = 1; off < 64; off <<= 1) acc[c] += __shfl_xor(acc[c], off);
    __shared__ float red[4][8];
    int w = threadIdx.x >> 6, l = threadIdx.x & 63;
    if (l == 0) {
#pragma unroll
        for (int c = 0; c < 8; ++c) red[w][c] = acc[c];
    }
    __syncthreads();
    if (threadIdx.x < 8)
        Sp[n*256 + pc*64 + c0 + threadIdx.x] =
            red[0][threadIdx.x] + red[1][threadIdx.x] + red[2][threadIdx.x] + red[3][threadIdx.x];
}

// ---------------------------------------------------------------------------
// context + per-(n,c) attention addend.
// ---------------------------------------------------------------------------
__global__ __launch_bounds__(512) void ctx_addc(
    const float* __restrict__ Sp, const float* __restrict__ st,
    const float* __restrict__ avw, const float* __restrict__ avb,
    const float* __restrict__ arw, const float* __restrict__ arb,
    float* __restrict__ addc)
{
    __shared__ float ctx[8][8];
    const int tid = threadIdx.x;
    if (tid < 64) {
        int n = tid >> 3, vc = tid & 7;
        float s = 0.f;
        for (int c = 0; c < 64; ++c) {
            float Sv = Sp[n*256 + c] + Sp[n*256 + 64 + c]
                     + Sp[n*256 + 128 + c] + Sp[n*256 + 192 + c];
            s += avw[vc*64 + c] * Sv;
        }
        ctx[n][vc] = s * st[8 + n] + avb[vc];
    }
    __syncthreads();
    int n = tid >> 6, c = tid & 63;
    float a = arb[c];
#pragma unroll
    for (int vc = 0; vc < 8; ++vc) a += arw[c*8 + vc] * ctx[n][vc];
    addc[n*64 + c] = a;
}

// ---------------------------------------------------------------------------
// Transformer via MFMA. R11: 64 tokens/block (LDS 26.6 KB -> 6 blocks/CU,
// 2x occupancy for the latency-bound load/store streams). Numerics identical.
// ---------------------------------------------------------------------------
__global__ __launch_bounds__(256) void transformer_mfma(
    float* __restrict__ out0, const float* __restrict__ addc,
    const float* __restrict__ lng, const float* __restrict__ lnb,
    const unsigned short* __restrict__ W1b, const float* __restrict__ fc1b,
    const unsigned short* __restrict__ W2b, const float* __restrict__ fc2b)
{
    __shared__ __align__(16) unsigned char lds[17408 + 9216];
    float*          Xt = (float*)lds;                         // [64ch][68] f32
    unsigned short* Xb = (unsigned short*)(lds + 17408);      // [64tok][72] bf16
    unsigned short* Hb = Xb;                                  // aliases Xb

    const int tid = threadIdx.x;
    const int n = blockIdx.x >> 10;
    const int p0 = (blockIdx.x & 1023) << 6;
    const float* ac = addc + n*64;

    // Phase 1: load 64 tokens x 64 ch (float4/lane), t = out0 + addc
#pragma unroll
    for (int k = 0; k < 4; ++k) {
        int v = k*256 + tid;
        int c = v >> 4, i4 = (v & 15) << 2;
        float4v q = *(const float4v*)(out0 + (size_t)(n*64 + c)*HW256 + p0 + i4);
        float a = ac[c];
#pragma unroll
        for (int r = 0; r < 4; ++r) q[r] += a;
        *(float4v*)&Xt[c*68 + i4] = q;
    }
    __syncthreads();

    // Phase 2: LN per token (threads 0..63), conflict-free column reads
    if (tid < 64) {
        float t[64];
#pragma unroll
        for (int c = 0; c < 64; ++c) t[c] = Xt[c*68 + tid];
        float mu = 0.f;
#pragma unroll
        for (int c = 0; c < 64; ++c) mu += t[c];
        mu *= (1.f/64.f);
        float var = 0.f;
#pragma unroll
        for (int c = 0; c < 64; ++c) { float d = t[c] - mu; var += d*d; }
        var *= (1.f/64.f);
        float rs = rsqrtf(var + 1e-5f);
#pragma unroll
        for (int c8 = 0; c8 < 8; ++c8) {
            short8v pk;
#pragma unroll
            for (int e = 0; e < 8; ++e) {
                int c = c8*8 + e;
                pk[e] = (short)f2bf((t[c] - mu)*rs*lng[c] + lnb[c]);
            }
            *(short8v*)&Xb[tid*72 + c8*8] = pk;
        }
    }
    __syncthreads();

    const int w = tid >> 6, l = tid & 63, lg = l >> 4, ln = l & 15;

    // Phase 3: GEMM1 (wave w owns tokens w*16..w*16+15)
    float4v acc1[4];
#pragma unroll
    for (int nt = 0; nt < 4; ++nt) acc1[nt] = (float4v){0.f,0.f,0.f,0.f};
#pragma unroll
    for (int kk = 0; kk < 2; ++kk) {
        short8v a = *(const short8v*)&Xb[(w*16 + ln)*72 + kk*32 + lg*8];
        short8v b[4];
#pragma unroll
        for (int nt = 0; nt < 4; ++nt)
            b[nt] = *(const short8v*)&W1b[(nt*16 + ln)*64 + kk*32 + lg*8];
#pragma unroll
        for (int nt = 0; nt < 4; ++nt)
            acc1[nt] = __builtin_amdgcn_mfma_f32_16x16x32_bf16(a, b[nt], acc1[nt], 0, 0, 0);
    }
    __syncthreads();   // all waves done reading Xb before Hb (=Xb) writes
#pragma unroll
    for (int nt = 0; nt < 4; ++nt) {
        int j = nt*16 + ln;
        float bj = fc1b[j];
#pragma unroll
        for (int r = 0; r < 4; ++r) {
            int token = w*16 + lg*4 + r;
            float m = acc1[nt][r] + bj;
            float g = 0.5f*m*(1.f + erff(m*0.70710678118654752f));
            Hb[token*72 + j] = f2bf(g);
        }
    }
    __syncthreads();

    // Phase 4: GEMM2 + epilogue (residual from Xt)
    float4v acc2[4];
#pragma unroll
    for (int nt = 0; nt < 4; ++nt) acc2[nt] = (float4v){0.f,0.f,0.f,0.f};
#pragma unroll
    for (int kk = 0; kk < 2; ++kk) {
        short8v a = *(const short8v*)&Hb[(w*16 + ln)*72 + kk*32 + lg*8];
        short8v b[4];
#pragma unroll
        for (int nt = 0; nt < 4; ++nt)
            b[nt] = *(const short8v*)&W2b[(nt*16 + ln)*64 + kk*32 + lg*8];
#pragma unroll
        for (int nt = 0; nt < 4; ++nt)
            acc2[nt] = __builtin_amdgcn_mfma_f32_16x16x32_bf16(a, b[nt], acc2[nt], 0, 0, 0);
    }
#pragma unroll
    for (int nt = 0; nt < 4; ++nt) {
        int c = nt*16 + ln;
        int tb = w*16 + lg*4;
        float add = fc2b[c];
        float4v t4 = *(const float4v*)&Xt[c*68 + tb];
        float* dst = out0 + (size_t)(n*64 + c)*HW256 + p0 + tb;
        float4v o;
#pragma unroll
        for (int r = 0; r < 4; ++r) o[r] = t4[r] + acc2[nt][r] + add;
        *(float4v*)dst = o;
    }
}

// ---------------------------------------------------------------------------
extern "C" void kernel_launch(void* const* d_in, const int* in_sizes, int n_in,
                              void* d_out, int out_size, void* d_ws, size_t ws_size,
                              hipStream_t stream)
{
    (void)in_sizes; (void)n_in; (void)out_size; (void)ws_size;
    const float* x    = (const float*)d_in[0];
    const float* w7a  = (const float*)d_in[1];
    const float* b7a  = (const float*)d_in[2];
    const float* w1   = (const float*)d_in[3];
    const float* b1   = (const float*)d_in[4];
    const float* g1   = (const float*)d_in[5];
    const float* be1  = (const float*)d_in[6];
    const float* w3a  = (const float*)d_in[7];
    const float* b3a  = (const float*)d_in[8];
    const float* g3a  = (const float*)d_in[9];
    const float* be3a = (const float*)d_in[10];
    const float* w3b  = (const float*)d_in[11];
    const float* b3b  = (const float*)d_in[12];
    const float* g3b  = (const float*)d_in[13];
    const float* be3b = (const float*)d_in[14];
    const float* w3c  = (const float*)d_in[15];
    const float* b3c  = (const float*)d_in[16];
    const float* g3c  = (const float*)d_in[17];
    const float* be3c = (const float*)d_in[18];
    const float* w7b  = (const float*)d_in[19];
    const float* b7b  = (const float*)d_in[20];
    const float* akw  = (const float*)d_in[21];
    const float* akb  = (const float*)d_in[22];
    const float* avw  = (const float*)d_in[25];
    const float* avb  = (const float*)d_in[26];
    const float* arw  = (const float*)d_in[27];
    const float* arb  = (const float*)d_in[28];
    const float* lng  = (const float*)d_in[29];
    const float* lnb  = (const float*)d_in[30];
    const float* fc1w = (const float*)d_in[31];
    const float* fc1b = (const float*)d_in[32];
    const float* fc2w = (const float*)d_in[33];
    const float* fc2b = (const float*)d_in[34];

    float* ws = (float*)d_ws;
    unsigned short* y2ci = (unsigned short*)ws;                         // 2,097,152 sh
    unsigned short* yci  = (unsigned short*)(ws + 1048576);             // 8,388,608 sh
    unsigned short* z1ci = (unsigned short*)(ws + 1048576 + 4194304);   // 8,388,608 sh (z1/z3)
    unsigned short* z2ci = (unsigned short*)(ws + 1048576 + 2*4194304); // 8,388,608 sh
    unsigned short* xci  = (unsigned short*)(ws + 1048576 + 3*4194304); // 8,388,608 sh (persists)
    float* o_k   = ws + 1048576 + 4*4194304;    // 524,288
    float* o_st  = o_k + 524288;                // 64
    float* o_pst = o_st + 64;                   // 128
    float* o_Sp  = o_pst + 128;                 // 2,048
    float* o_ad  = o_Sp + 2048;                 // 512
    unsigned short* p7aB = (unsigned short*)(o_ad + 512);   // 57,344 sh
    float* p1   = o_ad + 512 + 28672;           // 256
    float* q3a  = p1 + 256;
    float* q3b  = q3a + 16;
    float* q3c  = q3b + 16;
    unsigned short* w3aB = (unsigned short*)(q3c + 16);     // 3,072 sh each
    unsigned short* w3bB = w3aB + 3072;
    unsigned short* w3cB = w3bB + 3072;
    unsigned short* pwB  = w3cB + 3072;                     // 57,344 sh
    unsigned short* pwT1 = pwB + 57344;                     // 4,096 sh
    unsigned short* pwT2 = pwT1 + 4096;                     // 4,096 sh

    unsigned short* z3ci = z1ci;
    float* out0 = (float*)d_out;

    prepack<<<224, 256, 0, stream>>>(w7a, w1, w3a,b3a,g3a,be3a, w3b,b3b,g3b,be3b,
                                     w3c,b3c,g3c,be3c, w7b, fc1w, fc2w,
                                     p7aB, p1, q3a, q3b, q3c, w3aB, w3bB, w3cB,
                                     pwB, pwT1, pwT2);
    x_to_ci<<<2048, 256, 0, stream>>>(x, xci);
    conv7a_mfma<<<dim3(8,8,8), 256, 0, stream>>>(xci, p7aB, b7a, p1, b1, g1, be1, y2ci);
    resize_ci<<<dim3(16,16,8), dim3(16,16), 0, stream>>>(y2ci, yci);
    conv3_mfma<0><<<dim3(16,16,8), 256, 0, stream>>>(yci,  w3aB, q3a, nullptr, z1ci);
    conv3_mfma<1><<<dim3(16,16,8), 256, 0, stream>>>(z1ci, w3bB, q3b, yci,     z2ci);
    conv3_mfma<1><<<dim3(16,16,8), 256, 0, stream>>>(z2ci, w3cB, q3c, yci,     z3ci);
    conv7b_mfma<<<dim3(16,16,8), 256, 0, stream>>>(z3ci, pwB, xci, b7b, akw, akb, out0, o_k);
    softmax_part<<<dim3(8,8), 256, 0, stream>>>(o_k, o_pst);
    softmax_comb<<<1, 64, 0, stream>>>(o_pst, o_st);
    att_wsum<<<dim3(8,4,8), 256, 0, stream>>>(out0, o_k, o_st, o_Sp);
    ctx_addc<<<1, 512, 0, stream>>>(o_Sp, o_st, avw, avb, arw, arb, o_ad);
    transformer_mfma<<<8192, 256, 0, stream>>>(out0, o_ad, lng, lnb, pwT1, fc1b, pwT2, fc2b);
}